// Round 5
// baseline (862.198 us; speedup 1.0000x reference)
//
#include <hip/hip_runtime.h>
#include <hip/hip_bf16.h>

// Color_Attention: transposed (channel) attention.
//   Z = [I; C] (384 x 16384 bf16, per batch, tiled+swizzled, stored in d_out as scratch)
//   Z*Z^T upper triangle = { G_ii, G_ic, G_cc }  (one symmetric gram kernel, partials)
//   reduce_k sums partials -> G; mirror_k fills lower triangles
//   A_pre = Wq*G_ci*Wk^T ; nq = diag(Wq*G_cc*Wq^T); nk = diag(Wk*G_ii*Wk^T)
//   attn = softmax over head-diagonal 24x24 blocks of A_pre/(nq*nk)
//   P = Wo * blockdiag(attn) * Wv ; out = P @ input

typedef __attribute__((ext_vector_type(4))) float f32x4;
typedef __attribute__((ext_vector_type(8))) short short8;

#define MFMA16(a, b, c) __builtin_amdgcn_mfma_f32_16x16x32_bf16((a), (b), (c), 0, 0, 0)

__device__ __forceinline__ unsigned int pack_rne(float a, float b) {
  unsigned int ua = __float_as_uint(a), ub = __float_as_uint(b);
  ua += 0x7fffu + ((ua >> 16) & 1u);
  ub += 0x7fffu + ((ub >> 16) & 1u);
  return (ua >> 16) | (ub & 0xffff0000u);
}
__device__ __forceinline__ unsigned short bf16u_rne(float x) {
  unsigned int u = __float_as_uint(x);
  u += 0x7fffu + ((u >> 16) & 1u);
  return (unsigned short)(u >> 16);
}
union S8U { short8 s; unsigned int u[4]; };
__device__ __forceinline__ short8 load_cvt8(const float* p) {
  f32x4 x = *(const f32x4*)p;
  f32x4 y = *(const f32x4*)(p + 4);
  S8U r;
  r.u[0] = pack_rne(x[0], x[1]);
  r.u[1] = pack_rne(x[2], x[3]);
  r.u[2] = pack_rne(y[0], y[1]);
  r.u[3] = pack_rne(y[2], y[3]);
  return r.s;
}

#define HW 16384
#define CDIM 192
#define NB 8
#define TILE_B 49152  // 384 rows * 128 B
#define GSZ (CDIM * CDIM)

// ---------------- Kernel A: convert fp32 -> swizzled bf16 Z tiles ------------
__global__ __launch_bounds__(256) void convert_k(const float* __restrict__ input,
                                                 const float* __restrict__ color,
                                                 const float* __restrict__ Wv,
                                                 unsigned short* __restrict__ WvT,
                                                 char* __restrict__ zbf) {
  const int kc = blockIdx.x, b = blockIdx.y;
  const int t = threadIdx.x;
  if (kc == 256) {
    if (b == 0) {
      for (int idx = t; idx < CDIM * CDIM; idx += 256) {
        int j = idx / CDIM, cp = idx % CDIM;
        WvT[idx] = bf16u_rne(Wv[(size_t)cp * CDIM + j]);
      }
    }
    return;
  }
  char* zt = zbf + ((size_t)b * 256 + kc) * TILE_B;
  const int srow = t >> 4;             // 0..15
  const int c4 = (t & 15) * 4;         // f32 col
  const int cb = c4 * 2;               // byte col
  const int sw = (srow & 7) << 4;
  const float* ib = input + (size_t)b * CDIM * HW + (size_t)kc * 64 + c4;
  const float* cp = color + (size_t)b * CDIM * HW + (size_t)kc * 64 + c4;
#pragma unroll
  for (int r = 0; r < 12; ++r) {
    const int row = r * 16 + srow;
    f32x4 v = *(const f32x4*)(ib + (size_t)row * HW);
    unsigned long long p0 = (unsigned long long)pack_rne(v[0], v[1]) |
                            ((unsigned long long)pack_rne(v[2], v[3]) << 32);
    *(unsigned long long*)(zt + row * 128 + (cb ^ sw)) = p0;
    f32x4 w = *(const f32x4*)(cp + (size_t)row * HW);
    unsigned long long p1 = (unsigned long long)pack_rne(w[0], w[1]) |
                            ((unsigned long long)pack_rne(w[2], w[3]) << 32);
    *(unsigned long long*)(zt + (192 + row) * 128 + (cb ^ sw)) = p1;
  }
}

// ---------------- Kernel B: gram Z*Z^T (upper triangle), partial stores ------
__device__ __forceinline__ short8 zfrag(const char* buf, int row, int ks, int lg) {
  return *(const short8*)(buf + row * 128 + ((ks * 64 + lg * 16) ^ ((row & 7) << 4)));
}

__device__ __forceinline__ void stage48(const char* gsrc, char* ldst, int wave, int lane) {
#pragma unroll
  for (int i = 0; i < 6; ++i) {
    const int off = (wave * 6 + i) * 1024;
    __builtin_amdgcn_global_load_lds(
        (const __attribute__((address_space(1))) void*)(gsrc + off + lane * 16),
        (__attribute__((address_space(3))) void*)(ldst + off), 16, 0, 0);
  }
}

// waves 0..3: G_ic = I*C^T. A row-tiles 3w..3w+2 (I), B col-tiles 0..11 (C).
__device__ __forceinline__ void gic_step(const char* buf, int w, f32x4 (&acc)[39],
                                         int l15, int lg) {
#pragma unroll
  for (int ks = 0; ks < 2; ++ks) {
    short8 a[3];
#pragma unroll
    for (int tt = 0; tt < 3; ++tt) a[tt] = zfrag(buf, (w * 3 + tt) * 16 + l15, ks, lg);
#pragma unroll
    for (int tj = 0; tj < 12; ++tj) {
      short8 bf = zfrag(buf, 192 + tj * 16 + l15, ks, lg);
#pragma unroll
      for (int tt = 0; tt < 3; ++tt) acc[tt * 12 + tj] = MFMA16(a[tt], bf, acc[tt * 12 + tj]);
    }
  }
}

// sym waves: pairs (R,11-R) for R in {R0,R1,R2}; 13 tiles per pair.
template <int R0, int R1, int R2>
__device__ __forceinline__ void sym_step(const char* buf, int zbase, f32x4 (&acc)[39],
                                         int l15, int lg) {
#pragma unroll
  for (int ks = 0; ks < 2; ++ks) {
    short8 bfr[12];
#pragma unroll
    for (int tj = R0; tj < 12; ++tj) bfr[tj] = zfrag(buf, zbase + tj * 16 + l15, ks, lg);
#pragma unroll
    for (int p = 0; p < 3; ++p) {
      const int R = (p == 0) ? R0 : ((p == 1) ? R1 : R2);
      short8 aT = zfrag(buf, zbase + R * 16 + l15, ks, lg);
      short8 aB = zfrag(buf, zbase + (11 - R) * 16 + l15, ks, lg);
#pragma unroll
      for (int tj = 0; tj < 12; ++tj) {
        if (tj >= R) acc[p * 13 + (tj - R)] = MFMA16(aT, bfr[tj], acc[p * 13 + (tj - R)]);
        if (tj >= 11 - R) {
          const int s = p * 13 + (12 - R) + (tj - (11 - R));
          acc[s] = MFMA16(aB, bfr[tj], acc[s]);
        }
      }
    }
  }
}

// store upper-triangle tiles to the partial buffer (regular stores, no atomics)
template <int R0, int R1, int R2>
__device__ __forceinline__ void flush_sym_part(float* __restrict__ Ps, f32x4 (&acc)[39],
                                               int l15, int lg) {
#pragma unroll
  for (int p = 0; p < 3; ++p) {
    const int R = (p == 0) ? R0 : ((p == 1) ? R1 : R2);
#pragma unroll
    for (int tj = 0; tj < 12; ++tj) {
      if (tj >= R) {
        const f32x4 v = acc[p * 13 + (tj - R)];
        const int m0 = R * 16 + lg * 4, n = tj * 16 + l15;
#pragma unroll
        for (int r = 0; r < 4; ++r) Ps[(size_t)(m0 + r) * CDIM + n] = v[r];
      }
      if (tj >= 11 - R) {
        const f32x4 v = acc[p * 13 + (12 - R) + (tj - (11 - R))];
        const int m0 = (11 - R) * 16 + lg * 4, n = tj * 16 + l15;
#pragma unroll
        for (int r = 0; r < 4; ++r) Ps[(size_t)(m0 + r) * CDIM + n] = v[r];
      }
    }
  }
}

// grid (NPART, 8), 512 threads, 8 waves, LDS 2x48KB double buffer.
__global__ __launch_bounds__(512, 1) void gram2_k(const char* __restrict__ zbf,
                                                  float* __restrict__ part,
                                                  int npart, int cpb) {
  __shared__ __align__(16) char lds[2][TILE_B];
  const int tid = threadIdx.x, wave = tid >> 6, lane = tid & 63;
  const int l15 = lane & 15, lg = (lane >> 4) & 3;
  const int strip = blockIdx.x, b = blockIdx.y;
  const char* ztb = zbf + ((size_t)b * 256 + (size_t)strip * cpb) * TILE_B;

  f32x4 acc[39];
#pragma unroll
  for (int i = 0; i < 39; ++i) acc[i] = (f32x4){0.f, 0.f, 0.f, 0.f};

  stage48(ztb, lds[0], wave, lane);
#pragma unroll 1
  for (int c = 0; c < cpb - 1; ++c) {
    stage48(ztb + (size_t)(c + 1) * TILE_B, lds[(c + 1) & 1], wave, lane);
    asm volatile("s_waitcnt vmcnt(6)" ::: "memory");
    __builtin_amdgcn_sched_barrier(0);
    __builtin_amdgcn_s_barrier();
    const char* buf = lds[c & 1];
    if (wave < 4) gic_step(buf, wave, acc, l15, lg);
    else if (wave == 4) sym_step<0, 1, 2>(buf, 192, acc, l15, lg);
    else if (wave == 5) sym_step<3, 4, 5>(buf, 192, acc, l15, lg);
    else if (wave == 6) sym_step<0, 1, 2>(buf, 0, acc, l15, lg);
    else sym_step<3, 4, 5>(buf, 0, acc, l15, lg);
    asm volatile("s_waitcnt lgkmcnt(0)" ::: "memory");
    __builtin_amdgcn_sched_barrier(0);
    __builtin_amdgcn_s_barrier();
  }
  asm volatile("s_waitcnt vmcnt(0)" ::: "memory");
  __builtin_amdgcn_sched_barrier(0);
  __builtin_amdgcn_s_barrier();
  {
    const char* buf = lds[(cpb - 1) & 1];
    if (wave < 4) gic_step(buf, wave, acc, l15, lg);
    else if (wave == 4) sym_step<0, 1, 2>(buf, 192, acc, l15, lg);
    else if (wave == 5) sym_step<3, 4, 5>(buf, 192, acc, l15, lg);
    else if (wave == 6) sym_step<0, 1, 2>(buf, 0, acc, l15, lg);
    else sym_step<3, 4, 5>(buf, 0, acc, l15, lg);
  }

  float* pbase = part + ((size_t)(b * npart + strip) * 3) * GSZ;
  if (wave < 4) {
    float* P0 = pbase;  // t=0: G_ic, full matrix
#pragma unroll
    for (int tt = 0; tt < 3; ++tt) {
      const int m0 = (wave * 3 + tt) * 16 + lg * 4;
#pragma unroll
      for (int tj = 0; tj < 12; ++tj) {
        const int n = tj * 16 + l15;
        const f32x4 v = acc[tt * 12 + tj];
#pragma unroll
        for (int r = 0; r < 4; ++r) P0[(size_t)(m0 + r) * CDIM + n] = v[r];
      }
    }
  } else {
    float* Ps = pbase + (size_t)((wave < 6) ? 1 : 2) * GSZ;
    if (wave == 4 || wave == 6) flush_sym_part<0, 1, 2>(Ps, acc, l15, lg);
    else flush_sym_part<3, 4, 5>(Ps, acc, l15, lg);
  }
}

// ---------------- reduce partials -> G (upper tiles for sym types) ----------
// grid (NB, 3), 256 threads
__global__ __launch_bounds__(256) void reduce_k(const float* __restrict__ part,
                                                float* __restrict__ G, int npart) {
  const int b = blockIdx.x, t = blockIdx.y;
  const float* pb = part + ((size_t)b * npart * 3 + t) * GSZ;
  float* Gm = G + ((size_t)t * NB + b) * GSZ;
  for (int i = threadIdx.x; i < GSZ / 4; i += 256) {
    const int m = i / 48, n4 = (i % 48) * 4;
    if (t != 0 && (m >> 4) > (n4 >> 4)) continue;  // lower tile: mirror_k fills
    f32x4 s = (f32x4){0.f, 0.f, 0.f, 0.f};
    const float* p = pb + (size_t)m * CDIM + n4;
    for (int sgl = 0; sgl < npart; ++sgl) {
      f32x4 v = *(const f32x4*)(p + (size_t)sgl * 3 * GSZ);
      s[0] += v[0]; s[1] += v[1]; s[2] += v[2]; s[3] += v[3];
    }
    *(f32x4*)(Gm + (size_t)m * CDIM + n4) = s;
  }
}

// mirror lower triangle of symmetric grams (types 1,2)
__global__ void mirror_k(float* __restrict__ G) {
  float* Gm = G + ((size_t)(1 + blockIdx.y) * NB + blockIdx.x) * GSZ;
  for (int i = threadIdx.x; i < GSZ; i += 256) {
    const int m = i / CDIM, n = i - m * CDIM;
    if (m > n) Gm[i] = Gm[(size_t)n * CDIM + m];
  }
}

// ---------------- Kernel 2a: A_pre (type0), nq (type1), nk (type2) ----------
__global__ __launch_bounds__(256) void k2a(const float* __restrict__ G,
                                           const float* __restrict__ Wq,
                                           const float* __restrict__ Wk,
                                           float* __restrict__ A_pre,
                                           float* __restrict__ nqk) {
  const int b = blockIdx.x, type = blockIdx.y;
  __shared__ __align__(16) unsigned short Hs[192][200];
  const int tid = threadIdx.x, wave = tid >> 6, lane = tid & 63;
  const int l15 = lane & 15, lg = lane >> 4, row0 = wave * 48;
  const float* W1 = (type == 2) ? Wk : Wq;
  const float* Gm = G + ((size_t)type * NB + b) * GSZ;

  f32x4 acc[3][12];
#pragma unroll
  for (int t = 0; t < 3; t++)
#pragma unroll
    for (int j = 0; j < 12; j++) acc[t][j] = (f32x4){0.f, 0.f, 0.f, 0.f};

  for (int ks = 0; ks < 192; ks += 32) {
    short8 afr[3];
#pragma unroll
    for (int t = 0; t < 3; t++)
      afr[t] = load_cvt8(W1 + (size_t)(row0 + t * 16 + l15) * CDIM + ks + lg * 8);
#pragma unroll
    for (int tj = 0; tj < 12; tj++) {
      short8 bfr = load_cvt8(Gm + (size_t)(tj * 16 + l15) * CDIM + ks + lg * 8);
#pragma unroll
      for (int t = 0; t < 3; t++) acc[t][tj] = MFMA16(afr[t], bfr, acc[t][tj]);
    }
  }
#pragma unroll
  for (int t = 0; t < 3; t++)
#pragma unroll
    for (int tj = 0; tj < 12; tj++)
#pragma unroll
      for (int r = 0; r < 4; r++)
        Hs[row0 + t * 16 + lg * 4 + r][tj * 16 + l15] = bf16u_rne(acc[t][tj][r]);
  __syncthreads();

  if (type == 0) {
    f32x4 a2[3][12];
#pragma unroll
    for (int t = 0; t < 3; t++)
#pragma unroll
      for (int j = 0; j < 12; j++) a2[t][j] = (f32x4){0.f, 0.f, 0.f, 0.f};
    for (int ks = 0; ks < 192; ks += 32) {
      short8 afr[3];
#pragma unroll
      for (int t = 0; t < 3; t++)
        afr[t] = *(const short8*)&Hs[row0 + t * 16 + l15][ks + lg * 8];
#pragma unroll
      for (int tj = 0; tj < 12; tj++) {
        short8 bfr = load_cvt8(Wk + (size_t)(tj * 16 + l15) * CDIM + ks + lg * 8);
#pragma unroll
        for (int t = 0; t < 3; t++) a2[t][tj] = MFMA16(afr[t], bfr, a2[t][tj]);
      }
    }
    float* Ab = A_pre + (size_t)b * GSZ;
#pragma unroll
    for (int t = 0; t < 3; t++)
#pragma unroll
      for (int tj = 0; tj < 12; tj++)
#pragma unroll
        for (int r = 0; r < 4; r++)
          Ab[(size_t)(row0 + t * 16 + lg * 4 + r) * CDIM + tj * 16 + l15] = a2[t][tj][r];
  } else {
    f32x4 a2[3];
#pragma unroll
    for (int t = 0; t < 3; t++) a2[t] = (f32x4){0.f, 0.f, 0.f, 0.f};
    for (int ks = 0; ks < 192; ks += 32) {
#pragma unroll
      for (int t = 0; t < 3; t++) {
        short8 afr = *(const short8*)&Hs[row0 + t * 16 + l15][ks + lg * 8];
        short8 bfr = load_cvt8(W1 + (size_t)(row0 + t * 16 + l15) * CDIM + ks + lg * 8);
        a2[t] = MFMA16(afr, bfr, a2[t]);
      }
    }
    float* dst = nqk + ((size_t)(type - 1) * NB + b) * CDIM;
#pragma unroll
    for (int t = 0; t < 3; t++)
#pragma unroll
      for (int r = 0; r < 4; r++)
        if (lg * 4 + r == l15) dst[row0 + t * 16 + l15] = a2[t][r];
  }
}

// ---------------- Kernel 2b: per-head softmax ----------------
__global__ void k2b(const float* __restrict__ A_pre, const float* __restrict__ nqk,
                    float* __restrict__ attnw) {
  const int b = blockIdx.x, tid = threadIdx.x;
  const int h = tid >> 5, r = tid & 31;
  if (r >= 24) return;
  const float* Ab = A_pre + (size_t)b * GSZ;
  const float* nq = nqk + (size_t)b * CDIM;
  const float* nk = nqk + (size_t)(NB + b) * CDIM;
  const int c = h * 24 + r;
  const float qn = rsqrtf(fmaxf(nq[c], 1e-24f));
  float e[24];
  float mx = -1e30f;
#pragma unroll
  for (int d = 0; d < 24; d++) {
    float kn = rsqrtf(fmaxf(nk[h * 24 + d], 1e-24f));
    float l = Ab[(size_t)c * CDIM + h * 24 + d] * qn * kn;
    e[d] = l;
    mx = fmaxf(mx, l);
  }
  float s = 0.f;
#pragma unroll
  for (int d = 0; d < 24; d++) {
    float x = __expf(e[d] - mx);
    e[d] = x;
    s += x;
  }
  const float inv = 1.0f / s;
  float* dst = attnw + (((size_t)b * NB + h) * 24 + r) * 24;
#pragma unroll
  for (int d = 0; d < 24; d++) dst[d] = e[d] * inv;
}

// ---------------- Kernel 3: P = Wo * blockdiag(attn) * Wv  (bf16 out) -------
__global__ __launch_bounds__(256) void k3(const float* __restrict__ attnw,
                                          const float* __restrict__ Wo,
                                          const unsigned short* __restrict__ WvT,
                                          unsigned short* __restrict__ Pbf) {
  const int b = blockIdx.x;
  __shared__ __align__(16) unsigned short AT[192][200];
  __shared__ __align__(16) unsigned short Ms[192][200];
  const int tid = threadIdx.x, wave = tid >> 6, lane = tid & 63;
  const int l15 = lane & 15, lg = lane >> 4, row0 = wave * 48;

  unsigned int* ATu = (unsigned int*)&AT[0][0];
  for (int i = tid; i < 192 * 100; i += 256) ATu[i] = 0u;
  __syncthreads();
  const float* at = attnw + (size_t)b * NB * 24 * 24;
  for (int i = tid; i < 4608; i += 256) {
    int h = i / 576, rem = i % 576, c = rem / 24, d = rem % 24;
    AT[h * 24 + d][h * 24 + c] = bf16u_rne(at[(h * 24 + c) * 24 + d]);
  }
  __syncthreads();

  f32x4 acc[3][12];
#pragma unroll
  for (int t = 0; t < 3; t++)
#pragma unroll
    for (int j = 0; j < 12; j++) acc[t][j] = (f32x4){0.f, 0.f, 0.f, 0.f};
  for (int ks = 0; ks < 192; ks += 32) {
    short8 afr[3];
#pragma unroll
    for (int t = 0; t < 3; t++)
      afr[t] = load_cvt8(Wo + (size_t)(row0 + t * 16 + l15) * CDIM + ks + lg * 8);
#pragma unroll
    for (int tj = 0; tj < 12; tj++) {
      short8 bfr = *(const short8*)&AT[tj * 16 + l15][ks + lg * 8];
#pragma unroll
      for (int t = 0; t < 3; t++) acc[t][tj] = MFMA16(afr[t], bfr, acc[t][tj]);
    }
  }
#pragma unroll
  for (int t = 0; t < 3; t++)
#pragma unroll
    for (int tj = 0; tj < 12; tj++)
#pragma unroll
      for (int r = 0; r < 4; r++)
        Ms[row0 + t * 16 + lg * 4 + r][tj * 16 + l15] = bf16u_rne(acc[t][tj][r]);
  __syncthreads();

  f32x4 a2[3][12];
#pragma unroll
  for (int t = 0; t < 3; t++)
#pragma unroll
    for (int j = 0; j < 12; j++) a2[t][j] = (f32x4){0.f, 0.f, 0.f, 0.f};
  for (int ks = 0; ks < 192; ks += 32) {
    short8 afr[3];
#pragma unroll
    for (int t = 0; t < 3; t++)
      afr[t] = *(const short8*)&Ms[row0 + t * 16 + l15][ks + lg * 8];
#pragma unroll
    for (int tj = 0; tj < 12; tj++) {
      short8 bfr = *(const short8*)(WvT + (size_t)(tj * 16 + l15) * CDIM + ks + lg * 8);
#pragma unroll
      for (int t = 0; t < 3; t++) a2[t][tj] = MFMA16(afr[t], bfr, a2[t][tj]);
    }
  }
  unsigned short* Pb = Pbf + (size_t)b * GSZ;
#pragma unroll
  for (int t = 0; t < 3; t++)
#pragma unroll
    for (int tj = 0; tj < 12; tj++)
#pragma unroll
      for (int r = 0; r < 4; r++)
        Pb[(size_t)(row0 + t * 16 + lg * 4 + r) * CDIM + tj * 16 + l15] = bf16u_rne(a2[t][tj][r]);
}

// ---------------- Kernel D: out = P @ input  ----------------
__global__ __launch_bounds__(256) void kD(const unsigned short* __restrict__ Pbf,
                                          const float* __restrict__ input,
                                          float* __restrict__ out) {
  const int nchunk = blockIdx.x, b = blockIdx.y;
  const int n0 = nchunk * 128;
  __shared__ __align__(16) char BsT[128 * 384];
  const int tid = threadIdx.x, wave = tid >> 6, lane = tid & 63;
  const int l15 = lane & 15, lg = lane >> 4, row0 = wave * 48;

  {
    const int n4 = (tid & 31) * 4;
    const int kb0 = (tid >> 5) * 4;
    const float* src = input + (size_t)b * CDIM * HW + n0 + n4;
#pragma unroll
    for (int rnd = 0; rnd < 6; ++rnd) {
      const int kb = kb0 + rnd * 32;
      f32x4 v0 = *(const f32x4*)(src + (size_t)(kb + 0) * HW);
      f32x4 v1 = *(const f32x4*)(src + (size_t)(kb + 1) * HW);
      f32x4 v2 = *(const f32x4*)(src + (size_t)(kb + 2) * HW);
      f32x4 v3 = *(const f32x4*)(src + (size_t)(kb + 3) * HW);
#pragma unroll
      for (int i = 0; i < 4; ++i) {
        const int n = n4 + i;
        unsigned long long pk = (unsigned long long)pack_rne(v0[i], v1[i]) |
                                ((unsigned long long)pack_rne(v2[i], v3[i]) << 32);
        *(unsigned long long*)(BsT + n * 384 + ((kb * 2) ^ ((n & 7) << 4))) = pk;
      }
    }
  }
  __syncthreads();

  f32x4 acc[3][8];
#pragma unroll
  for (int t = 0; t < 3; t++)
#pragma unroll
    for (int j = 0; j < 8; j++) acc[t][j] = (f32x4){0.f, 0.f, 0.f, 0.f};

  const unsigned short* Pb = Pbf + (size_t)b * GSZ;
#pragma unroll 2
  for (int ks = 0; ks < 6; ks++) {
    short8 afr[3];
#pragma unroll
    for (int t = 0; t < 3; t++)
      afr[t] = *(const short8*)(Pb + (size_t)(row0 + t * 16 + l15) * CDIM + ks * 32 + lg * 8);
#pragma unroll
    for (int tn = 0; tn < 8; tn++) {
      const int n = tn * 16 + l15;
      short8 bfr = *(const short8*)(BsT + n * 384 + ((ks * 64 + lg * 16) ^ ((n & 7) << 4)));
#pragma unroll
      for (int t = 0; t < 3; t++) acc[t][tn] = MFMA16(afr[t], bfr, acc[t][tn]);
    }
  }
  float* ob = out + (size_t)b * CDIM * HW + n0;
#pragma unroll
  for (int t = 0; t < 3; t++)
#pragma unroll
    for (int tn = 0; tn < 8; tn++)
#pragma unroll
      for (int r = 0; r < 4; r++) {
        const int m = row0 + t * 16 + lg * 4 + r;
        ob[(size_t)m * HW + tn * 16 + l15] = acc[t][tn][r];
      }
}

// ---------------- launch ----------------
extern "C" void kernel_launch(void* const* d_in, const int* in_sizes, int n_in,
                              void* d_out, int out_size, void* d_ws, size_t ws_size,
                              hipStream_t stream) {
  const float* input = (const float*)d_in[0];
  const float* color = (const float*)d_in[1];
  const float* Wq = (const float*)d_in[2];
  const float* Wk = (const float*)d_in[3];
  const float* Wv = (const float*)d_in[4];
  const float* Wo = (const float*)d_in[5];
  float* out = (float*)d_out;
  char* ws = (char*)d_ws;

  const size_t OFF_G = 0;                        // 3*8*192*192*4 = 3538944
  const size_t OFF_APRE = 3538944;               // 8*192*192*4  = 1179648
  const size_t OFF_NQK = OFF_APRE + 1179648;     // 2*8*192*4    = 12288
  const size_t OFF_ATT = OFF_NQK + 12288;        // 8*8*24*24*4  = 147456
  const size_t OFF_WVT = OFF_ATT + 147456;       // 192*192*2    = 73728
  const size_t OFF_PBF = OFF_WVT + 73728;        // 8*192*192*2  = 589824
  const size_t OFF_PART = OFF_PBF + 589824;      // npart*8*3*192*192*4

  float* G = (float*)(ws + OFF_G);
  float* A_pre = (float*)(ws + OFF_APRE);
  float* nqk = (float*)(ws + OFF_NQK);
  float* attnw = (float*)(ws + OFF_ATT);
  unsigned short* WvT = (unsigned short*)(ws + OFF_WVT);
  unsigned short* Pbf = (unsigned short*)(ws + OFF_PBF);
  float* part = (float*)(ws + OFF_PART);

  // choose partial count from available workspace (deterministic per run)
  int npart = 32;
  while (npart > 2 && OFF_PART + (size_t)npart * NB * 3 * GSZ * 4 > ws_size) npart >>= 1;
  const int cpb = 256 / npart;

  // Z (bf16, swizzled tiles) lives in d_out as scratch; kD overwrites it last.
  char* zbf = (char*)d_out;

  convert_k<<<dim3(257, NB), dim3(256), 0, stream>>>(input, color, Wv, WvT, zbf);
  gram2_k<<<dim3(npart, NB), dim3(512), 0, stream>>>(zbf, part, npart, cpb);
  reduce_k<<<dim3(NB, 3), dim3(256), 0, stream>>>(part, G, npart);
  mirror_k<<<dim3(NB, 2), dim3(256), 0, stream>>>(G);
  k2a<<<dim3(NB, 3), dim3(256), 0, stream>>>(G, Wq, Wk, A_pre, nqk);
  k2b<<<dim3(NB), dim3(256), 0, stream>>>(A_pre, nqk, attnw);
  k3<<<dim3(NB), dim3(256), 0, stream>>>(attnw, Wo, WvT, Pbf);
  kD<<<dim3(HW / 128, NB), dim3(256), 0, stream>>>(Pbf, input, out);
}

// Round 6
// 472.986 us; speedup vs baseline: 1.8229x; 1.8229x over previous
//
#include <hip/hip_runtime.h>
#include <hip/hip_bf16.h>

// Color_Attention: transposed (channel) attention.
//   Z = [I; C] (384 x 16384 bf16, per batch, tiled+swizzled, stored in d_out as scratch)
//   Z*Z^T upper triangle = { G_ii, G_ic, G_cc }  (one symmetric gram kernel, partials)
//   reduce_k sums partials -> G; mirror_k fills lower triangles
//   A_pre = Wq*G_ci*Wk^T ; nq = diag(Wq*G_cc*Wq^T); nk = diag(Wk*G_ii*Wk^T)
//   attn = softmax over head-diagonal 24x24 blocks of A_pre/(nq*nk)
//   P = Wo * blockdiag(attn) * Wv ; out = P @ input

typedef __attribute__((ext_vector_type(4))) float f32x4;
typedef __attribute__((ext_vector_type(8))) short short8;

#define MFMA16(a, b, c) __builtin_amdgcn_mfma_f32_16x16x32_bf16((a), (b), (c), 0, 0, 0)

__device__ __forceinline__ unsigned int pack_rne(float a, float b) {
  unsigned int ua = __float_as_uint(a), ub = __float_as_uint(b);
  ua += 0x7fffu + ((ua >> 16) & 1u);
  ub += 0x7fffu + ((ub >> 16) & 1u);
  return (ua >> 16) | (ub & 0xffff0000u);
}
__device__ __forceinline__ unsigned short bf16u_rne(float x) {
  unsigned int u = __float_as_uint(x);
  u += 0x7fffu + ((u >> 16) & 1u);
  return (unsigned short)(u >> 16);
}
union S8U { short8 s; unsigned int u[4]; };
__device__ __forceinline__ short8 load_cvt8(const float* p) {
  f32x4 x = *(const f32x4*)p;
  f32x4 y = *(const f32x4*)(p + 4);
  S8U r;
  r.u[0] = pack_rne(x[0], x[1]);
  r.u[1] = pack_rne(x[2], x[3]);
  r.u[2] = pack_rne(y[0], y[1]);
  r.u[3] = pack_rne(y[2], y[3]);
  return r.s;
}

#define HW 16384
#define CDIM 192
#define NB 8
#define TILE_B 49152  // 384 rows * 128 B
#define GSZ (CDIM * CDIM)

// ---------------- Kernel A: convert fp32 -> swizzled bf16 Z tiles ------------
__global__ __launch_bounds__(256) void convert_k(const float* __restrict__ input,
                                                 const float* __restrict__ color,
                                                 const float* __restrict__ Wv,
                                                 unsigned short* __restrict__ WvT,
                                                 char* __restrict__ zbf) {
  const int kc = blockIdx.x, b = blockIdx.y;
  const int t = threadIdx.x;
  if (kc == 256) {
    if (b == 0) {
      for (int idx = t; idx < CDIM * CDIM; idx += 256) {
        int j = idx / CDIM, cp = idx % CDIM;
        WvT[idx] = bf16u_rne(Wv[(size_t)cp * CDIM + j]);
      }
    }
    return;
  }
  char* zt = zbf + ((size_t)b * 256 + kc) * TILE_B;
  const int srow = t >> 4;             // 0..15
  const int c4 = (t & 15) * 4;         // f32 col
  const int cb = c4 * 2;               // byte col
  const int sw = (srow & 7) << 4;
  const float* ib = input + (size_t)b * CDIM * HW + (size_t)kc * 64 + c4;
  const float* cp = color + (size_t)b * CDIM * HW + (size_t)kc * 64 + c4;
#pragma unroll
  for (int r = 0; r < 12; ++r) {
    const int row = r * 16 + srow;
    f32x4 v = *(const f32x4*)(ib + (size_t)row * HW);
    unsigned long long p0 = (unsigned long long)pack_rne(v[0], v[1]) |
                            ((unsigned long long)pack_rne(v[2], v[3]) << 32);
    *(unsigned long long*)(zt + row * 128 + (cb ^ sw)) = p0;
    f32x4 w = *(const f32x4*)(cp + (size_t)row * HW);
    unsigned long long p1 = (unsigned long long)pack_rne(w[0], w[1]) |
                            ((unsigned long long)pack_rne(w[2], w[3]) << 32);
    *(unsigned long long*)(zt + (192 + row) * 128 + (cb ^ sw)) = p1;
  }
}

// ---------------- Kernel B: gram Z*Z^T (upper triangle), partial stores ------
__device__ __forceinline__ short8 zfrag(const char* buf, int row, int ks, int lg) {
  return *(const short8*)(buf + row * 128 + ((ks * 64 + lg * 16) ^ ((row & 7) << 4)));
}

__device__ __forceinline__ void stage48(const char* gsrc, char* ldst, int wave, int lane) {
#pragma unroll
  for (int i = 0; i < 6; ++i) {
    const int off = (wave * 6 + i) * 1024;
    __builtin_amdgcn_global_load_lds(
        (const __attribute__((address_space(1))) void*)(gsrc + off + lane * 16),
        (__attribute__((address_space(3))) void*)(ldst + off), 16, 0, 0);
  }
}

// waves 0..3: G_ic = I*C^T. A row-tiles 3w..3w+2 (I), B col-tiles 0..11 (C).
__device__ __forceinline__ void gic_step(const char* buf, int w, f32x4 (&acc)[39],
                                         int l15, int lg) {
#pragma unroll
  for (int ks = 0; ks < 2; ++ks) {
    short8 a[3];
#pragma unroll
    for (int tt = 0; tt < 3; ++tt) a[tt] = zfrag(buf, (w * 3 + tt) * 16 + l15, ks, lg);
#pragma unroll
    for (int tj = 0; tj < 12; ++tj) {
      short8 bf = zfrag(buf, 192 + tj * 16 + l15, ks, lg);
#pragma unroll
      for (int tt = 0; tt < 3; ++tt) acc[tt * 12 + tj] = MFMA16(a[tt], bf, acc[tt * 12 + tj]);
    }
  }
}

// sym waves: pairs (R,11-R) for R in {R0,R1,R2}; 13 tiles per pair.
template <int R0, int R1, int R2>
__device__ __forceinline__ void sym_step(const char* buf, int zbase, f32x4 (&acc)[39],
                                         int l15, int lg) {
#pragma unroll
  for (int ks = 0; ks < 2; ++ks) {
    short8 bfr[12];
#pragma unroll
    for (int tj = R0; tj < 12; ++tj) bfr[tj] = zfrag(buf, zbase + tj * 16 + l15, ks, lg);
#pragma unroll
    for (int p = 0; p < 3; ++p) {
      const int R = (p == 0) ? R0 : ((p == 1) ? R1 : R2);
      short8 aT = zfrag(buf, zbase + R * 16 + l15, ks, lg);
      short8 aB = zfrag(buf, zbase + (11 - R) * 16 + l15, ks, lg);
#pragma unroll
      for (int tj = 0; tj < 12; ++tj) {
        if (tj >= R) acc[p * 13 + (tj - R)] = MFMA16(aT, bfr[tj], acc[p * 13 + (tj - R)]);
        if (tj >= 11 - R) {
          const int s = p * 13 + (12 - R) + (tj - (11 - R));
          acc[s] = MFMA16(aB, bfr[tj], acc[s]);
        }
      }
    }
  }
}

// store upper-triangle tiles to the partial buffer (regular stores, no atomics)
template <int R0, int R1, int R2>
__device__ __forceinline__ void flush_sym_part(float* __restrict__ Ps, f32x4 (&acc)[39],
                                               int l15, int lg) {
#pragma unroll
  for (int p = 0; p < 3; ++p) {
    const int R = (p == 0) ? R0 : ((p == 1) ? R1 : R2);
#pragma unroll
    for (int tj = 0; tj < 12; ++tj) {
      if (tj >= R) {
        const f32x4 v = acc[p * 13 + (tj - R)];
        const int m0 = R * 16 + lg * 4, n = tj * 16 + l15;
#pragma unroll
        for (int r = 0; r < 4; ++r) Ps[(size_t)(m0 + r) * CDIM + n] = v[r];
      }
      if (tj >= 11 - R) {
        const f32x4 v = acc[p * 13 + (12 - R) + (tj - (11 - R))];
        const int m0 = (11 - R) * 16 + lg * 4, n = tj * 16 + l15;
#pragma unroll
        for (int r = 0; r < 4; ++r) Ps[(size_t)(m0 + r) * CDIM + n] = v[r];
      }
    }
  }
}

// grid (NPART, 8), 512 threads, 8 waves, LDS 2x48KB double buffer.
__global__ __launch_bounds__(512, 1) void gram2_k(const char* __restrict__ zbf,
                                                  float* __restrict__ part,
                                                  int npart, int cpb) {
  __shared__ __align__(16) char lds[2][TILE_B];
  const int tid = threadIdx.x, wave = tid >> 6, lane = tid & 63;
  const int l15 = lane & 15, lg = (lane >> 4) & 3;
  const int strip = blockIdx.x, b = blockIdx.y;
  const char* ztb = zbf + ((size_t)b * 256 + (size_t)strip * cpb) * TILE_B;

  f32x4 acc[39];
#pragma unroll
  for (int i = 0; i < 39; ++i) acc[i] = (f32x4){0.f, 0.f, 0.f, 0.f};

  stage48(ztb, lds[0], wave, lane);
#pragma unroll 1
  for (int c = 0; c < cpb - 1; ++c) {
    stage48(ztb + (size_t)(c + 1) * TILE_B, lds[(c + 1) & 1], wave, lane);
    asm volatile("s_waitcnt vmcnt(6)" ::: "memory");
    __builtin_amdgcn_sched_barrier(0);
    __builtin_amdgcn_s_barrier();
    const char* buf = lds[c & 1];
    if (wave < 4) gic_step(buf, wave, acc, l15, lg);
    else if (wave == 4) sym_step<0, 1, 2>(buf, 192, acc, l15, lg);
    else if (wave == 5) sym_step<3, 4, 5>(buf, 192, acc, l15, lg);
    else if (wave == 6) sym_step<0, 1, 2>(buf, 0, acc, l15, lg);
    else sym_step<3, 4, 5>(buf, 0, acc, l15, lg);
    asm volatile("s_waitcnt lgkmcnt(0)" ::: "memory");
    __builtin_amdgcn_sched_barrier(0);
    __builtin_amdgcn_s_barrier();
  }
  asm volatile("s_waitcnt vmcnt(0)" ::: "memory");
  __builtin_amdgcn_sched_barrier(0);
  __builtin_amdgcn_s_barrier();
  {
    const char* buf = lds[(cpb - 1) & 1];
    if (wave < 4) gic_step(buf, wave, acc, l15, lg);
    else if (wave == 4) sym_step<0, 1, 2>(buf, 192, acc, l15, lg);
    else if (wave == 5) sym_step<3, 4, 5>(buf, 192, acc, l15, lg);
    else if (wave == 6) sym_step<0, 1, 2>(buf, 0, acc, l15, lg);
    else sym_step<3, 4, 5>(buf, 0, acc, l15, lg);
  }

  float* pbase = part + ((size_t)(b * npart + strip) * 3) * GSZ;
  if (wave < 4) {
    float* P0 = pbase;  // t=0: G_ic, full matrix
#pragma unroll
    for (int tt = 0; tt < 3; ++tt) {
      const int m0 = (wave * 3 + tt) * 16 + lg * 4;
#pragma unroll
      for (int tj = 0; tj < 12; ++tj) {
        const int n = tj * 16 + l15;
        const f32x4 v = acc[tt * 12 + tj];
#pragma unroll
        for (int r = 0; r < 4; ++r) P0[(size_t)(m0 + r) * CDIM + n] = v[r];
      }
    }
  } else {
    float* Ps = pbase + (size_t)((wave < 6) ? 1 : 2) * GSZ;
    if (wave == 4 || wave == 6) flush_sym_part<0, 1, 2>(Ps, acc, l15, lg);
    else flush_sym_part<3, 4, 5>(Ps, acc, l15, lg);
  }
}

// ---------------- reduce partials -> G (upper tiles for sym types) ----------
// grid (36, NB, 3), 256 threads; one f32x4 output per thread; NP fully unrolled.
template <int NP>
__global__ __launch_bounds__(256) void reduce_k(const float* __restrict__ part,
                                                float* __restrict__ G) {
  const int b = blockIdx.y, t = blockIdx.z;
  const int i = blockIdx.x * 256 + threadIdx.x;  // f32x4 index within GSZ
  const int m = i / 48, n4 = (i % 48) * 4;
  if (t != 0 && (m >> 4) > (n4 >> 4)) return;  // lower tile: mirror_k fills
  const float* p = part + ((size_t)b * NP * 3 + t) * GSZ + (size_t)m * CDIM + n4;
  f32x4 v[NP];
#pragma unroll
  for (int s = 0; s < NP; ++s) v[s] = *(const f32x4*)(p + (size_t)s * 3 * GSZ);
  f32x4 sum = v[0];
#pragma unroll
  for (int s = 1; s < NP; ++s) {
    sum[0] += v[s][0]; sum[1] += v[s][1]; sum[2] += v[s][2]; sum[3] += v[s][3];
  }
  float* Gm = G + ((size_t)t * NB + b) * GSZ;
  *(f32x4*)(Gm + (size_t)m * CDIM + n4) = sum;
}

// mirror lower triangle of symmetric grams (types 1,2)
__global__ void mirror_k(float* __restrict__ G) {
  float* Gm = G + ((size_t)(1 + blockIdx.y) * NB + blockIdx.x) * GSZ;
  for (int i = threadIdx.x; i < GSZ; i += 256) {
    const int m = i / CDIM, n = i - m * CDIM;
    if (m > n) Gm[i] = Gm[(size_t)n * CDIM + m];
  }
}

// ---------------- Kernel 2a: A_pre (type0), nq (type1), nk (type2) ----------
__global__ __launch_bounds__(256) void k2a(const float* __restrict__ G,
                                           const float* __restrict__ Wq,
                                           const float* __restrict__ Wk,
                                           float* __restrict__ A_pre,
                                           float* __restrict__ nqk) {
  const int b = blockIdx.x, type = blockIdx.y;
  __shared__ __align__(16) unsigned short Hs[192][200];
  const int tid = threadIdx.x, wave = tid >> 6, lane = tid & 63;
  const int l15 = lane & 15, lg = lane >> 4, row0 = wave * 48;
  const float* W1 = (type == 2) ? Wk : Wq;
  const float* Gm = G + ((size_t)type * NB + b) * GSZ;

  f32x4 acc[3][12];
#pragma unroll
  for (int t = 0; t < 3; t++)
#pragma unroll
    for (int j = 0; j < 12; j++) acc[t][j] = (f32x4){0.f, 0.f, 0.f, 0.f};

  for (int ks = 0; ks < 192; ks += 32) {
    short8 afr[3];
#pragma unroll
    for (int t = 0; t < 3; t++)
      afr[t] = load_cvt8(W1 + (size_t)(row0 + t * 16 + l15) * CDIM + ks + lg * 8);
#pragma unroll
    for (int tj = 0; tj < 12; tj++) {
      short8 bfr = load_cvt8(Gm + (size_t)(tj * 16 + l15) * CDIM + ks + lg * 8);
#pragma unroll
      for (int t = 0; t < 3; t++) acc[t][tj] = MFMA16(afr[t], bfr, acc[t][tj]);
    }
  }
#pragma unroll
  for (int t = 0; t < 3; t++)
#pragma unroll
    for (int tj = 0; tj < 12; tj++)
#pragma unroll
      for (int r = 0; r < 4; r++)
        Hs[row0 + t * 16 + lg * 4 + r][tj * 16 + l15] = bf16u_rne(acc[t][tj][r]);
  __syncthreads();

  if (type == 0) {
    f32x4 a2[3][12];
#pragma unroll
    for (int t = 0; t < 3; t++)
#pragma unroll
      for (int j = 0; j < 12; j++) a2[t][j] = (f32x4){0.f, 0.f, 0.f, 0.f};
    for (int ks = 0; ks < 192; ks += 32) {
      short8 afr[3];
#pragma unroll
      for (int t = 0; t < 3; t++)
        afr[t] = *(const short8*)&Hs[row0 + t * 16 + l15][ks + lg * 8];
#pragma unroll
      for (int tj = 0; tj < 12; tj++) {
        short8 bfr = load_cvt8(Wk + (size_t)(tj * 16 + l15) * CDIM + ks + lg * 8);
#pragma unroll
        for (int t = 0; t < 3; t++) a2[t][tj] = MFMA16(afr[t], bfr, a2[t][tj]);
      }
    }
    float* Ab = A_pre + (size_t)b * GSZ;
#pragma unroll
    for (int t = 0; t < 3; t++)
#pragma unroll
      for (int tj = 0; tj < 12; tj++)
#pragma unroll
        for (int r = 0; r < 4; r++)
          Ab[(size_t)(row0 + t * 16 + lg * 4 + r) * CDIM + tj * 16 + l15] = a2[t][tj][r];
  } else {
    f32x4 a2[3];
#pragma unroll
    for (int t = 0; t < 3; t++) a2[t] = (f32x4){0.f, 0.f, 0.f, 0.f};
    for (int ks = 0; ks < 192; ks += 32) {
#pragma unroll
      for (int t = 0; t < 3; t++) {
        short8 afr = *(const short8*)&Hs[row0 + t * 16 + l15][ks + lg * 8];
        short8 bfr = load_cvt8(W1 + (size_t)(row0 + t * 16 + l15) * CDIM + ks + lg * 8);
        a2[t] = MFMA16(afr, bfr, a2[t]);
      }
    }
    float* dst = nqk + ((size_t)(type - 1) * NB + b) * CDIM;
#pragma unroll
    for (int t = 0; t < 3; t++)
#pragma unroll
      for (int r = 0; r < 4; r++)
        if (lg * 4 + r == l15) dst[row0 + t * 16 + l15] = a2[t][r];
  }
}

// ---------------- Kernel 2b: per-head softmax ----------------
__global__ void k2b(const float* __restrict__ A_pre, const float* __restrict__ nqk,
                    float* __restrict__ attnw) {
  const int b = blockIdx.x, tid = threadIdx.x;
  const int h = tid >> 5, r = tid & 31;
  if (r >= 24) return;
  const float* Ab = A_pre + (size_t)b * GSZ;
  const float* nq = nqk + (size_t)b * CDIM;
  const float* nk = nqk + (size_t)(NB + b) * CDIM;
  const int c = h * 24 + r;
  const float qn = rsqrtf(fmaxf(nq[c], 1e-24f));
  float e[24];
  float mx = -1e30f;
#pragma unroll
  for (int d = 0; d < 24; d++) {
    float kn = rsqrtf(fmaxf(nk[h * 24 + d], 1e-24f));
    float l = Ab[(size_t)c * CDIM + h * 24 + d] * qn * kn;
    e[d] = l;
    mx = fmaxf(mx, l);
  }
  float s = 0.f;
#pragma unroll
  for (int d = 0; d < 24; d++) {
    float x = __expf(e[d] - mx);
    e[d] = x;
    s += x;
  }
  const float inv = 1.0f / s;
  float* dst = attnw + (((size_t)b * NB + h) * 24 + r) * 24;
#pragma unroll
  for (int d = 0; d < 24; d++) dst[d] = e[d] * inv;
}

// ---------------- Kernel 3: P = Wo * blockdiag(attn) * Wv  (bf16 out) -------
__global__ __launch_bounds__(256) void k3(const float* __restrict__ attnw,
                                          const float* __restrict__ Wo,
                                          const unsigned short* __restrict__ WvT,
                                          unsigned short* __restrict__ Pbf) {
  const int b = blockIdx.x;
  __shared__ __align__(16) unsigned short AT[192][200];
  __shared__ __align__(16) unsigned short Ms[192][200];
  const int tid = threadIdx.x, wave = tid >> 6, lane = tid & 63;
  const int l15 = lane & 15, lg = lane >> 4, row0 = wave * 48;

  unsigned int* ATu = (unsigned int*)&AT[0][0];
  for (int i = tid; i < 192 * 100; i += 256) ATu[i] = 0u;
  __syncthreads();
  const float* at = attnw + (size_t)b * NB * 24 * 24;
  for (int i = tid; i < 4608; i += 256) {
    int h = i / 576, rem = i % 576, c = rem / 24, d = rem % 24;
    AT[h * 24 + d][h * 24 + c] = bf16u_rne(at[(h * 24 + c) * 24 + d]);
  }
  __syncthreads();

  f32x4 acc[3][12];
#pragma unroll
  for (int t = 0; t < 3; t++)
#pragma unroll
    for (int j = 0; j < 12; j++) acc[t][j] = (f32x4){0.f, 0.f, 0.f, 0.f};
  for (int ks = 0; ks < 192; ks += 32) {
    short8 afr[3];
#pragma unroll
    for (int t = 0; t < 3; t++)
      afr[t] = load_cvt8(Wo + (size_t)(row0 + t * 16 + l15) * CDIM + ks + lg * 8);
#pragma unroll
    for (int tj = 0; tj < 12; tj++) {
      short8 bfr = *(const short8*)&AT[tj * 16 + l15][ks + lg * 8];
#pragma unroll
      for (int t = 0; t < 3; t++) acc[t][tj] = MFMA16(afr[t], bfr, acc[t][tj]);
    }
  }
#pragma unroll
  for (int t = 0; t < 3; t++)
#pragma unroll
    for (int tj = 0; tj < 12; tj++)
#pragma unroll
      for (int r = 0; r < 4; r++)
        Ms[row0 + t * 16 + lg * 4 + r][tj * 16 + l15] = bf16u_rne(acc[t][tj][r]);
  __syncthreads();

  f32x4 a2[3][12];
#pragma unroll
  for (int t = 0; t < 3; t++)
#pragma unroll
    for (int j = 0; j < 12; j++) a2[t][j] = (f32x4){0.f, 0.f, 0.f, 0.f};
  for (int ks = 0; ks < 192; ks += 32) {
    short8 afr[3];
#pragma unroll
    for (int t = 0; t < 3; t++)
      afr[t] = *(const short8*)&Ms[row0 + t * 16 + l15][ks + lg * 8];
#pragma unroll
    for (int tj = 0; tj < 12; tj++) {
      short8 bfr = *(const short8*)(WvT + (size_t)(tj * 16 + l15) * CDIM + ks + lg * 8);
#pragma unroll
      for (int t = 0; t < 3; t++) a2[t][tj] = MFMA16(afr[t], bfr, a2[t][tj]);
    }
  }
  unsigned short* Pb = Pbf + (size_t)b * GSZ;
#pragma unroll
  for (int t = 0; t < 3; t++)
#pragma unroll
    for (int tj = 0; tj < 12; tj++)
#pragma unroll
      for (int r = 0; r < 4; r++)
        Pb[(size_t)(row0 + t * 16 + lg * 4 + r) * CDIM + tj * 16 + l15] = bf16u_rne(a2[t][tj][r]);
}

// ---------------- Kernel D: out = P @ input  ----------------
__global__ __launch_bounds__(256) void kD(const unsigned short* __restrict__ Pbf,
                                          const float* __restrict__ input,
                                          float* __restrict__ out) {
  const int nchunk = blockIdx.x, b = blockIdx.y;
  const int n0 = nchunk * 128;
  __shared__ __align__(16) char BsT[128 * 384];
  const int tid = threadIdx.x, wave = tid >> 6, lane = tid & 63;
  const int l15 = lane & 15, lg = lane >> 4, row0 = wave * 48;

  {
    const int n4 = (tid & 31) * 4;
    const int kb0 = (tid >> 5) * 4;
    const float* src = input + (size_t)b * CDIM * HW + n0 + n4;
#pragma unroll
    for (int rnd = 0; rnd < 6; ++rnd) {
      const int kb = kb0 + rnd * 32;
      f32x4 v0 = *(const f32x4*)(src + (size_t)(kb + 0) * HW);
      f32x4 v1 = *(const f32x4*)(src + (size_t)(kb + 1) * HW);
      f32x4 v2 = *(const f32x4*)(src + (size_t)(kb + 2) * HW);
      f32x4 v3 = *(const f32x4*)(src + (size_t)(kb + 3) * HW);
#pragma unroll
      for (int i = 0; i < 4; ++i) {
        const int n = n4 + i;
        unsigned long long pk = (unsigned long long)pack_rne(v0[i], v1[i]) |
                                ((unsigned long long)pack_rne(v2[i], v3[i]) << 32);
        *(unsigned long long*)(BsT + n * 384 + ((kb * 2) ^ ((n & 7) << 4))) = pk;
      }
    }
  }
  __syncthreads();

  f32x4 acc[3][8];
#pragma unroll
  for (int t = 0; t < 3; t++)
#pragma unroll
    for (int j = 0; j < 8; j++) acc[t][j] = (f32x4){0.f, 0.f, 0.f, 0.f};

  const unsigned short* Pb = Pbf + (size_t)b * GSZ;
#pragma unroll 2
  for (int ks = 0; ks < 6; ks++) {
    short8 afr[3];
#pragma unroll
    for (int t = 0; t < 3; t++)
      afr[t] = *(const short8*)(Pb + (size_t)(row0 + t * 16 + l15) * CDIM + ks * 32 + lg * 8);
#pragma unroll
    for (int tn = 0; tn < 8; tn++) {
      const int n = tn * 16 + l15;
      short8 bfr = *(const short8*)(BsT + n * 384 + ((ks * 64 + lg * 16) ^ ((n & 7) << 4)));
#pragma unroll
      for (int t = 0; t < 3; t++) acc[t][tn] = MFMA16(afr[t], bfr, acc[t][tn]);
    }
  }
  float* ob = out + (size_t)b * CDIM * HW + n0;
#pragma unroll
  for (int t = 0; t < 3; t++)
#pragma unroll
    for (int tn = 0; tn < 8; tn++)
#pragma unroll
      for (int r = 0; r < 4; r++) {
        const int m = row0 + t * 16 + lg * 4 + r;
        ob[(size_t)m * HW + tn * 16 + l15] = acc[t][tn][r];
      }
}

// ---------------- launch ----------------
extern "C" void kernel_launch(void* const* d_in, const int* in_sizes, int n_in,
                              void* d_out, int out_size, void* d_ws, size_t ws_size,
                              hipStream_t stream) {
  const float* input = (const float*)d_in[0];
  const float* color = (const float*)d_in[1];
  const float* Wq = (const float*)d_in[2];
  const float* Wk = (const float*)d_in[3];
  const float* Wv = (const float*)d_in[4];
  const float* Wo = (const float*)d_in[5];
  float* out = (float*)d_out;
  char* ws = (char*)d_ws;

  const size_t OFF_G = 0;                        // 3*8*192*192*4 = 3538944
  const size_t OFF_APRE = 3538944;               // 8*192*192*4  = 1179648
  const size_t OFF_NQK = OFF_APRE + 1179648;     // 2*8*192*4    = 12288
  const size_t OFF_ATT = OFF_NQK + 12288;        // 8*8*24*24*4  = 147456
  const size_t OFF_WVT = OFF_ATT + 147456;       // 192*192*2    = 73728
  const size_t OFF_PBF = OFF_WVT + 73728;        // 8*192*192*2  = 589824
  const size_t OFF_PART = OFF_PBF + 589824;      // npart*8*3*192*192*4

  float* G = (float*)(ws + OFF_G);
  float* A_pre = (float*)(ws + OFF_APRE);
  float* nqk = (float*)(ws + OFF_NQK);
  float* attnw = (float*)(ws + OFF_ATT);
  unsigned short* WvT = (unsigned short*)(ws + OFF_WVT);
  unsigned short* Pbf = (unsigned short*)(ws + OFF_PBF);
  float* part = (float*)(ws + OFF_PART);

  // choose partial count from available workspace (deterministic per run)
  int npart = 32;
  while (npart > 2 && OFF_PART + (size_t)npart * NB * 3 * GSZ * 4 > ws_size) npart >>= 1;
  const int cpb = 256 / npart;

  // Z (bf16, swizzled tiles) lives in d_out as scratch; kD overwrites it last.
  char* zbf = (char*)d_out;

  convert_k<<<dim3(257, NB), dim3(256), 0, stream>>>(input, color, Wv, WvT, zbf);
  gram2_k<<<dim3(npart, NB), dim3(512), 0, stream>>>(zbf, part, npart, cpb);
  switch (npart) {
    case 32: reduce_k<32><<<dim3(36, NB, 3), dim3(256), 0, stream>>>(part, G); break;
    case 16: reduce_k<16><<<dim3(36, NB, 3), dim3(256), 0, stream>>>(part, G); break;
    case 8:  reduce_k<8><<<dim3(36, NB, 3), dim3(256), 0, stream>>>(part, G); break;
    case 4:  reduce_k<4><<<dim3(36, NB, 3), dim3(256), 0, stream>>>(part, G); break;
    default: reduce_k<2><<<dim3(36, NB, 3), dim3(256), 0, stream>>>(part, G); break;
  }
  mirror_k<<<dim3(NB, 2), dim3(256), 0, stream>>>(G);
  k2a<<<dim3(NB, 3), dim3(256), 0, stream>>>(G, Wq, Wk, A_pre, nqk);
  k2b<<<dim3(NB), dim3(256), 0, stream>>>(A_pre, nqk, attnw);
  k3<<<dim3(NB), dim3(256), 0, stream>>>(attnw, Wo, WvT, Pbf);
  kD<<<dim3(HW / 128, NB), dim3(256), 0, stream>>>(Pbf, input, out);
}

// Round 7
// 453.894 us; speedup vs baseline: 1.8996x; 1.0421x over previous
//
#include <hip/hip_runtime.h>
#include <hip/hip_bf16.h>

// Color_Attention: transposed (channel) attention.
//   Z = [I; C] (384 x 16384 bf16, per batch, tiled+swizzled, stored in d_out as scratch)
//   Z*Z^T upper triangle = { G_ii, G_ic, G_cc }  (one symmetric gram kernel, partials)
//   reduce_k sums blocked partials -> G (writes both triangles)
//   A_pre = Wq*G_ci*Wk^T ; nq = diag(Wq*G_cc*Wq^T); nk = diag(Wk*G_ii*Wk^T)
//   attn = softmax over head-diagonal 24x24 blocks of A_pre/(nq*nk)
//   P = Wo * blockdiag(attn) * Wv ; out = P @ input

typedef __attribute__((ext_vector_type(4))) float f32x4;
typedef __attribute__((ext_vector_type(8))) short short8;

#define MFMA16(a, b, c) __builtin_amdgcn_mfma_f32_16x16x32_bf16((a), (b), (c), 0, 0, 0)

__device__ __forceinline__ unsigned int pack_rne(float a, float b) {
  unsigned int ua = __float_as_uint(a), ub = __float_as_uint(b);
  ua += 0x7fffu + ((ua >> 16) & 1u);
  ub += 0x7fffu + ((ub >> 16) & 1u);
  return (ua >> 16) | (ub & 0xffff0000u);
}
__device__ __forceinline__ unsigned short bf16u_rne(float x) {
  unsigned int u = __float_as_uint(x);
  u += 0x7fffu + ((u >> 16) & 1u);
  return (unsigned short)(u >> 16);
}
union S8U { short8 s; unsigned int u[4]; };
__device__ __forceinline__ short8 load_cvt8(const float* p) {
  f32x4 x = *(const f32x4*)p;
  f32x4 y = *(const f32x4*)(p + 4);
  S8U r;
  r.u[0] = pack_rne(x[0], x[1]);
  r.u[1] = pack_rne(x[2], x[3]);
  r.u[2] = pack_rne(y[0], y[1]);
  r.u[3] = pack_rne(y[2], y[3]);
  return r.s;
}

#define HW 16384
#define CDIM 192
#define NB 8
#define TILE_B 49152  // 384 rows * 128 B
#define GSZ (CDIM * CDIM)
#define NTILE 300     // blocked partial records per (b,strip): 144 G_ic + 4*39 sym

// ---------------- Kernel A: convert fp32 -> swizzled bf16 Z tiles ------------
__global__ __launch_bounds__(256) void convert_k(const float* __restrict__ input,
                                                 const float* __restrict__ color,
                                                 const float* __restrict__ Wv,
                                                 unsigned short* __restrict__ WvT,
                                                 char* __restrict__ zbf) {
  const int kc = blockIdx.x, b = blockIdx.y;
  const int t = threadIdx.x;
  if (kc == 256) {
    if (b == 0) {
      for (int idx = t; idx < CDIM * CDIM; idx += 256) {
        int j = idx / CDIM, cp = idx % CDIM;
        WvT[idx] = bf16u_rne(Wv[(size_t)cp * CDIM + j]);
      }
    }
    return;
  }
  char* zt = zbf + ((size_t)b * 256 + kc) * TILE_B;
  const int srow = t >> 4;             // 0..15
  const int c4 = (t & 15) * 4;         // f32 col
  const int cb = c4 * 2;               // byte col
  const int sw = (srow & 7) << 4;
  const float* ib = input + (size_t)b * CDIM * HW + (size_t)kc * 64 + c4;
  const float* cp = color + (size_t)b * CDIM * HW + (size_t)kc * 64 + c4;
#pragma unroll
  for (int r = 0; r < 12; ++r) {
    const int row = r * 16 + srow;
    f32x4 v = *(const f32x4*)(ib + (size_t)row * HW);
    unsigned long long p0 = (unsigned long long)pack_rne(v[0], v[1]) |
                            ((unsigned long long)pack_rne(v[2], v[3]) << 32);
    *(unsigned long long*)(zt + row * 128 + (cb ^ sw)) = p0;
    f32x4 w = *(const f32x4*)(cp + (size_t)row * HW);
    unsigned long long p1 = (unsigned long long)pack_rne(w[0], w[1]) |
                            ((unsigned long long)pack_rne(w[2], w[3]) << 32);
    *(unsigned long long*)(zt + (192 + row) * 128 + (cb ^ sw)) = p1;
  }
}

// ---------------- Kernel B: gram Z*Z^T (upper triangle), blocked partials ----
__device__ __forceinline__ short8 zfrag(const char* buf, int row, int ks, int lg) {
  return *(const short8*)(buf + row * 128 + ((ks * 64 + lg * 16) ^ ((row & 7) << 4)));
}

__device__ __forceinline__ void stage48(const char* gsrc, char* ldst, int wave, int lane) {
#pragma unroll
  for (int i = 0; i < 6; ++i) {
    const int off = (wave * 6 + i) * 1024;
    __builtin_amdgcn_global_load_lds(
        (const __attribute__((address_space(1))) void*)(gsrc + off + lane * 16),
        (__attribute__((address_space(3))) void*)(ldst + off), 16, 0, 0);
  }
}

// waves 0..3: G_ic = I*C^T. A row-tiles 3w..3w+2 (I), B col-tiles 0..11 (C).
__device__ __forceinline__ void gic_step(const char* buf, int w, f32x4 (&acc)[39],
                                         int l15, int lg) {
#pragma unroll
  for (int ks = 0; ks < 2; ++ks) {
    short8 a[3];
#pragma unroll
    for (int tt = 0; tt < 3; ++tt) a[tt] = zfrag(buf, (w * 3 + tt) * 16 + l15, ks, lg);
#pragma unroll
    for (int tj = 0; tj < 12; ++tj) {
      short8 bf = zfrag(buf, 192 + tj * 16 + l15, ks, lg);
#pragma unroll
      for (int tt = 0; tt < 3; ++tt) acc[tt * 12 + tj] = MFMA16(a[tt], bf, acc[tt * 12 + tj]);
    }
  }
}

// sym waves: pairs (R,11-R) for R in {R0,R1,R2}; 13 tiles per pair.
// slot layout: p*13 + (tj-R) for row R (tj=R..11); p*13 + (12-R) + (tj-(11-R)) for row 11-R.
template <int R0, int R1, int R2>
__device__ __forceinline__ void sym_step(const char* buf, int zbase, f32x4 (&acc)[39],
                                         int l15, int lg) {
#pragma unroll
  for (int ks = 0; ks < 2; ++ks) {
    short8 bfr[12];
#pragma unroll
    for (int tj = R0; tj < 12; ++tj) bfr[tj] = zfrag(buf, zbase + tj * 16 + l15, ks, lg);
#pragma unroll
    for (int p = 0; p < 3; ++p) {
      const int R = (p == 0) ? R0 : ((p == 1) ? R1 : R2);
      short8 aT = zfrag(buf, zbase + R * 16 + l15, ks, lg);
      short8 aB = zfrag(buf, zbase + (11 - R) * 16 + l15, ks, lg);
#pragma unroll
      for (int tj = 0; tj < 12; ++tj) {
        if (tj >= R) acc[p * 13 + (tj - R)] = MFMA16(aT, bfr[tj], acc[p * 13 + (tj - R)]);
        if (tj >= 11 - R) {
          const int s = p * 13 + (12 - R) + (tj - (11 - R));
          acc[s] = MFMA16(aB, bfr[tj], acc[s]);
        }
      }
    }
  }
}

// grid (NPART, 8), 512 threads, 8 waves, LDS 2x48KB double buffer.
__global__ __launch_bounds__(512, 1) void gram2_k(const char* __restrict__ zbf,
                                                  float* __restrict__ part,
                                                  int npart, int cpb) {
  __shared__ __align__(16) char lds[2][TILE_B];
  const int tid = threadIdx.x, wave = tid >> 6, lane = tid & 63;
  const int l15 = lane & 15, lg = (lane >> 4) & 3;
  const int strip = blockIdx.x, b = blockIdx.y;
  const char* ztb = zbf + ((size_t)b * 256 + (size_t)strip * cpb) * TILE_B;

  f32x4 acc[39];
#pragma unroll
  for (int i = 0; i < 39; ++i) acc[i] = (f32x4){0.f, 0.f, 0.f, 0.f};

  stage48(ztb, lds[0], wave, lane);
#pragma unroll 1
  for (int c = 0; c < cpb - 1; ++c) {
    stage48(ztb + (size_t)(c + 1) * TILE_B, lds[(c + 1) & 1], wave, lane);
    asm volatile("s_waitcnt vmcnt(6)" ::: "memory");
    __builtin_amdgcn_sched_barrier(0);
    __builtin_amdgcn_s_barrier();
    const char* buf = lds[c & 1];
    if (wave < 4) gic_step(buf, wave, acc, l15, lg);
    else if (wave == 4) sym_step<0, 1, 2>(buf, 192, acc, l15, lg);
    else if (wave == 5) sym_step<3, 4, 5>(buf, 192, acc, l15, lg);
    else if (wave == 6) sym_step<0, 1, 2>(buf, 0, acc, l15, lg);
    else sym_step<3, 4, 5>(buf, 0, acc, l15, lg);
    asm volatile("s_waitcnt lgkmcnt(0)" ::: "memory");
    __builtin_amdgcn_sched_barrier(0);
    __builtin_amdgcn_s_barrier();
  }
  asm volatile("s_waitcnt vmcnt(0)" ::: "memory");
  __builtin_amdgcn_sched_barrier(0);
  __builtin_amdgcn_s_barrier();
  {
    const char* buf = lds[(cpb - 1) & 1];
    if (wave < 4) gic_step(buf, wave, acc, l15, lg);
    else if (wave == 4) sym_step<0, 1, 2>(buf, 192, acc, l15, lg);
    else if (wave == 5) sym_step<3, 4, 5>(buf, 192, acc, l15, lg);
    else if (wave == 6) sym_step<0, 1, 2>(buf, 0, acc, l15, lg);
    else sym_step<3, 4, 5>(buf, 0, acc, l15, lg);
  }

  // -------- blocked flush: one contiguous 1KB record per 16x16 tile --------
  float* pbase = part + (size_t)(b * npart + strip) * NTILE * 256;
  if (wave < 4) {
#pragma unroll
    for (int tt = 0; tt < 3; ++tt)
#pragma unroll
      for (int tj = 0; tj < 12; ++tj)
        *(f32x4*)(pbase + ((size_t)(wave * 36 + tt * 12 + tj) * 64 + lane) * 4) =
            acc[tt * 12 + tj];
  } else {
#pragma unroll
    for (int s = 0; s < 39; ++s)
      *(f32x4*)(pbase + ((size_t)(144 + (wave - 4) * 39 + s) * 64 + lane) * 4) = acc[s];
  }
}

// ---------------- reduce blocked partials -> G (both triangles) -------------
// grid (75, NB), 256 threads: 4 tiles per block, NP fully unrolled.
template <int NP>
__global__ __launch_bounds__(256) void reduce_k(const float* __restrict__ part,
                                                float* __restrict__ G) {
  const int b = blockIdx.y;
  const int T = blockIdx.x * 4 + (threadIdx.x >> 6);
  const int lane = threadIdx.x & 63;
  const float* p = part + ((size_t)b * NP * NTILE + T) * 256 + lane * 4;
  f32x4 v[NP];
#pragma unroll
  for (int s = 0; s < NP; ++s) v[s] = *(const f32x4*)(p + (size_t)s * NTILE * 256);
  f32x4 sum = v[0];
#pragma unroll
  for (int s = 1; s < NP; ++s) {
    sum[0] += v[s][0]; sum[1] += v[s][1]; sum[2] += v[s][2]; sum[3] += v[s][3];
  }
  // map record T -> (type, row-tile rt, col-tile ct)
  int type, rt, ct;
  if (T < 144) {
    type = 0;
    const int w = T / 36, rem = T % 36;
    rt = w * 3 + rem / 12;
    ct = rem % 12;
  } else {
    const int idx = T - 144, wg = idx / 39, s = idx % 39;
    type = (wg < 2) ? 1 : 2;
    const int R = ((wg & 1) ? 3 : 0) + s / 13;
    const int q = s % 13;
    if (q <= 11 - R) { rt = R; ct = R + q; }
    else { rt = 11 - R; ct = q - 1; }
  }
  float* Gm = G + ((size_t)type * NB + b) * GSZ;
  const int l15 = lane & 15, lg = lane >> 4;
  const int row0 = rt * 16 + lg * 4, col = ct * 16 + l15;
#pragma unroll
  for (int r = 0; r < 4; ++r) Gm[(size_t)(row0 + r) * CDIM + col] = sum[r];
  if (type != 0 && rt != ct) {
#pragma unroll
    for (int r = 0; r < 4; ++r) Gm[(size_t)col * CDIM + (row0 + r)] = sum[r];
  }
}

// ---------------- Kernel 2a: A_pre (type0), nq (type1), nk (type2) ----------
__global__ __launch_bounds__(256) void k2a(const float* __restrict__ G,
                                           const float* __restrict__ Wq,
                                           const float* __restrict__ Wk,
                                           float* __restrict__ A_pre,
                                           float* __restrict__ nqk) {
  const int b = blockIdx.x, type = blockIdx.y;
  __shared__ __align__(16) unsigned short Hs[192][200];
  const int tid = threadIdx.x, wave = tid >> 6, lane = tid & 63;
  const int l15 = lane & 15, lg = lane >> 4, row0 = wave * 48;
  const float* W1 = (type == 2) ? Wk : Wq;
  const float* Gm = G + ((size_t)type * NB + b) * GSZ;

  f32x4 acc[3][12];
#pragma unroll
  for (int t = 0; t < 3; t++)
#pragma unroll
    for (int j = 0; j < 12; j++) acc[t][j] = (f32x4){0.f, 0.f, 0.f, 0.f};

  for (int ks = 0; ks < 192; ks += 32) {
    short8 afr[3];
#pragma unroll
    for (int t = 0; t < 3; t++)
      afr[t] = load_cvt8(W1 + (size_t)(row0 + t * 16 + l15) * CDIM + ks + lg * 8);
#pragma unroll
    for (int tj = 0; tj < 12; tj++) {
      short8 bfr = load_cvt8(Gm + (size_t)(tj * 16 + l15) * CDIM + ks + lg * 8);
#pragma unroll
      for (int t = 0; t < 3; t++) acc[t][tj] = MFMA16(afr[t], bfr, acc[t][tj]);
    }
  }
#pragma unroll
  for (int t = 0; t < 3; t++)
#pragma unroll
    for (int tj = 0; tj < 12; tj++)
#pragma unroll
      for (int r = 0; r < 4; r++)
        Hs[row0 + t * 16 + lg * 4 + r][tj * 16 + l15] = bf16u_rne(acc[t][tj][r]);
  __syncthreads();

  if (type == 0) {
    f32x4 a2[3][12];
#pragma unroll
    for (int t = 0; t < 3; t++)
#pragma unroll
      for (int j = 0; j < 12; j++) a2[t][j] = (f32x4){0.f, 0.f, 0.f, 0.f};
    for (int ks = 0; ks < 192; ks += 32) {
      short8 afr[3];
#pragma unroll
      for (int t = 0; t < 3; t++)
        afr[t] = *(const short8*)&Hs[row0 + t * 16 + l15][ks + lg * 8];
#pragma unroll
      for (int tj = 0; tj < 12; tj++) {
        short8 bfr = load_cvt8(Wk + (size_t)(tj * 16 + l15) * CDIM + ks + lg * 8);
#pragma unroll
        for (int t = 0; t < 3; t++) a2[t][tj] = MFMA16(afr[t], bfr, a2[t][tj]);
      }
    }
    float* Ab = A_pre + (size_t)b * GSZ;
#pragma unroll
    for (int t = 0; t < 3; t++)
#pragma unroll
      for (int tj = 0; tj < 12; tj++)
#pragma unroll
        for (int r = 0; r < 4; r++)
          Ab[(size_t)(row0 + t * 16 + lg * 4 + r) * CDIM + tj * 16 + l15] = a2[t][tj][r];
  } else {
    f32x4 a2[3];
#pragma unroll
    for (int t = 0; t < 3; t++) a2[t] = (f32x4){0.f, 0.f, 0.f, 0.f};
    for (int ks = 0; ks < 192; ks += 32) {
#pragma unroll
      for (int t = 0; t < 3; t++) {
        short8 afr = *(const short8*)&Hs[row0 + t * 16 + l15][ks + lg * 8];
        short8 bfr = load_cvt8(W1 + (size_t)(row0 + t * 16 + l15) * CDIM + ks + lg * 8);
        a2[t] = MFMA16(afr, bfr, a2[t]);
      }
    }
    float* dst = nqk + ((size_t)(type - 1) * NB + b) * CDIM;
#pragma unroll
    for (int t = 0; t < 3; t++)
#pragma unroll
      for (int r = 0; r < 4; r++)
        if (lg * 4 + r == l15) dst[row0 + t * 16 + l15] = a2[t][r];
  }
}

// ---------------- Kernel 2b: per-head softmax ----------------
__global__ void k2b(const float* __restrict__ A_pre, const float* __restrict__ nqk,
                    float* __restrict__ attnw) {
  const int b = blockIdx.x, tid = threadIdx.x;
  const int h = tid >> 5, r = tid & 31;
  if (r >= 24) return;
  const float* Ab = A_pre + (size_t)b * GSZ;
  const float* nq = nqk + (size_t)b * CDIM;
  const float* nk = nqk + (size_t)(NB + b) * CDIM;
  const int c = h * 24 + r;
  const float qn = rsqrtf(fmaxf(nq[c], 1e-24f));
  float e[24];
  float mx = -1e30f;
#pragma unroll
  for (int d = 0; d < 24; d++) {
    float kn = rsqrtf(fmaxf(nk[h * 24 + d], 1e-24f));
    float l = Ab[(size_t)c * CDIM + h * 24 + d] * qn * kn;
    e[d] = l;
    mx = fmaxf(mx, l);
  }
  float s = 0.f;
#pragma unroll
  for (int d = 0; d < 24; d++) {
    float x = __expf(e[d] - mx);
    e[d] = x;
    s += x;
  }
  const float inv = 1.0f / s;
  float* dst = attnw + (((size_t)b * NB + h) * 24 + r) * 24;
#pragma unroll
  for (int d = 0; d < 24; d++) dst[d] = e[d] * inv;
}

// ---------------- Kernel 3: P = Wo * blockdiag(attn) * Wv  (bf16 out) -------
__global__ __launch_bounds__(256) void k3(const float* __restrict__ attnw,
                                          const float* __restrict__ Wo,
                                          const unsigned short* __restrict__ WvT,
                                          unsigned short* __restrict__ Pbf) {
  const int b = blockIdx.x;
  __shared__ __align__(16) unsigned short AT[192][200];
  __shared__ __align__(16) unsigned short Ms[192][200];
  const int tid = threadIdx.x, wave = tid >> 6, lane = tid & 63;
  const int l15 = lane & 15, lg = lane >> 4, row0 = wave * 48;

  unsigned int* ATu = (unsigned int*)&AT[0][0];
  for (int i = tid; i < 192 * 100; i += 256) ATu[i] = 0u;
  __syncthreads();
  const float* at = attnw + (size_t)b * NB * 24 * 24;
  for (int i = tid; i < 4608; i += 256) {
    int h = i / 576, rem = i % 576, c = rem / 24, d = rem % 24;
    AT[h * 24 + d][h * 24 + c] = bf16u_rne(at[(h * 24 + c) * 24 + d]);
  }
  __syncthreads();

  f32x4 acc[3][12];
#pragma unroll
  for (int t = 0; t < 3; t++)
#pragma unroll
    for (int j = 0; j < 12; j++) acc[t][j] = (f32x4){0.f, 0.f, 0.f, 0.f};
  for (int ks = 0; ks < 192; ks += 32) {
    short8 afr[3];
#pragma unroll
    for (int t = 0; t < 3; t++)
      afr[t] = load_cvt8(Wo + (size_t)(row0 + t * 16 + l15) * CDIM + ks + lg * 8);
#pragma unroll
    for (int tj = 0; tj < 12; tj++) {
      short8 bfr = *(const short8*)&AT[tj * 16 + l15][ks + lg * 8];
#pragma unroll
      for (int t = 0; t < 3; t++) acc[t][tj] = MFMA16(afr[t], bfr, acc[t][tj]);
    }
  }
#pragma unroll
  for (int t = 0; t < 3; t++)
#pragma unroll
    for (int tj = 0; tj < 12; tj++)
#pragma unroll
      for (int r = 0; r < 4; r++)
        Ms[row0 + t * 16 + lg * 4 + r][tj * 16 + l15] = bf16u_rne(acc[t][tj][r]);
  __syncthreads();

  f32x4 a2[3][12];
#pragma unroll
  for (int t = 0; t < 3; t++)
#pragma unroll
    for (int j = 0; j < 12; j++) a2[t][j] = (f32x4){0.f, 0.f, 0.f, 0.f};
  for (int ks = 0; ks < 192; ks += 32) {
    short8 afr[3];
#pragma unroll
    for (int t = 0; t < 3; t++)
      afr[t] = *(const short8*)&Ms[row0 + t * 16 + l15][ks + lg * 8];
#pragma unroll
    for (int tj = 0; tj < 12; tj++) {
      short8 bfr = *(const short8*)(WvT + (size_t)(tj * 16 + l15) * CDIM + ks + lg * 8);
#pragma unroll
      for (int t = 0; t < 3; t++) a2[t][tj] = MFMA16(afr[t], bfr, a2[t][tj]);
    }
  }
  unsigned short* Pb = Pbf + (size_t)b * GSZ;
#pragma unroll
  for (int t = 0; t < 3; t++)
#pragma unroll
    for (int tj = 0; tj < 12; tj++)
#pragma unroll
      for (int r = 0; r < 4; r++)
        Pb[(size_t)(row0 + t * 16 + lg * 4 + r) * CDIM + tj * 16 + l15] = bf16u_rne(a2[t][tj][r]);
}

// ---------------- Kernel D: out = P @ input  ----------------
__global__ __launch_bounds__(256) void kD(const unsigned short* __restrict__ Pbf,
                                          const float* __restrict__ input,
                                          float* __restrict__ out) {
  const int nchunk = blockIdx.x, b = blockIdx.y;
  const int n0 = nchunk * 128;
  __shared__ __align__(16) char BsT[128 * 384];
  const int tid = threadIdx.x, wave = tid >> 6, lane = tid & 63;
  const int l15 = lane & 15, lg = lane >> 4, row0 = wave * 48;

  {
    const int n4 = (tid & 31) * 4;
    const int kb0 = (tid >> 5) * 4;
    const float* src = input + (size_t)b * CDIM * HW + n0 + n4;
#pragma unroll
    for (int rnd = 0; rnd < 6; ++rnd) {
      const int kb = kb0 + rnd * 32;
      f32x4 v0 = *(const f32x4*)(src + (size_t)(kb + 0) * HW);
      f32x4 v1 = *(const f32x4*)(src + (size_t)(kb + 1) * HW);
      f32x4 v2 = *(const f32x4*)(src + (size_t)(kb + 2) * HW);
      f32x4 v3 = *(const f32x4*)(src + (size_t)(kb + 3) * HW);
#pragma unroll
      for (int i = 0; i < 4; ++i) {
        const int n = n4 + i;
        unsigned long long pk = (unsigned long long)pack_rne(v0[i], v1[i]) |
                                ((unsigned long long)pack_rne(v2[i], v3[i]) << 32);
        *(unsigned long long*)(BsT + n * 384 + ((kb * 2) ^ ((n & 7) << 4))) = pk;
      }
    }
  }
  __syncthreads();

  f32x4 acc[3][8];
#pragma unroll
  for (int t = 0; t < 3; t++)
#pragma unroll
    for (int j = 0; j < 8; j++) acc[t][j] = (f32x4){0.f, 0.f, 0.f, 0.f};

  const unsigned short* Pb = Pbf + (size_t)b * GSZ;
#pragma unroll 2
  for (int ks = 0; ks < 6; ks++) {
    short8 afr[3];
#pragma unroll
    for (int t = 0; t < 3; t++)
      afr[t] = *(const short8*)(Pb + (size_t)(row0 + t * 16 + l15) * CDIM + ks * 32 + lg * 8);
#pragma unroll
    for (int tn = 0; tn < 8; tn++) {
      const int n = tn * 16 + l15;
      short8 bfr = *(const short8*)(BsT + n * 384 + ((ks * 64 + lg * 16) ^ ((n & 7) << 4)));
#pragma unroll
      for (int t = 0; t < 3; t++) acc[t][tn] = MFMA16(afr[t], bfr, acc[t][tn]);
    }
  }
  float* ob = out + (size_t)b * CDIM * HW + n0;
#pragma unroll
  for (int t = 0; t < 3; t++)
#pragma unroll
    for (int tn = 0; tn < 8; tn++)
#pragma unroll
      for (int r = 0; r < 4; r++) {
        const int m = row0 + t * 16 + lg * 4 + r;
        ob[(size_t)m * HW + tn * 16 + l15] = acc[t][tn][r];
      }
}

// ---------------- launch ----------------
extern "C" void kernel_launch(void* const* d_in, const int* in_sizes, int n_in,
                              void* d_out, int out_size, void* d_ws, size_t ws_size,
                              hipStream_t stream) {
  const float* input = (const float*)d_in[0];
  const float* color = (const float*)d_in[1];
  const float* Wq = (const float*)d_in[2];
  const float* Wk = (const float*)d_in[3];
  const float* Wv = (const float*)d_in[4];
  const float* Wo = (const float*)d_in[5];
  float* out = (float*)d_out;
  char* ws = (char*)d_ws;

  const size_t OFF_G = 0;                        // 3*8*192*192*4 = 3538944
  const size_t OFF_APRE = 3538944;               // 8*192*192*4  = 1179648
  const size_t OFF_NQK = OFF_APRE + 1179648;     // 2*8*192*4    = 12288
  const size_t OFF_ATT = OFF_NQK + 12288;        // 8*8*24*24*4  = 147456
  const size_t OFF_WVT = OFF_ATT + 147456;       // 192*192*2    = 73728
  const size_t OFF_PBF = OFF_WVT + 73728;        // 8*192*192*2  = 589824
  const size_t OFF_PART = OFF_PBF + 589824;      // npart*8*300*1024

  float* G = (float*)(ws + OFF_G);
  float* A_pre = (float*)(ws + OFF_APRE);
  float* nqk = (float*)(ws + OFF_NQK);
  float* attnw = (float*)(ws + OFF_ATT);
  unsigned short* WvT = (unsigned short*)(ws + OFF_WVT);
  unsigned short* Pbf = (unsigned short*)(ws + OFF_PBF);
  float* part = (float*)(ws + OFF_PART);

  // choose partial count from available workspace (deterministic per run)
  int npart = 32;
  while (npart > 2 && OFF_PART + (size_t)npart * NB * NTILE * 1024 > ws_size) npart >>= 1;
  const int cpb = 256 / npart;

  // Z (bf16, swizzled tiles) lives in d_out as scratch; kD overwrites it last.
  char* zbf = (char*)d_out;

  convert_k<<<dim3(257, NB), dim3(256), 0, stream>>>(input, color, Wv, WvT, zbf);
  gram2_k<<<dim3(npart, NB), dim3(512), 0, stream>>>(zbf, part, npart, cpb);
  switch (npart) {
    case 32: reduce_k<32><<<dim3(75, NB), dim3(256), 0, stream>>>(part, G); break;
    case 16: reduce_k<16><<<dim3(75, NB), dim3(256), 0, stream>>>(part, G); break;
    case 8:  reduce_k<8><<<dim3(75, NB), dim3(256), 0, stream>>>(part, G); break;
    case 4:  reduce_k<4><<<dim3(75, NB), dim3(256), 0, stream>>>(part, G); break;
    default: reduce_k<2><<<dim3(75, NB), dim3(256), 0, stream>>>(part, G); break;
  }
  k2a<<<dim3(NB, 3), dim3(256), 0, stream>>>(G, Wq, Wk, A_pre, nqk);
  k2b<<<dim3(NB), dim3(256), 0, stream>>>(A_pre, nqk, attnw);
  k3<<<dim3(NB), dim3(256), 0, stream>>>(attnw, Wo, WvT, Pbf);
  kD<<<dim3(HW / 128, NB), dim3(256), 0, stream>>>(Pbf, input, out);
}

// Round 8
// 267.051 us; speedup vs baseline: 3.2286x; 1.6997x over previous
//
#include <hip/hip_runtime.h>
#include <hip/hip_bf16.h>

// Color_Attention: transposed (channel) attention.
//   Z = [I; C] (384 x 16384 bf16, per batch, tiled+swizzled, stored in d_out as scratch)
//   Z*Z^T upper triangle (24x24 tiles, 300 tiles) = { G_ii, G_ic, G_cc }
//   gram2_k: 12 waves, wave w owns row-pair (w, 23-w) = 25 tiles = 100 acc VGPRs
//   reduce_k sums blocked partials -> G (writes both triangles)
//   A_pre = Wq*G_ci*Wk^T ; nq = diag(Wq*G_cc*Wq^T); nk = diag(Wk*G_ii*Wk^T)
//   attn = softmax over head-diagonal 24x24 blocks of A_pre/(nq*nk)
//   P = Wo * blockdiag(attn) * Wv ; out = P @ input

typedef __attribute__((ext_vector_type(4))) float f32x4;
typedef __attribute__((ext_vector_type(8))) short short8;

#define MFMA16(a, b, c) __builtin_amdgcn_mfma_f32_16x16x32_bf16((a), (b), (c), 0, 0, 0)

__device__ __forceinline__ unsigned int pack_rne(float a, float b) {
  unsigned int ua = __float_as_uint(a), ub = __float_as_uint(b);
  ua += 0x7fffu + ((ua >> 16) & 1u);
  ub += 0x7fffu + ((ub >> 16) & 1u);
  return (ua >> 16) | (ub & 0xffff0000u);
}
__device__ __forceinline__ unsigned short bf16u_rne(float x) {
  unsigned int u = __float_as_uint(x);
  u += 0x7fffu + ((u >> 16) & 1u);
  return (unsigned short)(u >> 16);
}
union S8U { short8 s; unsigned int u[4]; };
__device__ __forceinline__ short8 load_cvt8(const float* p) {
  f32x4 x = *(const f32x4*)p;
  f32x4 y = *(const f32x4*)(p + 4);
  S8U r;
  r.u[0] = pack_rne(x[0], x[1]);
  r.u[1] = pack_rne(x[2], x[3]);
  r.u[2] = pack_rne(y[0], y[1]);
  r.u[3] = pack_rne(y[2], y[3]);
  return r.s;
}

#define HW 16384
#define CDIM 192
#define NB 8
#define TILE_B 49152  // 384 rows * 128 B
#define GSZ (CDIM * CDIM)
#define NTILE 300     // blocked partial records per (b,strip): 12 waves * 25 tiles

// ---------------- Kernel A: convert fp32 -> swizzled bf16 Z tiles ------------
__global__ __launch_bounds__(256) void convert_k(const float* __restrict__ input,
                                                 const float* __restrict__ color,
                                                 const float* __restrict__ Wv,
                                                 unsigned short* __restrict__ WvT,
                                                 char* __restrict__ zbf) {
  const int kc = blockIdx.x, b = blockIdx.y;
  const int t = threadIdx.x;
  if (kc == 256) {
    if (b == 0) {
      for (int idx = t; idx < CDIM * CDIM; idx += 256) {
        int j = idx / CDIM, cp = idx % CDIM;
        WvT[idx] = bf16u_rne(Wv[(size_t)cp * CDIM + j]);
      }
    }
    return;
  }
  char* zt = zbf + ((size_t)b * 256 + kc) * TILE_B;
  const int srow = t >> 4;             // 0..15
  const int c4 = (t & 15) * 4;         // f32 col
  const int cb = c4 * 2;               // byte col
  const int sw = (srow & 7) << 4;
  const float* ib = input + (size_t)b * CDIM * HW + (size_t)kc * 64 + c4;
  const float* cp = color + (size_t)b * CDIM * HW + (size_t)kc * 64 + c4;
#pragma unroll
  for (int r = 0; r < 12; ++r) {
    const int row = r * 16 + srow;
    f32x4 v = *(const f32x4*)(ib + (size_t)row * HW);
    unsigned long long p0 = (unsigned long long)pack_rne(v[0], v[1]) |
                            ((unsigned long long)pack_rne(v[2], v[3]) << 32);
    *(unsigned long long*)(zt + row * 128 + (cb ^ sw)) = p0;
    f32x4 w = *(const f32x4*)(cp + (size_t)row * HW);
    unsigned long long p1 = (unsigned long long)pack_rne(w[0], w[1]) |
                            ((unsigned long long)pack_rne(w[2], w[3]) << 32);
    *(unsigned long long*)(zt + (192 + row) * 128 + (cb ^ sw)) = p1;
  }
}

// ---------------- Kernel B: gram Z*Z^T (upper triangle), blocked partials ----
__device__ __forceinline__ short8 zfrag(const char* buf, int row, int ks, int lg) {
  return *(const short8*)(buf + row * 128 + ((ks * 64 + lg * 16) ^ ((row & 7) << 4)));
}

// 12 waves x 4 KB: covers the whole 48KB tile
__device__ __forceinline__ void stage48(const char* gsrc, char* ldst, int wave, int lane) {
#pragma unroll
  for (int i = 0; i < 4; ++i) {
    const int off = (wave * 4 + i) * 1024;
    __builtin_amdgcn_global_load_lds(
        (const __attribute__((address_space(1))) void*)(gsrc + off + lane * 16),
        (__attribute__((address_space(3))) void*)(ldst + off), 16, 0, 0);
  }
}

// wave W owns Z-tile rows {W, 23-W}: 25 upper-triangle tiles, all static indexing.
// slots: row W, col ct -> ct-W  (ct=W..23);  row 23-W, col ct -> ct+1 (ct=23-W..23)
template <int W>
__device__ __forceinline__ void pair_step(const char* buf, f32x4 (&acc)[25],
                                          int l15, int lg) {
#pragma unroll
  for (int ks = 0; ks < 2; ++ks) {
    const short8 aT = zfrag(buf, W * 16 + l15, ks, lg);
    const short8 aB = zfrag(buf, (23 - W) * 16 + l15, ks, lg);
#pragma unroll
    for (int ct = W; ct < 24; ++ct) {
      const short8 b = zfrag(buf, ct * 16 + l15, ks, lg);
      acc[ct - W] = MFMA16(aT, b, acc[ct - W]);
      if (ct >= 23 - W) acc[ct + 1] = MFMA16(aB, b, acc[ct + 1]);
    }
  }
}

__device__ __forceinline__ void pair_dispatch(int wave, const char* buf,
                                              f32x4 (&acc)[25], int l15, int lg) {
  switch (wave) {
    case 0: pair_step<0>(buf, acc, l15, lg); break;
    case 1: pair_step<1>(buf, acc, l15, lg); break;
    case 2: pair_step<2>(buf, acc, l15, lg); break;
    case 3: pair_step<3>(buf, acc, l15, lg); break;
    case 4: pair_step<4>(buf, acc, l15, lg); break;
    case 5: pair_step<5>(buf, acc, l15, lg); break;
    case 6: pair_step<6>(buf, acc, l15, lg); break;
    case 7: pair_step<7>(buf, acc, l15, lg); break;
    case 8: pair_step<8>(buf, acc, l15, lg); break;
    case 9: pair_step<9>(buf, acc, l15, lg); break;
    case 10: pair_step<10>(buf, acc, l15, lg); break;
    default: pair_step<11>(buf, acc, l15, lg); break;
  }
}

// grid (NPART, 8), 768 threads (12 waves), LDS 2x48KB double buffer.
__global__ __launch_bounds__(768) void gram2_k(const char* __restrict__ zbf,
                                               float* __restrict__ part,
                                               int npart, int cpb) {
  __shared__ __align__(16) char lds[2][TILE_B];
  const int tid = threadIdx.x, wave = tid >> 6, lane = tid & 63;
  const int l15 = lane & 15, lg = (lane >> 4) & 3;
  const int strip = blockIdx.x, b = blockIdx.y;
  const char* ztb = zbf + ((size_t)b * 256 + (size_t)strip * cpb) * TILE_B;

  f32x4 acc[25];
#pragma unroll
  for (int i = 0; i < 25; ++i) acc[i] = (f32x4){0.f, 0.f, 0.f, 0.f};

  stage48(ztb, lds[0], wave, lane);
#pragma unroll 1
  for (int c = 0; c < cpb - 1; ++c) {
    stage48(ztb + (size_t)(c + 1) * TILE_B, lds[(c + 1) & 1], wave, lane);
    asm volatile("s_waitcnt vmcnt(4)" ::: "memory");
    __builtin_amdgcn_sched_barrier(0);
    __builtin_amdgcn_s_barrier();
    pair_dispatch(wave, lds[c & 1], acc, l15, lg);
    asm volatile("s_waitcnt lgkmcnt(0)" ::: "memory");
    __builtin_amdgcn_sched_barrier(0);
    __builtin_amdgcn_s_barrier();
  }
  asm volatile("s_waitcnt vmcnt(0)" ::: "memory");
  __builtin_amdgcn_sched_barrier(0);
  __builtin_amdgcn_s_barrier();
  pair_dispatch(wave, lds[(cpb - 1) & 1], acc, l15, lg);

  // -------- blocked flush: one contiguous 1KB record per 16x16 tile --------
  float* pbase = part + (size_t)(b * npart + strip) * NTILE * 256;
#pragma unroll
  for (int s = 0; s < 25; ++s)
    *(f32x4*)(pbase + ((size_t)(wave * 25 + s) * 64 + lane) * 4) = acc[s];
}

// ---------------- reduce blocked partials -> G (both triangles) -------------
// grid (75, NB), 256 threads: 4 records per block, NP fully unrolled.
template <int NP>
__global__ __launch_bounds__(256) void reduce_k(const float* __restrict__ part,
                                                float* __restrict__ G) {
  const int b = blockIdx.y;
  const int T = blockIdx.x * 4 + (threadIdx.x >> 6);
  const int lane = threadIdx.x & 63;
  const float* p = part + ((size_t)b * NP * NTILE + T) * 256 + lane * 4;
  f32x4 v[NP];
#pragma unroll
  for (int s = 0; s < NP; ++s) v[s] = *(const f32x4*)(p + (size_t)s * NTILE * 256);
  f32x4 sum = v[0];
#pragma unroll
  for (int s = 1; s < NP; ++s) {
    sum[0] += v[s][0]; sum[1] += v[s][1]; sum[2] += v[s][2]; sum[3] += v[s][3];
  }
  // decode record T -> Z-tile (rt, ct) with rt <= ct
  const int w = T / 25, s = T % 25;
  int rt, ct;
  if (s <= 23 - w) { rt = w; ct = w + s; }
  else { rt = 23 - w; ct = s - 1; }
  // map Z-tile to G type: rows 0..11 = I, 12..23 = C
  int type, gm, gn;
  if (ct < 12) { type = 2; gm = rt; gn = ct; }            // I*I^T
  else if (rt < 12) { type = 0; gm = rt; gn = ct - 12; }  // I*C^T (full)
  else { type = 1; gm = rt - 12; gn = ct - 12; }          // C*C^T
  float* Gm = G + ((size_t)type * NB + b) * GSZ;
  const int l15 = lane & 15, lg = lane >> 4;
  const int row0 = gm * 16 + lg * 4, col = gn * 16 + l15;
#pragma unroll
  for (int r = 0; r < 4; ++r) Gm[(size_t)(row0 + r) * CDIM + col] = sum[r];
  if (type != 0 && rt != ct) {
#pragma unroll
    for (int r = 0; r < 4; ++r) Gm[(size_t)col * CDIM + (row0 + r)] = sum[r];
  }
}

// ---------------- Kernel 2a: A_pre (type0), nq (type1), nk (type2) ----------
__global__ __launch_bounds__(256) void k2a(const float* __restrict__ G,
                                           const float* __restrict__ Wq,
                                           const float* __restrict__ Wk,
                                           float* __restrict__ A_pre,
                                           float* __restrict__ nqk) {
  const int b = blockIdx.x, type = blockIdx.y;
  __shared__ __align__(16) unsigned short Hs[192][200];
  const int tid = threadIdx.x, wave = tid >> 6, lane = tid & 63;
  const int l15 = lane & 15, lg = lane >> 4, row0 = wave * 48;
  const float* W1 = (type == 2) ? Wk : Wq;
  const float* Gm = G + ((size_t)type * NB + b) * GSZ;

  f32x4 acc[3][12];
#pragma unroll
  for (int t = 0; t < 3; t++)
#pragma unroll
    for (int j = 0; j < 12; j++) acc[t][j] = (f32x4){0.f, 0.f, 0.f, 0.f};

  for (int ks = 0; ks < 192; ks += 32) {
    short8 afr[3];
#pragma unroll
    for (int t = 0; t < 3; t++)
      afr[t] = load_cvt8(W1 + (size_t)(row0 + t * 16 + l15) * CDIM + ks + lg * 8);
#pragma unroll
    for (int tj = 0; tj < 12; tj++) {
      short8 bfr = load_cvt8(Gm + (size_t)(tj * 16 + l15) * CDIM + ks + lg * 8);
#pragma unroll
      for (int t = 0; t < 3; t++) acc[t][tj] = MFMA16(afr[t], bfr, acc[t][tj]);
    }
  }
#pragma unroll
  for (int t = 0; t < 3; t++)
#pragma unroll
    for (int tj = 0; tj < 12; tj++)
#pragma unroll
      for (int r = 0; r < 4; r++)
        Hs[row0 + t * 16 + lg * 4 + r][tj * 16 + l15] = bf16u_rne(acc[t][tj][r]);
  __syncthreads();

  if (type == 0) {
    f32x4 a2[3][12];
#pragma unroll
    for (int t = 0; t < 3; t++)
#pragma unroll
      for (int j = 0; j < 12; j++) a2[t][j] = (f32x4){0.f, 0.f, 0.f, 0.f};
    for (int ks = 0; ks < 192; ks += 32) {
      short8 afr[3];
#pragma unroll
      for (int t = 0; t < 3; t++)
        afr[t] = *(const short8*)&Hs[row0 + t * 16 + l15][ks + lg * 8];
#pragma unroll
      for (int tj = 0; tj < 12; tj++) {
        short8 bfr = load_cvt8(Wk + (size_t)(tj * 16 + l15) * CDIM + ks + lg * 8);
#pragma unroll
        for (int t = 0; t < 3; t++) a2[t][tj] = MFMA16(afr[t], bfr, a2[t][tj]);
      }
    }
    float* Ab = A_pre + (size_t)b * GSZ;
#pragma unroll
    for (int t = 0; t < 3; t++)
#pragma unroll
      for (int tj = 0; tj < 12; tj++)
#pragma unroll
        for (int r = 0; r < 4; r++)
          Ab[(size_t)(row0 + t * 16 + lg * 4 + r) * CDIM + tj * 16 + l15] = a2[t][tj][r];
  } else {
    f32x4 a2[3];
#pragma unroll
    for (int t = 0; t < 3; t++) a2[t] = (f32x4){0.f, 0.f, 0.f, 0.f};
    for (int ks = 0; ks < 192; ks += 32) {
#pragma unroll
      for (int t = 0; t < 3; t++) {
        short8 afr = *(const short8*)&Hs[row0 + t * 16 + l15][ks + lg * 8];
        short8 bfr = load_cvt8(W1 + (size_t)(row0 + t * 16 + l15) * CDIM + ks + lg * 8);
        a2[t] = MFMA16(afr, bfr, a2[t]);
      }
    }
    float* dst = nqk + ((size_t)(type - 1) * NB + b) * CDIM;
#pragma unroll
    for (int t = 0; t < 3; t++)
#pragma unroll
      for (int r = 0; r < 4; r++)
        if (lg * 4 + r == l15) dst[row0 + t * 16 + l15] = a2[t][r];
  }
}

// ---------------- Kernel 2b: per-head softmax ----------------
__global__ void k2b(const float* __restrict__ A_pre, const float* __restrict__ nqk,
                    float* __restrict__ attnw) {
  const int b = blockIdx.x, tid = threadIdx.x;
  const int h = tid >> 5, r = tid & 31;
  if (r >= 24) return;
  const float* Ab = A_pre + (size_t)b * GSZ;
  const float* nq = nqk + (size_t)b * CDIM;
  const float* nk = nqk + (size_t)(NB + b) * CDIM;
  const int c = h * 24 + r;
  const float qn = rsqrtf(fmaxf(nq[c], 1e-24f));
  float e[24];
  float mx = -1e30f;
#pragma unroll
  for (int d = 0; d < 24; d++) {
    float kn = rsqrtf(fmaxf(nk[h * 24 + d], 1e-24f));
    float l = Ab[(size_t)c * CDIM + h * 24 + d] * qn * kn;
    e[d] = l;
    mx = fmaxf(mx, l);
  }
  float s = 0.f;
#pragma unroll
  for (int d = 0; d < 24; d++) {
    float x = __expf(e[d] - mx);
    e[d] = x;
    s += x;
  }
  const float inv = 1.0f / s;
  float* dst = attnw + (((size_t)b * NB + h) * 24 + r) * 24;
#pragma unroll
  for (int d = 0; d < 24; d++) dst[d] = e[d] * inv;
}

// ---------------- Kernel 3: P = Wo * blockdiag(attn) * Wv  (bf16 out) -------
__global__ __launch_bounds__(256) void k3(const float* __restrict__ attnw,
                                          const float* __restrict__ Wo,
                                          const unsigned short* __restrict__ WvT,
                                          unsigned short* __restrict__ Pbf) {
  const int b = blockIdx.x;
  __shared__ __align__(16) unsigned short AT[192][200];
  __shared__ __align__(16) unsigned short Ms[192][200];
  const int tid = threadIdx.x, wave = tid >> 6, lane = tid & 63;
  const int l15 = lane & 15, lg = lane >> 4, row0 = wave * 48;

  unsigned int* ATu = (unsigned int*)&AT[0][0];
  for (int i = tid; i < 192 * 100; i += 256) ATu[i] = 0u;
  __syncthreads();
  const float* at = attnw + (size_t)b * NB * 24 * 24;
  for (int i = tid; i < 4608; i += 256) {
    int h = i / 576, rem = i % 576, c = rem / 24, d = rem % 24;
    AT[h * 24 + d][h * 24 + c] = bf16u_rne(at[(h * 24 + c) * 24 + d]);
  }
  __syncthreads();

  f32x4 acc[3][12];
#pragma unroll
  for (int t = 0; t < 3; t++)
#pragma unroll
    for (int j = 0; j < 12; j++) acc[t][j] = (f32x4){0.f, 0.f, 0.f, 0.f};
  for (int ks = 0; ks < 192; ks += 32) {
    short8 afr[3];
#pragma unroll
    for (int t = 0; t < 3; t++)
      afr[t] = load_cvt8(Wo + (size_t)(row0 + t * 16 + l15) * CDIM + ks + lg * 8);
#pragma unroll
    for (int tj = 0; tj < 12; tj++) {
      short8 bfr = *(const short8*)&AT[tj * 16 + l15][ks + lg * 8];
#pragma unroll
      for (int t = 0; t < 3; t++) acc[t][tj] = MFMA16(afr[t], bfr, acc[t][tj]);
    }
  }
#pragma unroll
  for (int t = 0; t < 3; t++)
#pragma unroll
    for (int tj = 0; tj < 12; tj++)
#pragma unroll
      for (int r = 0; r < 4; r++)
        Ms[row0 + t * 16 + lg * 4 + r][tj * 16 + l15] = bf16u_rne(acc[t][tj][r]);
  __syncthreads();

  f32x4 a2[3][12];
#pragma unroll
  for (int t = 0; t < 3; t++)
#pragma unroll
    for (int j = 0; j < 12; j++) a2[t][j] = (f32x4){0.f, 0.f, 0.f, 0.f};
  for (int ks = 0; ks < 192; ks += 32) {
    short8 afr[3];
#pragma unroll
    for (int t = 0; t < 3; t++)
      afr[t] = *(const short8*)&Ms[row0 + t * 16 + l15][ks + lg * 8];
#pragma unroll
    for (int tj = 0; tj < 12; tj++) {
      short8 bfr = *(const short8*)(WvT + (size_t)(tj * 16 + l15) * CDIM + ks + lg * 8);
#pragma unroll
      for (int t = 0; t < 3; t++) a2[t][tj] = MFMA16(afr[t], bfr, a2[t][tj]);
    }
  }
  unsigned short* Pb = Pbf + (size_t)b * GSZ;
#pragma unroll
  for (int t = 0; t < 3; t++)
#pragma unroll
    for (int tj = 0; tj < 12; tj++)
#pragma unroll
      for (int r = 0; r < 4; r++)
        Pb[(size_t)(row0 + t * 16 + lg * 4 + r) * CDIM + tj * 16 + l15] = bf16u_rne(a2[t][tj][r]);
}

// ---------------- Kernel D: out = P @ input  ----------------
__global__ __launch_bounds__(256) void kD(const unsigned short* __restrict__ Pbf,
                                          const float* __restrict__ input,
                                          float* __restrict__ out) {
  const int nchunk = blockIdx.x, b = blockIdx.y;
  const int n0 = nchunk * 128;
  __shared__ __align__(16) char BsT[128 * 384];
  const int tid = threadIdx.x, wave = tid >> 6, lane = tid & 63;
  const int l15 = lane & 15, lg = lane >> 4, row0 = wave * 48;

  {
    const int n4 = (tid & 31) * 4;
    const int kb0 = (tid >> 5) * 4;
    const float* src = input + (size_t)b * CDIM * HW + n0 + n4;
#pragma unroll
    for (int rnd = 0; rnd < 6; ++rnd) {
      const int kb = kb0 + rnd * 32;
      f32x4 v0 = *(const f32x4*)(src + (size_t)(kb + 0) * HW);
      f32x4 v1 = *(const f32x4*)(src + (size_t)(kb + 1) * HW);
      f32x4 v2 = *(const f32x4*)(src + (size_t)(kb + 2) * HW);
      f32x4 v3 = *(const f32x4*)(src + (size_t)(kb + 3) * HW);
#pragma unroll
      for (int i = 0; i < 4; ++i) {
        const int n = n4 + i;
        unsigned long long pk = (unsigned long long)pack_rne(v0[i], v1[i]) |
                                ((unsigned long long)pack_rne(v2[i], v3[i]) << 32);
        *(unsigned long long*)(BsT + n * 384 + ((kb * 2) ^ ((n & 7) << 4))) = pk;
      }
    }
  }
  __syncthreads();

  f32x4 acc[3][8];
#pragma unroll
  for (int t = 0; t < 3; t++)
#pragma unroll
    for (int j = 0; j < 8; j++) acc[t][j] = (f32x4){0.f, 0.f, 0.f, 0.f};

  const unsigned short* Pb = Pbf + (size_t)b * GSZ;
#pragma unroll 2
  for (int ks = 0; ks < 6; ks++) {
    short8 afr[3];
#pragma unroll
    for (int t = 0; t < 3; t++)
      afr[t] = *(const short8*)(Pb + (size_t)(row0 + t * 16 + l15) * CDIM + ks * 32 + lg * 8);
#pragma unroll
    for (int tn = 0; tn < 8; tn++) {
      const int n = tn * 16 + l15;
      short8 bfr = *(const short8*)(BsT + n * 384 + ((ks * 64 + lg * 16) ^ ((n & 7) << 4)));
#pragma unroll
      for (int t = 0; t < 3; t++) acc[t][tn] = MFMA16(afr[t], bfr, acc[t][tn]);
    }
  }
  float* ob = out + (size_t)b * CDIM * HW + n0;
#pragma unroll
  for (int t = 0; t < 3; t++)
#pragma unroll
    for (int tn = 0; tn < 8; tn++)
#pragma unroll
      for (int r = 0; r < 4; r++) {
        const int m = row0 + t * 16 + lg * 4 + r;
        ob[(size_t)m * HW + tn * 16 + l15] = acc[t][tn][r];
      }
}

// ---------------- launch ----------------
extern "C" void kernel_launch(void* const* d_in, const int* in_sizes, int n_in,
                              void* d_out, int out_size, void* d_ws, size_t ws_size,
                              hipStream_t stream) {
  const float* input = (const float*)d_in[0];
  const float* color = (const float*)d_in[1];
  const float* Wq = (const float*)d_in[2];
  const float* Wk = (const float*)d_in[3];
  const float* Wv = (const float*)d_in[4];
  const float* Wo = (const float*)d_in[5];
  float* out = (float*)d_out;
  char* ws = (char*)d_ws;

  const size_t OFF_G = 0;                        // 3*8*192*192*4 = 3538944
  const size_t OFF_APRE = 3538944;               // 8*192*192*4  = 1179648
  const size_t OFF_NQK = OFF_APRE + 1179648;     // 2*8*192*4    = 12288
  const size_t OFF_ATT = OFF_NQK + 12288;        // 8*8*24*24*4  = 147456
  const size_t OFF_WVT = OFF_ATT + 147456;       // 192*192*2    = 73728
  const size_t OFF_PBF = OFF_WVT + 73728;        // 8*192*192*2  = 589824
  const size_t OFF_PART = OFF_PBF + 589824;      // npart*8*300*1024

  float* G = (float*)(ws + OFF_G);
  float* A_pre = (float*)(ws + OFF_APRE);
  float* nqk = (float*)(ws + OFF_NQK);
  float* attnw = (float*)(ws + OFF_ATT);
  unsigned short* WvT = (unsigned short*)(ws + OFF_WVT);
  unsigned short* Pbf = (unsigned short*)(ws + OFF_PBF);
  float* part = (float*)(ws + OFF_PART);

  // choose partial count from available workspace (deterministic per run)
  int npart = 32;
  while (npart > 2 && OFF_PART + (size_t)npart * NB * NTILE * 1024 > ws_size) npart >>= 1;
  const int cpb = 256 / npart;

  // Z (bf16, swizzled tiles) lives in d_out as scratch; kD overwrites it last.
  char* zbf = (char*)d_out;

  convert_k<<<dim3(257, NB), dim3(256), 0, stream>>>(input, color, Wv, WvT, zbf);
  gram2_k<<<dim3(npart, NB), dim3(768), 0, stream>>>(zbf, part, npart, cpb);
  switch (npart) {
    case 32: reduce_k<32><<<dim3(75, NB), dim3(256), 0, stream>>>(part, G); break;
    case 16: reduce_k<16><<<dim3(75, NB), dim3(256), 0, stream>>>(part, G); break;
    case 8:  reduce_k<8><<<dim3(75, NB), dim3(256), 0, stream>>>(part, G); break;
    case 4:  reduce_k<4><<<dim3(75, NB), dim3(256), 0, stream>>>(part, G); break;
    default: reduce_k<2><<<dim3(75, NB), dim3(256), 0, stream>>>(part, G); break;
  }
  k2a<<<dim3(NB, 3), dim3(256), 0, stream>>>(G, Wq, Wk, A_pre, nqk);
  k2b<<<dim3(NB), dim3(256), 0, stream>>>(A_pre, nqk, attnw);
  k3<<<dim3(NB), dim3(256), 0, stream>>>(attnw, Wo, WvT, Pbf);
  kD<<<dim3(HW / 128, NB), dim3(256), 0, stream>>>(Pbf, input, out);
}

// Round 9
// 244.244 us; speedup vs baseline: 3.5301x; 1.0934x over previous
//
#include <hip/hip_runtime.h>
#include <hip/hip_bf16.h>

// Color_Attention: transposed (channel) attention.
//   Z = [I; C] (384 x 16384 bf16, per batch, tiled+swizzled, stored in d_out as scratch)
//   Z*Z^T upper triangle (24x24 tiles, 300 tiles) = { G_ii, G_ic, G_cc }
//   gram2_k: 12 waves, wave w owns row-pair (w, 23-w) = 25 tiles = 100 acc VGPRs
//   reduce_k sums blocked partials -> G (writes both triangles)
//   A_pre = Wq*G_ci*Wk^T ; nq = diag(Wq*G_cc*Wq^T); nk = diag(Wk*G_ii*Wk^T)
//   attn = softmax over head-diagonal 24x24 blocks of A_pre/(nq*nk)
//   P = Wo * blockdiag(attn) * Wv ; out = P @ input

typedef __attribute__((ext_vector_type(4))) float f32x4;
typedef __attribute__((ext_vector_type(8))) short short8;

#define MFMA16(a, b, c) __builtin_amdgcn_mfma_f32_16x16x32_bf16((a), (b), (c), 0, 0, 0)

__device__ __forceinline__ unsigned int pack_rne(float a, float b) {
  unsigned int ua = __float_as_uint(a), ub = __float_as_uint(b);
  ua += 0x7fffu + ((ua >> 16) & 1u);
  ub += 0x7fffu + ((ub >> 16) & 1u);
  return (ua >> 16) | (ub & 0xffff0000u);
}
__device__ __forceinline__ unsigned short bf16u_rne(float x) {
  unsigned int u = __float_as_uint(x);
  u += 0x7fffu + ((u >> 16) & 1u);
  return (unsigned short)(u >> 16);
}
union S8U { short8 s; unsigned int u[4]; };
__device__ __forceinline__ short8 load_cvt8(const float* p) {
  f32x4 x = *(const f32x4*)p;
  f32x4 y = *(const f32x4*)(p + 4);
  S8U r;
  r.u[0] = pack_rne(x[0], x[1]);
  r.u[1] = pack_rne(x[2], x[3]);
  r.u[2] = pack_rne(y[0], y[1]);
  r.u[3] = pack_rne(y[2], y[3]);
  return r.s;
}

#define HW 16384
#define CDIM 192
#define NB 8
#define TILE_B 49152  // 384 rows * 128 B
#define GSZ (CDIM * CDIM)
#define NTILE 300     // blocked partial records per (b,strip): 12 waves * 25 tiles

// ---------------- Kernel 0: transpose Wv -> bf16 WvT ----------------
__global__ void k0_wvt(const float* __restrict__ Wv, unsigned short* __restrict__ WvT) {
  int idx = blockIdx.x * 256 + threadIdx.x;
  if (idx < CDIM * CDIM) {
    int j = idx / CDIM, cp = idx % CDIM;
    WvT[idx] = bf16u_rne(Wv[(size_t)cp * CDIM + j]);
  }
}

// ---------------- Kernel A: convert fp32 -> swizzled bf16 Z tiles ------------
// Streaming layout: grid (16 colgroups, 24 = 12 rowgroups x 2 tensors, NB).
// Each block: 16 rows x 1024 contiguous cols of one tensor.
// Reads: per round one wave = 1KB sequential. Writes: 4 x 128B full-line segs.
__global__ __launch_bounds__(256) void convert_k(const float* __restrict__ input,
                                                 const float* __restrict__ color,
                                                 char* __restrict__ zbf) {
  const int cg = blockIdx.x, rgt = blockIdx.y, b = blockIdx.z;
  const int tensor = rgt >= 12;
  const int rg = (rgt - (tensor ? 12 : 0)) * 16;
  const int c4 = threadIdx.x * 4;  // 0..1020
  const float* X = (tensor ? color : input) +
                   (size_t)b * CDIM * HW + (size_t)rg * HW + (size_t)cg * 1024 + c4;
  f32x4 v[16];
#pragma unroll
  for (int r = 0; r < 16; ++r) v[r] = *(const f32x4*)(X + (size_t)r * HW);

  const int kcl = c4 >> 6;   // 0..15: local tile
  const int cit = c4 & 63;   // col within tile
  char* zt = zbf + ((size_t)b * 256 + cg * 16 + kcl) * TILE_B + (tensor ? 192 * 128 : 0);
#pragma unroll
  for (int r = 0; r < 16; ++r) {
    const int row = rg + r;
    unsigned long long pk = (unsigned long long)pack_rne(v[r][0], v[r][1]) |
                            ((unsigned long long)pack_rne(v[r][2], v[r][3]) << 32);
    *(unsigned long long*)(zt + row * 128 + ((cit * 2) ^ ((row & 7) << 4))) = pk;
  }
}

// ---------------- Kernel B: gram Z*Z^T (upper triangle), blocked partials ----
__device__ __forceinline__ short8 zfrag(const char* buf, int row, int ks, int lg) {
  return *(const short8*)(buf + row * 128 + ((ks * 64 + lg * 16) ^ ((row & 7) << 4)));
}

// 12 waves x 4 KB: covers the whole 48KB tile
__device__ __forceinline__ void stage48(const char* gsrc, char* ldst, int wave, int lane) {
#pragma unroll
  for (int i = 0; i < 4; ++i) {
    const int off = (wave * 4 + i) * 1024;
    __builtin_amdgcn_global_load_lds(
        (const __attribute__((address_space(1))) void*)(gsrc + off + lane * 16),
        (__attribute__((address_space(3))) void*)(ldst + off), 16, 0, 0);
  }
}

// wave W owns Z-tile rows {W, 23-W}: 25 upper-triangle tiles, all static indexing.
// slots: row W, col ct -> ct-W  (ct=W..23);  row 23-W, col ct -> ct+1 (ct=23-W..23)
template <int W>
__device__ __forceinline__ void pair_step(const char* buf, f32x4 (&acc)[25],
                                          int l15, int lg) {
#pragma unroll
  for (int ks = 0; ks < 2; ++ks) {
    const short8 aT = zfrag(buf, W * 16 + l15, ks, lg);
    const short8 aB = zfrag(buf, (23 - W) * 16 + l15, ks, lg);
#pragma unroll
    for (int ct = W; ct < 24; ++ct) {
      const short8 b = zfrag(buf, ct * 16 + l15, ks, lg);
      acc[ct - W] = MFMA16(aT, b, acc[ct - W]);
      if (ct >= 23 - W) acc[ct + 1] = MFMA16(aB, b, acc[ct + 1]);
    }
  }
}

__device__ __forceinline__ void pair_dispatch(int wave, const char* buf,
                                              f32x4 (&acc)[25], int l15, int lg) {
  switch (wave) {
    case 0: pair_step<0>(buf, acc, l15, lg); break;
    case 1: pair_step<1>(buf, acc, l15, lg); break;
    case 2: pair_step<2>(buf, acc, l15, lg); break;
    case 3: pair_step<3>(buf, acc, l15, lg); break;
    case 4: pair_step<4>(buf, acc, l15, lg); break;
    case 5: pair_step<5>(buf, acc, l15, lg); break;
    case 6: pair_step<6>(buf, acc, l15, lg); break;
    case 7: pair_step<7>(buf, acc, l15, lg); break;
    case 8: pair_step<8>(buf, acc, l15, lg); break;
    case 9: pair_step<9>(buf, acc, l15, lg); break;
    case 10: pair_step<10>(buf, acc, l15, lg); break;
    default: pair_step<11>(buf, acc, l15, lg); break;
  }
}

// grid (NPART, 8), 768 threads (12 waves), LDS 2x48KB double buffer.
__global__ __launch_bounds__(768) void gram2_k(const char* __restrict__ zbf,
                                               float* __restrict__ part,
                                               int npart, int cpb) {
  __shared__ __align__(16) char lds[2][TILE_B];
  const int tid = threadIdx.x, wave = tid >> 6, lane = tid & 63;
  const int l15 = lane & 15, lg = (lane >> 4) & 3;
  const int strip = blockIdx.x, b = blockIdx.y;
  const char* ztb = zbf + ((size_t)b * 256 + (size_t)strip * cpb) * TILE_B;

  f32x4 acc[25];
#pragma unroll
  for (int i = 0; i < 25; ++i) acc[i] = (f32x4){0.f, 0.f, 0.f, 0.f};

  stage48(ztb, lds[0], wave, lane);
#pragma unroll 1
  for (int c = 0; c < cpb - 1; ++c) {
    stage48(ztb + (size_t)(c + 1) * TILE_B, lds[(c + 1) & 1], wave, lane);
    asm volatile("s_waitcnt vmcnt(4)" ::: "memory");
    __builtin_amdgcn_sched_barrier(0);
    __builtin_amdgcn_s_barrier();
    pair_dispatch(wave, lds[c & 1], acc, l15, lg);
    asm volatile("s_waitcnt lgkmcnt(0)" ::: "memory");
    __builtin_amdgcn_sched_barrier(0);
    __builtin_amdgcn_s_barrier();
  }
  asm volatile("s_waitcnt vmcnt(0)" ::: "memory");
  __builtin_amdgcn_sched_barrier(0);
  __builtin_amdgcn_s_barrier();
  pair_dispatch(wave, lds[(cpb - 1) & 1], acc, l15, lg);

  // -------- blocked flush: one contiguous 1KB record per 16x16 tile --------
  float* pbase = part + (size_t)(b * npart + strip) * NTILE * 256;
#pragma unroll
  for (int s = 0; s < 25; ++s)
    *(f32x4*)(pbase + ((size_t)(wave * 25 + s) * 64 + lane) * 4) = acc[s];
}

// ---------------- reduce blocked partials -> G (both triangles) -------------
// grid (75, NB), 256 threads: 4 records per block, NP fully unrolled.
template <int NP>
__global__ __launch_bounds__(256) void reduce_k(const float* __restrict__ part,
                                                float* __restrict__ G) {
  const int b = blockIdx.y;
  const int T = blockIdx.x * 4 + (threadIdx.x >> 6);
  const int lane = threadIdx.x & 63;
  const float* p = part + ((size_t)b * NP * NTILE + T) * 256 + lane * 4;
  f32x4 v[NP];
#pragma unroll
  for (int s = 0; s < NP; ++s) v[s] = *(const f32x4*)(p + (size_t)s * NTILE * 256);
  f32x4 sum = v[0];
#pragma unroll
  for (int s = 1; s < NP; ++s) {
    sum[0] += v[s][0]; sum[1] += v[s][1]; sum[2] += v[s][2]; sum[3] += v[s][3];
  }
  // decode record T -> Z-tile (rt, ct) with rt <= ct
  const int w = T / 25, s = T % 25;
  int rt, ct;
  if (s <= 23 - w) { rt = w; ct = w + s; }
  else { rt = 23 - w; ct = s - 1; }
  // map Z-tile to G type: rows 0..11 = I, 12..23 = C
  int type, gm, gn;
  if (ct < 12) { type = 2; gm = rt; gn = ct; }            // I*I^T
  else if (rt < 12) { type = 0; gm = rt; gn = ct - 12; }  // I*C^T (full)
  else { type = 1; gm = rt - 12; gn = ct - 12; }          // C*C^T
  float* Gm = G + ((size_t)type * NB + b) * GSZ;
  const int l15 = lane & 15, lg = lane >> 4;
  const int row0 = gm * 16 + lg * 4, col = gn * 16 + l15;
#pragma unroll
  for (int r = 0; r < 4; ++r) Gm[(size_t)(row0 + r) * CDIM + col] = sum[r];
  if (type != 0 && rt != ct) {
#pragma unroll
    for (int r = 0; r < 4; ++r) Gm[(size_t)col * CDIM + (row0 + r)] = sum[r];
  }
}

// ---------------- Kernel 2a: A_pre (type0), nq (type1), nk (type2) ----------
__global__ __launch_bounds__(256) void k2a(const float* __restrict__ G,
                                           const float* __restrict__ Wq,
                                           const float* __restrict__ Wk,
                                           float* __restrict__ A_pre,
                                           float* __restrict__ nqk) {
  const int b = blockIdx.x, type = blockIdx.y;
  __shared__ __align__(16) unsigned short Hs[192][200];
  const int tid = threadIdx.x, wave = tid >> 6, lane = tid & 63;
  const int l15 = lane & 15, lg = lane >> 4, row0 = wave * 48;
  const float* W1 = (type == 2) ? Wk : Wq;
  const float* Gm = G + ((size_t)type * NB + b) * GSZ;

  f32x4 acc[3][12];
#pragma unroll
  for (int t = 0; t < 3; t++)
#pragma unroll
    for (int j = 0; j < 12; j++) acc[t][j] = (f32x4){0.f, 0.f, 0.f, 0.f};

  for (int ks = 0; ks < 192; ks += 32) {
    short8 afr[3];
#pragma unroll
    for (int t = 0; t < 3; t++)
      afr[t] = load_cvt8(W1 + (size_t)(row0 + t * 16 + l15) * CDIM + ks + lg * 8);
#pragma unroll
    for (int tj = 0; tj < 12; tj++) {
      short8 bfr = load_cvt8(Gm + (size_t)(tj * 16 + l15) * CDIM + ks + lg * 8);
#pragma unroll
      for (int t = 0; t < 3; t++) acc[t][tj] = MFMA16(afr[t], bfr, acc[t][tj]);
    }
  }
#pragma unroll
  for (int t = 0; t < 3; t++)
#pragma unroll
    for (int tj = 0; tj < 12; tj++)
#pragma unroll
      for (int r = 0; r < 4; r++)
        Hs[row0 + t * 16 + lg * 4 + r][tj * 16 + l15] = bf16u_rne(acc[t][tj][r]);
  __syncthreads();

  if (type == 0) {
    f32x4 a2[3][12];
#pragma unroll
    for (int t = 0; t < 3; t++)
#pragma unroll
      for (int j = 0; j < 12; j++) a2[t][j] = (f32x4){0.f, 0.f, 0.f, 0.f};
    for (int ks = 0; ks < 192; ks += 32) {
      short8 afr[3];
#pragma unroll
      for (int t = 0; t < 3; t++)
        afr[t] = *(const short8*)&Hs[row0 + t * 16 + l15][ks + lg * 8];
#pragma unroll
      for (int tj = 0; tj < 12; tj++) {
        short8 bfr = load_cvt8(Wk + (size_t)(tj * 16 + l15) * CDIM + ks + lg * 8);
#pragma unroll
        for (int t = 0; t < 3; t++) a2[t][tj] = MFMA16(afr[t], bfr, a2[t][tj]);
      }
    }
    float* Ab = A_pre + (size_t)b * GSZ;
#pragma unroll
    for (int t = 0; t < 3; t++)
#pragma unroll
      for (int tj = 0; tj < 12; tj++)
#pragma unroll
        for (int r = 0; r < 4; r++)
          Ab[(size_t)(row0 + t * 16 + lg * 4 + r) * CDIM + tj * 16 + l15] = a2[t][tj][r];
  } else {
    f32x4 a2[3];
#pragma unroll
    for (int t = 0; t < 3; t++) a2[t] = (f32x4){0.f, 0.f, 0.f, 0.f};
    for (int ks = 0; ks < 192; ks += 32) {
#pragma unroll
      for (int t = 0; t < 3; t++) {
        short8 afr = *(const short8*)&Hs[row0 + t * 16 + l15][ks + lg * 8];
        short8 bfr = load_cvt8(W1 + (size_t)(row0 + t * 16 + l15) * CDIM + ks + lg * 8);
        a2[t] = MFMA16(afr, bfr, a2[t]);
      }
    }
    float* dst = nqk + ((size_t)(type - 1) * NB + b) * CDIM;
#pragma unroll
    for (int t = 0; t < 3; t++)
#pragma unroll
      for (int r = 0; r < 4; r++)
        if (lg * 4 + r == l15) dst[row0 + t * 16 + l15] = a2[t][r];
  }
}

// ---------------- Kernel 2b: per-head softmax ----------------
__global__ void k2b(const float* __restrict__ A_pre, const float* __restrict__ nqk,
                    float* __restrict__ attnw) {
  const int b = blockIdx.x, tid = threadIdx.x;
  const int h = tid >> 5, r = tid & 31;
  if (r >= 24) return;
  const float* Ab = A_pre + (size_t)b * GSZ;
  const float* nq = nqk + (size_t)b * CDIM;
  const float* nk = nqk + (size_t)(NB + b) * CDIM;
  const int c = h * 24 + r;
  const float qn = rsqrtf(fmaxf(nq[c], 1e-24f));
  float e[24];
  float mx = -1e30f;
#pragma unroll
  for (int d = 0; d < 24; d++) {
    float kn = rsqrtf(fmaxf(nk[h * 24 + d], 1e-24f));
    float l = Ab[(size_t)c * CDIM + h * 24 + d] * qn * kn;
    e[d] = l;
    mx = fmaxf(mx, l);
  }
  float s = 0.f;
#pragma unroll
  for (int d = 0; d < 24; d++) {
    float x = __expf(e[d] - mx);
    e[d] = x;
    s += x;
  }
  const float inv = 1.0f / s;
  float* dst = attnw + (((size_t)b * NB + h) * 24 + r) * 24;
#pragma unroll
  for (int d = 0; d < 24; d++) dst[d] = e[d] * inv;
}

// ---------------- Kernel 3: P = Wo * blockdiag(attn) * Wv  (bf16 out) -------
__global__ __launch_bounds__(256) void k3(const float* __restrict__ attnw,
                                          const float* __restrict__ Wo,
                                          const unsigned short* __restrict__ WvT,
                                          unsigned short* __restrict__ Pbf) {
  const int b = blockIdx.x;
  __shared__ __align__(16) unsigned short AT[192][200];
  __shared__ __align__(16) unsigned short Ms[192][200];
  const int tid = threadIdx.x, wave = tid >> 6, lane = tid & 63;
  const int l15 = lane & 15, lg = lane >> 4, row0 = wave * 48;

  unsigned int* ATu = (unsigned int*)&AT[0][0];
  for (int i = tid; i < 192 * 100; i += 256) ATu[i] = 0u;
  __syncthreads();
  const float* at = attnw + (size_t)b * NB * 24 * 24;
  for (int i = tid; i < 4608; i += 256) {
    int h = i / 576, rem = i % 576, c = rem / 24, d = rem % 24;
    AT[h * 24 + d][h * 24 + c] = bf16u_rne(at[(h * 24 + c) * 24 + d]);
  }
  __syncthreads();

  f32x4 acc[3][12];
#pragma unroll
  for (int t = 0; t < 3; t++)
#pragma unroll
    for (int j = 0; j < 12; j++) acc[t][j] = (f32x4){0.f, 0.f, 0.f, 0.f};
  for (int ks = 0; ks < 192; ks += 32) {
    short8 afr[3];
#pragma unroll
    for (int t = 0; t < 3; t++)
      afr[t] = load_cvt8(Wo + (size_t)(row0 + t * 16 + l15) * CDIM + ks + lg * 8);
#pragma unroll
    for (int tj = 0; tj < 12; tj++) {
      short8 bfr = *(const short8*)&AT[tj * 16 + l15][ks + lg * 8];
#pragma unroll
      for (int t = 0; t < 3; t++) acc[t][tj] = MFMA16(afr[t], bfr, acc[t][tj]);
    }
  }
#pragma unroll
  for (int t = 0; t < 3; t++)
#pragma unroll
    for (int tj = 0; tj < 12; tj++)
#pragma unroll
      for (int r = 0; r < 4; r++)
        Ms[row0 + t * 16 + lg * 4 + r][tj * 16 + l15] = bf16u_rne(acc[t][tj][r]);
  __syncthreads();

  f32x4 a2[3][12];
#pragma unroll
  for (int t = 0; t < 3; t++)
#pragma unroll
    for (int j = 0; j < 12; j++) a2[t][j] = (f32x4){0.f, 0.f, 0.f, 0.f};
  for (int ks = 0; ks < 192; ks += 32) {
    short8 afr[3];
#pragma unroll
    for (int t = 0; t < 3; t++)
      afr[t] = *(const short8*)&Ms[row0 + t * 16 + l15][ks + lg * 8];
#pragma unroll
    for (int tj = 0; tj < 12; tj++) {
      short8 bfr = *(const short8*)(WvT + (size_t)(tj * 16 + l15) * CDIM + ks + lg * 8);
#pragma unroll
      for (int t = 0; t < 3; t++) a2[t][tj] = MFMA16(afr[t], bfr, a2[t][tj]);
    }
  }
  unsigned short* Pb = Pbf + (size_t)b * GSZ;
#pragma unroll
  for (int t = 0; t < 3; t++)
#pragma unroll
    for (int tj = 0; tj < 12; tj++)
#pragma unroll
      for (int r = 0; r < 4; r++)
        Pb[(size_t)(row0 + t * 16 + lg * 4 + r) * CDIM + tj * 16 + l15] = bf16u_rne(a2[t][tj][r]);
}

// ---------------- Kernel D: out = P @ input  ----------------
__global__ __launch_bounds__(256) void kD(const unsigned short* __restrict__ Pbf,
                                          const float* __restrict__ input,
                                          float* __restrict__ out) {
  const int nchunk = blockIdx.x, b = blockIdx.y;
  const int n0 = nchunk * 128;
  __shared__ __align__(16) char BsT[128 * 384];
  const int tid = threadIdx.x, wave = tid >> 6, lane = tid & 63;
  const int l15 = lane & 15, lg = lane >> 4, row0 = wave * 48;

  {
    const int n4 = (tid & 31) * 4;
    const int kb0 = (tid >> 5) * 4;
    const float* src = input + (size_t)b * CDIM * HW + n0 + n4;
#pragma unroll
    for (int rnd = 0; rnd < 6; ++rnd) {
      const int kb = kb0 + rnd * 32;
      f32x4 v0 = *(const f32x4*)(src + (size_t)(kb + 0) * HW);
      f32x4 v1 = *(const f32x4*)(src + (size_t)(kb + 1) * HW);
      f32x4 v2 = *(const f32x4*)(src + (size_t)(kb + 2) * HW);
      f32x4 v3 = *(const f32x4*)(src + (size_t)(kb + 3) * HW);
#pragma unroll
      for (int i = 0; i < 4; ++i) {
        const int n = n4 + i;
        unsigned long long pk = (unsigned long long)pack_rne(v0[i], v1[i]) |
                                ((unsigned long long)pack_rne(v2[i], v3[i]) << 32);
        *(unsigned long long*)(BsT + n * 384 + ((kb * 2) ^ ((n & 7) << 4))) = pk;
      }
    }
  }
  __syncthreads();

  f32x4 acc[3][8];
#pragma unroll
  for (int t = 0; t < 3; t++)
#pragma unroll
    for (int j = 0; j < 8; j++) acc[t][j] = (f32x4){0.f, 0.f, 0.f, 0.f};

  const unsigned short* Pb = Pbf + (size_t)b * GSZ;
#pragma unroll 2
  for (int ks = 0; ks < 6; ks++) {
    short8 afr[3];
#pragma unroll
    for (int t = 0; t < 3; t++)
      afr[t] = *(const short8*)(Pb + (size_t)(row0 + t * 16 + l15) * CDIM + ks * 32 + lg * 8);
#pragma unroll
    for (int tn = 0; tn < 8; tn++) {
      const int n = tn * 16 + l15;
      short8 bfr = *(const short8*)(BsT + n * 384 + ((ks * 64 + lg * 16) ^ ((n & 7) << 4)));
#pragma unroll
      for (int t = 0; t < 3; t++) acc[t][tn] = MFMA16(afr[t], bfr, acc[t][tn]);
    }
  }
  float* ob = out + (size_t)b * CDIM * HW + n0;
#pragma unroll
  for (int t = 0; t < 3; t++)
#pragma unroll
    for (int tn = 0; tn < 8; tn++)
#pragma unroll
      for (int r = 0; r < 4; r++) {
        const int m = row0 + t * 16 + lg * 4 + r;
        ob[(size_t)m * HW + tn * 16 + l15] = acc[t][tn][r];
      }
}

// ---------------- launch ----------------
extern "C" void kernel_launch(void* const* d_in, const int* in_sizes, int n_in,
                              void* d_out, int out_size, void* d_ws, size_t ws_size,
                              hipStream_t stream) {
  const float* input = (const float*)d_in[0];
  const float* color = (const float*)d_in[1];
  const float* Wq = (const float*)d_in[2];
  const float* Wk = (const float*)d_in[3];
  const float* Wv = (const float*)d_in[4];
  const float* Wo = (const float*)d_in[5];
  float* out = (float*)d_out;
  char* ws = (char*)d_ws;

  const size_t OFF_G = 0;                        // 3*8*192*192*4 = 3538944
  const size_t OFF_APRE = 3538944;               // 8*192*192*4  = 1179648
  const size_t OFF_NQK = OFF_APRE + 1179648;     // 2*8*192*4    = 12288
  const size_t OFF_ATT = OFF_NQK + 12288;        // 8*8*24*24*4  = 147456
  const size_t OFF_WVT = OFF_ATT + 147456;       // 192*192*2    = 73728
  const size_t OFF_PBF = OFF_WVT + 73728;        // 8*192*192*2  = 589824
  const size_t OFF_PART = OFF_PBF + 589824;      // npart*8*300*1024

  float* G = (float*)(ws + OFF_G);
  float* A_pre = (float*)(ws + OFF_APRE);
  float* nqk = (float*)(ws + OFF_NQK);
  float* attnw = (float*)(ws + OFF_ATT);
  unsigned short* WvT = (unsigned short*)(ws + OFF_WVT);
  unsigned short* Pbf = (unsigned short*)(ws + OFF_PBF);
  float* part = (float*)(ws + OFF_PART);

  // choose partial count from available workspace (deterministic per run)
  int npart = 32;
  while (npart > 2 && OFF_PART + (size_t)npart * NB * NTILE * 1024 > ws_size) npart >>= 1;
  const int cpb = 256 / npart;

  // Z (bf16, swizzled tiles) lives in d_out as scratch; kD overwrites it last.
  char* zbf = (char*)d_out;

  k0_wvt<<<dim3(144), dim3(256), 0, stream>>>(Wv, WvT);
  convert_k<<<dim3(16, 24, NB), dim3(256), 0, stream>>>(input, color, zbf);
  gram2_k<<<dim3(npart, NB), dim3(768), 0, stream>>>(zbf, part, npart, cpb);
  switch (npart) {
    case 32: reduce_k<32><<<dim3(75, NB), dim3(256), 0, stream>>>(part, G); break;
    case 16: reduce_k<16><<<dim3(75, NB), dim3(256), 0, stream>>>(part, G); break;
    case 8:  reduce_k<8><<<dim3(75, NB), dim3(256), 0, stream>>>(part, G); break;
    case 4:  reduce_k<4><<<dim3(75, NB), dim3(256), 0, stream>>>(part, G); break;
    default: reduce_k<2><<<dim3(75, NB), dim3(256), 0, stream>>>(part, G); break;
  }
  k2a<<<dim3(NB, 3), dim3(256), 0, stream>>>(G, Wq, Wk, A_pre, nqk);
  k2b<<<dim3(NB), dim3(256), 0, stream>>>(A_pre, nqk, attnw);
  k3<<<dim3(NB), dim3(256), 0, stream>>>(attnw, Wo, WvT, Pbf);
  kD<<<dim3(HW / 128, NB), dim3(256), 0, stream>>>(Pbf, input, out);
}

// Round 10
// 242.949 us; speedup vs baseline: 3.5489x; 1.0053x over previous
//
#include <hip/hip_runtime.h>
#include <hip/hip_bf16.h>

// Color_Attention: transposed (channel) attention.
//   Z = [I; C] (384 x 16384 bf16, per batch, tiled+swizzled, stored in d_out as scratch)
//   Z*Z^T upper triangle (24x24 tiles, 300 tiles) = { G_ii, G_ic, G_cc }
//   gram2_k: 12 waves, wave w owns row-pair (w, 23-w) = 25 tiles = 100 acc VGPRs
//   reduce_k sums blocked partials -> G (writes both triangles)
//   A_pre = Wq*G_ci*Wk^T ; nq = diag(Wq*G_cc*Wq^T); nk = diag(Wk*G_ii*Wk^T)
//   attn = softmax over head-diagonal 24x24 blocks of A_pre/(nq*nk)
//   P = Wo * blockdiag(attn) * Wv ; out = P @ input

typedef __attribute__((ext_vector_type(4))) float f32x4;
typedef __attribute__((ext_vector_type(8))) short short8;

#define MFMA16(a, b, c) __builtin_amdgcn_mfma_f32_16x16x32_bf16((a), (b), (c), 0, 0, 0)

__device__ __forceinline__ unsigned int pack_rne(float a, float b) {
  unsigned int ua = __float_as_uint(a), ub = __float_as_uint(b);
  ua += 0x7fffu + ((ua >> 16) & 1u);
  ub += 0x7fffu + ((ub >> 16) & 1u);
  return (ua >> 16) | (ub & 0xffff0000u);
}
__device__ __forceinline__ unsigned short bf16u_rne(float x) {
  unsigned int u = __float_as_uint(x);
  u += 0x7fffu + ((u >> 16) & 1u);
  return (unsigned short)(u >> 16);
}
union S8U { short8 s; unsigned int u[4]; };
__device__ __forceinline__ short8 load_cvt8(const float* p) {
  f32x4 x = *(const f32x4*)p;
  f32x4 y = *(const f32x4*)(p + 4);
  S8U r;
  r.u[0] = pack_rne(x[0], x[1]);
  r.u[1] = pack_rne(x[2], x[3]);
  r.u[2] = pack_rne(y[0], y[1]);
  r.u[3] = pack_rne(y[2], y[3]);
  return r.s;
}

#define HW 16384
#define CDIM 192
#define NB 8
#define TILE_B 49152  // 384 rows * 128 B
#define GSZ (CDIM * CDIM)
#define NTILE 300     // blocked partial records per (b,strip): 12 waves * 25 tiles

// ---------------- Kernel 0: transpose Wv -> bf16 WvT ----------------
__global__ void k0_wvt(const float* __restrict__ Wv, unsigned short* __restrict__ WvT) {
  int idx = blockIdx.x * 256 + threadIdx.x;
  if (idx < CDIM * CDIM) {
    int j = idx / CDIM, cp = idx % CDIM;
    WvT[idx] = bf16u_rne(Wv[(size_t)cp * CDIM + j]);
  }
}

// ---------------- Kernel A: convert fp32 -> swizzled bf16 Z tiles ------------
// grid (16 colgroups, 24 = 12 rowgroups x 2 tensors, NB).
// Thread: 8 consecutive floats x 8 rows. All 16 loads issued before any store
// (sched_barrier) -> 16 outstanding loads/wave. Stores are 16B (full swizzle unit).
__global__ __launch_bounds__(256) void convert_k(const float* __restrict__ input,
                                                 const float* __restrict__ color,
                                                 char* __restrict__ zbf) {
  const int cg = blockIdx.x, rgt = blockIdx.y, b = blockIdx.z;
  const int tensor = rgt >= 12;
  const int rg = (rgt - (tensor ? 12 : 0)) * 16;
  const int tid = threadIdx.x;
  const int c8 = (tid & 127) * 8;        // col (8 floats per thread)
  const int rbase = (tid >> 7) * 8;      // row half
  const float* X = (tensor ? color : input) +
                   (size_t)b * CDIM * HW + (size_t)(rg + rbase) * HW +
                   (size_t)cg * 1024 + c8;
  f32x4 v[16];
#pragma unroll
  for (int r = 0; r < 8; ++r) {
    v[2 * r] = *(const f32x4*)(X + (size_t)r * HW);
    v[2 * r + 1] = *(const f32x4*)(X + (size_t)r * HW + 4);
  }
  __builtin_amdgcn_sched_barrier(0);

  const int kcl = c8 >> 6;   // local tile within colgroup
  const int cit = c8 & 63;   // col within tile
  char* zt = zbf + ((size_t)b * 256 + cg * 16 + kcl) * TILE_B + (tensor ? 192 * 128 : 0);
#pragma unroll
  for (int r = 0; r < 8; ++r) {
    const int row = rg + rbase + r;
    S8U pk;
    pk.u[0] = pack_rne(v[2 * r][0], v[2 * r][1]);
    pk.u[1] = pack_rne(v[2 * r][2], v[2 * r][3]);
    pk.u[2] = pack_rne(v[2 * r + 1][0], v[2 * r + 1][1]);
    pk.u[3] = pack_rne(v[2 * r + 1][2], v[2 * r + 1][3]);
    *(short8*)(zt + row * 128 + ((cit * 2) ^ ((row & 7) << 4))) = pk.s;
  }
}

// ---------------- Kernel B: gram Z*Z^T (upper triangle), blocked partials ----
__device__ __forceinline__ short8 zfrag(const char* buf, int row, int ks, int lg) {
  return *(const short8*)(buf + row * 128 + ((ks * 64 + lg * 16) ^ ((row & 7) << 4)));
}

// 12 waves x 4 KB: covers the whole 48KB tile
__device__ __forceinline__ void stage48(const char* gsrc, char* ldst, int wave, int lane) {
#pragma unroll
  for (int i = 0; i < 4; ++i) {
    const int off = (wave * 4 + i) * 1024;
    __builtin_amdgcn_global_load_lds(
        (const __attribute__((address_space(1))) void*)(gsrc + off + lane * 16),
        (__attribute__((address_space(3))) void*)(ldst + off), 16, 0, 0);
  }
}

// wave W owns Z-tile rows {W, 23-W}: 25 upper-triangle tiles, all static indexing.
// slots: row W, col ct -> ct-W  (ct=W..23);  row 23-W, col ct -> ct+1 (ct=23-W..23)
template <int W>
__device__ __forceinline__ void pair_step(const char* buf, f32x4 (&acc)[25],
                                          int l15, int lg) {
#pragma unroll
  for (int ks = 0; ks < 2; ++ks) {
    const short8 aT = zfrag(buf, W * 16 + l15, ks, lg);
    const short8 aB = zfrag(buf, (23 - W) * 16 + l15, ks, lg);
#pragma unroll
    for (int ct = W; ct < 24; ++ct) {
      const short8 b = zfrag(buf, ct * 16 + l15, ks, lg);
      acc[ct - W] = MFMA16(aT, b, acc[ct - W]);
      if (ct >= 23 - W) acc[ct + 1] = MFMA16(aB, b, acc[ct + 1]);
    }
  }
}

__device__ __forceinline__ void pair_dispatch(int wave, const char* buf,
                                              f32x4 (&acc)[25], int l15, int lg) {
  switch (wave) {
    case 0: pair_step<0>(buf, acc, l15, lg); break;
    case 1: pair_step<1>(buf, acc, l15, lg); break;
    case 2: pair_step<2>(buf, acc, l15, lg); break;
    case 3: pair_step<3>(buf, acc, l15, lg); break;
    case 4: pair_step<4>(buf, acc, l15, lg); break;
    case 5: pair_step<5>(buf, acc, l15, lg); break;
    case 6: pair_step<6>(buf, acc, l15, lg); break;
    case 7: pair_step<7>(buf, acc, l15, lg); break;
    case 8: pair_step<8>(buf, acc, l15, lg); break;
    case 9: pair_step<9>(buf, acc, l15, lg); break;
    case 10: pair_step<10>(buf, acc, l15, lg); break;
    default: pair_step<11>(buf, acc, l15, lg); break;
  }
}

// grid (NPART, 8), 768 threads (12 waves), LDS 2x48KB double buffer.
__global__ __launch_bounds__(768) void gram2_k(const char* __restrict__ zbf,
                                               float* __restrict__ part,
                                               int npart, int cpb) {
  __shared__ __align__(16) char lds[2][TILE_B];
  const int tid = threadIdx.x, wave = tid >> 6, lane = tid & 63;
  const int l15 = lane & 15, lg = (lane >> 4) & 3;
  const int strip = blockIdx.x, b = blockIdx.y;
  const char* ztb = zbf + ((size_t)b * 256 + (size_t)strip * cpb) * TILE_B;

  f32x4 acc[25];
#pragma unroll
  for (int i = 0; i < 25; ++i) acc[i] = (f32x4){0.f, 0.f, 0.f, 0.f};

  stage48(ztb, lds[0], wave, lane);
#pragma unroll 1
  for (int c = 0; c < cpb - 1; ++c) {
    stage48(ztb + (size_t)(c + 1) * TILE_B, lds[(c + 1) & 1], wave, lane);
    asm volatile("s_waitcnt vmcnt(4)" ::: "memory");
    __builtin_amdgcn_sched_barrier(0);
    __builtin_amdgcn_s_barrier();
    pair_dispatch(wave, lds[c & 1], acc, l15, lg);
    asm volatile("s_waitcnt lgkmcnt(0)" ::: "memory");
    __builtin_amdgcn_sched_barrier(0);
    __builtin_amdgcn_s_barrier();
  }
  asm volatile("s_waitcnt vmcnt(0)" ::: "memory");
  __builtin_amdgcn_sched_barrier(0);
  __builtin_amdgcn_s_barrier();
  pair_dispatch(wave, lds[(cpb - 1) & 1], acc, l15, lg);

  // -------- blocked flush: one contiguous 1KB record per 16x16 tile --------
  float* pbase = part + (size_t)(b * npart + strip) * NTILE * 256;
#pragma unroll
  for (int s = 0; s < 25; ++s)
    *(f32x4*)(pbase + ((size_t)(wave * 25 + s) * 64 + lane) * 4) = acc[s];
}

// ---------------- reduce blocked partials -> G (both triangles) -------------
// grid (75, NB), 256 threads: 4 records per block, NP fully unrolled.
template <int NP>
__global__ __launch_bounds__(256) void reduce_k(const float* __restrict__ part,
                                                float* __restrict__ G) {
  const int b = blockIdx.y;
  const int T = blockIdx.x * 4 + (threadIdx.x >> 6);
  const int lane = threadIdx.x & 63;
  const float* p = part + ((size_t)b * NP * NTILE + T) * 256 + lane * 4;
  f32x4 v[NP];
#pragma unroll
  for (int s = 0; s < NP; ++s) v[s] = *(const f32x4*)(p + (size_t)s * NTILE * 256);
  f32x4 sum = v[0];
#pragma unroll
  for (int s = 1; s < NP; ++s) {
    sum[0] += v[s][0]; sum[1] += v[s][1]; sum[2] += v[s][2]; sum[3] += v[s][3];
  }
  // decode record T -> Z-tile (rt, ct) with rt <= ct
  const int w = T / 25, s = T % 25;
  int rt, ct;
  if (s <= 23 - w) { rt = w; ct = w + s; }
  else { rt = 23 - w; ct = s - 1; }
  // map Z-tile to G type: rows 0..11 = I, 12..23 = C
  int type, gm, gn;
  if (ct < 12) { type = 2; gm = rt; gn = ct; }            // I*I^T
  else if (rt < 12) { type = 0; gm = rt; gn = ct - 12; }  // I*C^T (full)
  else { type = 1; gm = rt - 12; gn = ct - 12; }          // C*C^T
  float* Gm = G + ((size_t)type * NB + b) * GSZ;
  const int l15 = lane & 15, lg = lane >> 4;
  const int row0 = gm * 16 + lg * 4, col = gn * 16 + l15;
#pragma unroll
  for (int r = 0; r < 4; ++r) Gm[(size_t)(row0 + r) * CDIM + col] = sum[r];
  if (type != 0 && rt != ct) {
#pragma unroll
    for (int r = 0; r < 4; ++r) Gm[(size_t)col * CDIM + (row0 + r)] = sum[r];
  }
}

// ---------------- Kernel 2a: A_pre (type0), nq (type1), nk (type2) ----------
__global__ __launch_bounds__(256) void k2a(const float* __restrict__ G,
                                           const float* __restrict__ Wq,
                                           const float* __restrict__ Wk,
                                           float* __restrict__ A_pre,
                                           float* __restrict__ nqk) {
  const int b = blockIdx.x, type = blockIdx.y;
  __shared__ __align__(16) unsigned short Hs[192][200];
  const int tid = threadIdx.x, wave = tid >> 6, lane = tid & 63;
  const int l15 = lane & 15, lg = lane >> 4, row0 = wave * 48;
  const float* W1 = (type == 2) ? Wk : Wq;
  const float* Gm = G + ((size_t)type * NB + b) * GSZ;

  f32x4 acc[3][12];
#pragma unroll
  for (int t = 0; t < 3; t++)
#pragma unroll
    for (int j = 0; j < 12; j++) acc[t][j] = (f32x4){0.f, 0.f, 0.f, 0.f};

  for (int ks = 0; ks < 192; ks += 32) {
    short8 afr[3];
#pragma unroll
    for (int t = 0; t < 3; t++)
      afr[t] = load_cvt8(W1 + (size_t)(row0 + t * 16 + l15) * CDIM + ks + lg * 8);
#pragma unroll
    for (int tj = 0; tj < 12; tj++) {
      short8 bfr = load_cvt8(Gm + (size_t)(tj * 16 + l15) * CDIM + ks + lg * 8);
#pragma unroll
      for (int t = 0; t < 3; t++) acc[t][tj] = MFMA16(afr[t], bfr, acc[t][tj]);
    }
  }
#pragma unroll
  for (int t = 0; t < 3; t++)
#pragma unroll
    for (int tj = 0; tj < 12; tj++)
#pragma unroll
      for (int r = 0; r < 4; r++)
        Hs[row0 + t * 16 + lg * 4 + r][tj * 16 + l15] = bf16u_rne(acc[t][tj][r]);
  __syncthreads();

  if (type == 0) {
    f32x4 a2[3][12];
#pragma unroll
    for (int t = 0; t < 3; t++)
#pragma unroll
      for (int j = 0; j < 12; j++) a2[t][j] = (f32x4){0.f, 0.f, 0.f, 0.f};
    for (int ks = 0; ks < 192; ks += 32) {
      short8 afr[3];
#pragma unroll
      for (int t = 0; t < 3; t++)
        afr[t] = *(const short8*)&Hs[row0 + t * 16 + l15][ks + lg * 8];
#pragma unroll
      for (int tj = 0; tj < 12; tj++) {
        short8 bfr = load_cvt8(Wk + (size_t)(tj * 16 + l15) * CDIM + ks + lg * 8);
#pragma unroll
        for (int t = 0; t < 3; t++) a2[t][tj] = MFMA16(afr[t], bfr, a2[t][tj]);
      }
    }
    float* Ab = A_pre + (size_t)b * GSZ;
#pragma unroll
    for (int t = 0; t < 3; t++)
#pragma unroll
      for (int tj = 0; tj < 12; tj++)
#pragma unroll
        for (int r = 0; r < 4; r++)
          Ab[(size_t)(row0 + t * 16 + lg * 4 + r) * CDIM + tj * 16 + l15] = a2[t][tj][r];
  } else {
    f32x4 a2[3];
#pragma unroll
    for (int t = 0; t < 3; t++) a2[t] = (f32x4){0.f, 0.f, 0.f, 0.f};
    for (int ks = 0; ks < 192; ks += 32) {
#pragma unroll
      for (int t = 0; t < 3; t++) {
        short8 afr = *(const short8*)&Hs[row0 + t * 16 + l15][ks + lg * 8];
        short8 bfr = load_cvt8(W1 + (size_t)(row0 + t * 16 + l15) * CDIM + ks + lg * 8);
        a2[t] = MFMA16(afr, bfr, a2[t]);
      }
    }
    float* dst = nqk + ((size_t)(type - 1) * NB + b) * CDIM;
#pragma unroll
    for (int t = 0; t < 3; t++)
#pragma unroll
      for (int r = 0; r < 4; r++)
        if (lg * 4 + r == l15) dst[row0 + t * 16 + l15] = a2[t][r];
  }
}

// ---------------- Kernel 2b: per-head softmax ----------------
__global__ void k2b(const float* __restrict__ A_pre, const float* __restrict__ nqk,
                    float* __restrict__ attnw) {
  const int b = blockIdx.x, tid = threadIdx.x;
  const int h = tid >> 5, r = tid & 31;
  if (r >= 24) return;
  const float* Ab = A_pre + (size_t)b * GSZ;
  const float* nq = nqk + (size_t)b * CDIM;
  const float* nk = nqk + (size_t)(NB + b) * CDIM;
  const int c = h * 24 + r;
  const float qn = rsqrtf(fmaxf(nq[c], 1e-24f));
  float e[24];
  float mx = -1e30f;
#pragma unroll
  for (int d = 0; d < 24; d++) {
    float kn = rsqrtf(fmaxf(nk[h * 24 + d], 1e-24f));
    float l = Ab[(size_t)c * CDIM + h * 24 + d] * qn * kn;
    e[d] = l;
    mx = fmaxf(mx, l);
  }
  float s = 0.f;
#pragma unroll
  for (int d = 0; d < 24; d++) {
    float x = __expf(e[d] - mx);
    e[d] = x;
    s += x;
  }
  const float inv = 1.0f / s;
  float* dst = attnw + (((size_t)b * NB + h) * 24 + r) * 24;
#pragma unroll
  for (int d = 0; d < 24; d++) dst[d] = e[d] * inv;
}

// ---------------- Kernel 3: P = Wo * blockdiag(attn) * Wv  (bf16 out) -------
__global__ __launch_bounds__(256) void k3(const float* __restrict__ attnw,
                                          const float* __restrict__ Wo,
                                          const unsigned short* __restrict__ WvT,
                                          unsigned short* __restrict__ Pbf) {
  const int b = blockIdx.x;
  __shared__ __align__(16) unsigned short AT[192][200];
  __shared__ __align__(16) unsigned short Ms[192][200];
  const int tid = threadIdx.x, wave = tid >> 6, lane = tid & 63;
  const int l15 = lane & 15, lg = lane >> 4, row0 = wave * 48;

  unsigned int* ATu = (unsigned int*)&AT[0][0];
  for (int i = tid; i < 192 * 100; i += 256) ATu[i] = 0u;
  __syncthreads();
  const float* at = attnw + (size_t)b * NB * 24 * 24;
  for (int i = tid; i < 4608; i += 256) {
    int h = i / 576, rem = i % 576, c = rem / 24, d = rem % 24;
    AT[h * 24 + d][h * 24 + c] = bf16u_rne(at[(h * 24 + c) * 24 + d]);
  }
  __syncthreads();

  f32x4 acc[3][12];
#pragma unroll
  for (int t = 0; t < 3; t++)
#pragma unroll
    for (int j = 0; j < 12; j++) acc[t][j] = (f32x4){0.f, 0.f, 0.f, 0.f};
  for (int ks = 0; ks < 192; ks += 32) {
    short8 afr[3];
#pragma unroll
    for (int t = 0; t < 3; t++)
      afr[t] = load_cvt8(Wo + (size_t)(row0 + t * 16 + l15) * CDIM + ks + lg * 8);
#pragma unroll
    for (int tj = 0; tj < 12; tj++) {
      short8 bfr = *(const short8*)&AT[tj * 16 + l15][ks + lg * 8];
#pragma unroll
      for (int t = 0; t < 3; t++) acc[t][tj] = MFMA16(afr[t], bfr, acc[t][tj]);
    }
  }
#pragma unroll
  for (int t = 0; t < 3; t++)
#pragma unroll
    for (int tj = 0; tj < 12; tj++)
#pragma unroll
      for (int r = 0; r < 4; r++)
        Ms[row0 + t * 16 + lg * 4 + r][tj * 16 + l15] = bf16u_rne(acc[t][tj][r]);
  __syncthreads();

  f32x4 a2[3][12];
#pragma unroll
  for (int t = 0; t < 3; t++)
#pragma unroll
    for (int j = 0; j < 12; j++) a2[t][j] = (f32x4){0.f, 0.f, 0.f, 0.f};
  for (int ks = 0; ks < 192; ks += 32) {
    short8 afr[3];
#pragma unroll
    for (int t = 0; t < 3; t++)
      afr[t] = *(const short8*)&Ms[row0 + t * 16 + l15][ks + lg * 8];
#pragma unroll
    for (int tj = 0; tj < 12; tj++) {
      short8 bfr = *(const short8*)(WvT + (size_t)(tj * 16 + l15) * CDIM + ks + lg * 8);
#pragma unroll
      for (int t = 0; t < 3; t++) a2[t][tj] = MFMA16(afr[t], bfr, a2[t][tj]);
    }
  }
  unsigned short* Pb = Pbf + (size_t)b * GSZ;
#pragma unroll
  for (int t = 0; t < 3; t++)
#pragma unroll
    for (int tj = 0; tj < 12; tj++)
#pragma unroll
      for (int r = 0; r < 4; r++)
        Pb[(size_t)(row0 + t * 16 + lg * 4 + r) * CDIM + tj * 16 + l15] = bf16u_rne(a2[t][tj][r]);
}

// ---------------- Kernel D: out = P @ input  ----------------
__global__ __launch_bounds__(256) void kD(const unsigned short* __restrict__ Pbf,
                                          const float* __restrict__ input,
                                          float* __restrict__ out) {
  const int nchunk = blockIdx.x, b = blockIdx.y;
  const int n0 = nchunk * 128;
  __shared__ __align__(16) char BsT[128 * 384];
  const int tid = threadIdx.x, wave = tid >> 6, lane = tid & 63;
  const int l15 = lane & 15, lg = lane >> 4, row0 = wave * 48;

  {
    const int n4 = (tid & 31) * 4;
    const int kb0 = (tid >> 5) * 4;
    const float* src = input + (size_t)b * CDIM * HW + n0 + n4;
    f32x4 w[24];
#pragma unroll
    for (int rnd = 0; rnd < 6; ++rnd)
#pragma unroll
      for (int j = 0; j < 4; ++j)
        w[rnd * 4 + j] = *(const f32x4*)(src + (size_t)(kb0 + rnd * 32 + j) * HW);
    __builtin_amdgcn_sched_barrier(0);
    char* bsb = BsT;
#pragma unroll
    for (int rnd = 0; rnd < 6; ++rnd) {
      const int kb = kb0 + rnd * 32;
#pragma unroll
      for (int i = 0; i < 4; ++i) {
        const int n = n4 + i;
        unsigned long long pk =
            (unsigned long long)pack_rne(w[rnd * 4 + 0][i], w[rnd * 4 + 1][i]) |
            ((unsigned long long)pack_rne(w[rnd * 4 + 2][i], w[rnd * 4 + 3][i]) << 32);
        *(unsigned long long*)(bsb + n * 384 + ((kb * 2) ^ ((n & 7) << 4))) = pk;
      }
    }
  }
  __syncthreads();

  f32x4 acc[3][8];
#pragma unroll
  for (int t = 0; t < 3; t++)
#pragma unroll
    for (int j = 0; j < 8; j++) acc[t][j] = (f32x4){0.f, 0.f, 0.f, 0.f};

  const unsigned short* Pb = Pbf + (size_t)b * GSZ;
#pragma unroll 2
  for (int ks = 0; ks < 6; ks++) {
    short8 afr[3];
#pragma unroll
    for (int t = 0; t < 3; t++)
      afr[t] = *(const short8*)(Pb + (size_t)(row0 + t * 16 + l15) * CDIM + ks * 32 + lg * 8);
#pragma unroll
    for (int tn = 0; tn < 8; tn++) {
      const int n = tn * 16 + l15;
      short8 bfr = *(const short8*)(BsT + n * 384 + ((ks * 64 + lg * 16) ^ ((n & 7) << 4)));
#pragma unroll
      for (int t = 0; t < 3; t++) acc[t][tn] = MFMA16(afr[t], bfr, acc[t][tn]);
    }
  }
  float* ob = out + (size_t)b * CDIM * HW + n0;
#pragma unroll
  for (int t = 0; t < 3; t++)
#pragma unroll
    for (int tn = 0; tn < 8; tn++)
#pragma unroll
      for (int r = 0; r < 4; r++) {
        const int m = row0 + t * 16 + lg * 4 + r;
        ob[(size_t)m * HW + tn * 16 + l15] = acc[t][tn][r];
      }
}

// ---------------- launch ----------------
extern "C" void kernel_launch(void* const* d_in, const int* in_sizes, int n_in,
                              void* d_out, int out_size, void* d_ws, size_t ws_size,
                              hipStream_t stream) {
  const float* input = (const float*)d_in[0];
  const float* color = (const float*)d_in[1];
  const float* Wq = (const float*)d_in[2];
  const float* Wk = (const float*)d_in[3];
  const float* Wv = (const float*)d_in[4];
  const float* Wo = (const float*)d_in[5];
  float* out = (float*)d_out;
  char* ws = (char*)d_ws;

  const size_t OFF_G = 0;                        // 3*8*192*192*4 = 3538944
  const size_t OFF_APRE = 3538944;               // 8*192*192*4  = 1179648
  const size_t OFF_NQK = OFF_APRE + 1179648;     // 2*8*192*4    = 12288
  const size_t OFF_ATT = OFF_NQK + 12288;        // 8*8*24*24*4  = 147456
  const size_t OFF_WVT = OFF_ATT + 147456;       // 192*192*2    = 73728
  const size_t OFF_PBF = OFF_WVT + 73728;        // 8*192*192*2  = 589824
  const size_t OFF_PART = OFF_PBF + 589824;      // npart*8*300*1024

  float* G = (float*)(ws + OFF_G);
  float* A_pre = (float*)(ws + OFF_APRE);
  float* nqk = (float*)(ws + OFF_NQK);
  float* attnw = (float*)(ws + OFF_ATT);
  unsigned short* WvT = (unsigned short*)(ws + OFF_WVT);
  unsigned short* Pbf = (unsigned short*)(ws + OFF_PBF);
  float* part = (float*)(ws + OFF_PART);

  // choose partial count from available workspace (deterministic per run)
  int npart = 32;
  while (npart > 2 && OFF_PART + (size_t)npart * NB * NTILE * 1024 > ws_size) npart >>= 1;
  const int cpb = 256 / npart;

  // Z (bf16, swizzled tiles) lives in d_out as scratch; kD overwrites it last.
  char* zbf = (char*)d_out;

  k0_wvt<<<dim3(144), dim3(256), 0, stream>>>(Wv, WvT);
  convert_k<<<dim3(16, 24, NB), dim3(256), 0, stream>>>(input, color, zbf);
  gram2_k<<<dim3(npart, NB), dim3(768), 0, stream>>>(zbf, part, npart, cpb);
  switch (npart) {
    case 32: reduce_k<32><<<dim3(75, NB), dim3(256), 0, stream>>>(part, G); break;
    case 16: reduce_k<16><<<dim3(75, NB), dim3(256), 0, stream>>>(part, G); break;
    case 8:  reduce_k<8><<<dim3(75, NB), dim3(256), 0, stream>>>(part, G); break;
    case 4:  reduce_k<4><<<dim3(75, NB), dim3(256), 0, stream>>>(part, G); break;
    default: reduce_k<2><<<dim3(75, NB), dim3(256), 0, stream>>>(part, G); break;
  }
  k2a<<<dim3(NB, 3), dim3(256), 0, stream>>>(G, Wq, Wk, A_pre, nqk);
  k2b<<<dim3(NB), dim3(256), 0, stream>>>(A_pre, nqk, attnw);
  k3<<<dim3(NB), dim3(256), 0, stream>>>(attnw, Wo, WvT, Pbf);
  kD<<<dim3(HW / 128, NB), dim3(256), 0, stream>>>(Pbf, input, out);
}

// Round 11
// 203.523 us; speedup vs baseline: 4.2364x; 1.1937x over previous
//
#include <hip/hip_runtime.h>
#include <hip/hip_bf16.h>

// Color_Attention: transposed (channel) attention.
//   gram2_k (fused): stages fp32 [I;C] 384x32 chunks direct to LDS via
//   global_load_lds, packs to bf16 in LDS (80B-stride rows, bank-even),
//   MFMA Z*Z^T upper triangle (24x24 tiles, 300 tiles) -> blocked partials.
//   reduce_k sums partials -> G {G_ic, G_cc, G_ii} (writes both triangles)
//   A_pre = Wq*G_ci*Wk^T ; nq = diag(Wq*G_cc*Wq^T); nk = diag(Wk*G_ii*Wk^T)
//   attn = softmax over head-diagonal 24x24 blocks of A_pre/(nq*nk)
//   P = Wo * blockdiag(attn) * Wv ; out = P @ input

typedef __attribute__((ext_vector_type(4))) float f32x4;
typedef __attribute__((ext_vector_type(8))) short short8;

#define MFMA16(a, b, c) __builtin_amdgcn_mfma_f32_16x16x32_bf16((a), (b), (c), 0, 0, 0)

__device__ __forceinline__ unsigned int pack_rne(float a, float b) {
  unsigned int ua = __float_as_uint(a), ub = __float_as_uint(b);
  ua += 0x7fffu + ((ua >> 16) & 1u);
  ub += 0x7fffu + ((ub >> 16) & 1u);
  return (ua >> 16) | (ub & 0xffff0000u);
}
__device__ __forceinline__ unsigned short bf16u_rne(float x) {
  unsigned int u = __float_as_uint(x);
  u += 0x7fffu + ((u >> 16) & 1u);
  return (unsigned short)(u >> 16);
}
union S8U { short8 s; unsigned int u[4]; };
__device__ __forceinline__ short8 load_cvt8(const float* p) {
  f32x4 x = *(const f32x4*)p;
  f32x4 y = *(const f32x4*)(p + 4);
  S8U r;
  r.u[0] = pack_rne(x[0], x[1]);
  r.u[1] = pack_rne(x[2], x[3]);
  r.u[2] = pack_rne(y[0], y[1]);
  r.u[3] = pack_rne(y[2], y[3]);
  return r.s;
}

#define HW 16384
#define CDIM 192
#define NB 8
#define GSZ (CDIM * CDIM)
#define NTILE 300     // blocked partial records per (b,strip): 12 waves * 25 tiles
#define FCHUNK 49152  // fp32 chunk: 384 rows x 32 cols x 4B
#define BROW 80       // bf16 buffer row stride (bank-even: quad = (5*row+lg)%8)

// ---------------- Kernel 0: transpose Wv -> bf16 WvT ----------------
__global__ void k0_wvt(const float* __restrict__ Wv, unsigned short* __restrict__ WvT) {
  int idx = blockIdx.x * 256 + threadIdx.x;
  if (idx < CDIM * CDIM) {
    int j = idx / CDIM, cp = idx % CDIM;
    WvT[idx] = bf16u_rne(Wv[(size_t)cp * CDIM + j]);
  }
}

// ---------------- Kernel B (fused): gram Z*Z^T, fp32 direct staging ----------
__device__ __forceinline__ short8 bfrag(const char* buf, int row, int lg) {
  return *(const short8*)(buf + row * BROW + lg * 16);
}

// stage one 384x32 fp32 chunk: 48 x 1KB gload_lds (4 per wave).
// instr covers 8 rows (8 lanes/row, 16B each). instr<24 -> input, else color.
__device__ __forceinline__ void stageF(const float* __restrict__ ib,
                                       const float* __restrict__ cb, int c0,
                                       char* fdst, int wave, int lane) {
#pragma unroll
  for (int i = 0; i < 4; ++i) {
    const int instr = wave * 4 + i;
    const int tensor = instr >= 24;
    const int rl = (instr - (tensor ? 24 : 0)) * 8 + (lane >> 3);
    const float* T = tensor ? cb : ib;
    const float* g = T + (size_t)rl * HW + c0 + (lane & 7) * 4;
    __builtin_amdgcn_global_load_lds(
        (const __attribute__((address_space(1))) void*)g,
        (__attribute__((address_space(3))) void*)(fdst + instr * 1024), 16, 0, 0);
  }
}

// wave W owns Z-tile rows {W, 23-W}: 25 upper-triangle tiles, static indexing.
// slots: row W, col ct -> ct-W (ct=W..23); row 23-W, col ct -> ct+1 (ct>=23-W)
template <int W>
__device__ __forceinline__ void pair_step(const char* bb, f32x4 (&acc)[25],
                                          int l15, int lg) {
  const short8 aT = bfrag(bb, W * 16 + l15, lg);
  const short8 aB = bfrag(bb, (23 - W) * 16 + l15, lg);
#pragma unroll
  for (int ct = W; ct < 24; ++ct) {
    const short8 b = bfrag(bb, ct * 16 + l15, lg);
    acc[ct - W] = MFMA16(aT, b, acc[ct - W]);
    if (ct >= 23 - W) acc[ct + 1] = MFMA16(aB, b, acc[ct + 1]);
  }
}

__device__ __forceinline__ void pair_dispatch(int wave, const char* bb,
                                              f32x4 (&acc)[25], int l15, int lg) {
  switch (wave) {
    case 0: pair_step<0>(bb, acc, l15, lg); break;
    case 1: pair_step<1>(bb, acc, l15, lg); break;
    case 2: pair_step<2>(bb, acc, l15, lg); break;
    case 3: pair_step<3>(bb, acc, l15, lg); break;
    case 4: pair_step<4>(bb, acc, l15, lg); break;
    case 5: pair_step<5>(bb, acc, l15, lg); break;
    case 6: pair_step<6>(bb, acc, l15, lg); break;
    case 7: pair_step<7>(bb, acc, l15, lg); break;
    case 8: pair_step<8>(bb, acc, l15, lg); break;
    case 9: pair_step<9>(bb, acc, l15, lg); break;
    case 10: pair_step<10>(bb, acc, l15, lg); break;
    default: pair_step<11>(bb, acc, l15, lg); break;
  }
}

// grid (NPART, 8), 768 threads (12 waves).
// LDS: fbuf 2x48KB fp32 double-buffer + bbuf 30KB bf16 = 129KB (1 block/CU).
__global__ __launch_bounds__(768) void gram2_k(const float* __restrict__ input,
                                               const float* __restrict__ color,
                                               float* __restrict__ part,
                                               int npart, int cpb) {
  __shared__ __align__(16) char fbuf[2][FCHUNK];
  __shared__ __align__(16) char bbuf[384 * BROW];
  const int tid = threadIdx.x, wave = tid >> 6, lane = tid & 63;
  const int l15 = lane & 15, lg = (lane >> 4) & 3;
  const int strip = blockIdx.x, b = blockIdx.y;
  const float* ib = input + (size_t)b * CDIM * HW;
  const float* cb = color + (size_t)b * CDIM * HW;
  const int cbase = strip * cpb;  // chunk index base (32-col chunks)

  f32x4 acc[25];
#pragma unroll
  for (int i = 0; i < 25; ++i) acc[i] = (f32x4){0.f, 0.f, 0.f, 0.f};

  stageF(ib, cb, cbase * 32, fbuf[0], wave, lane);
#pragma unroll 1
  for (int c = 0; c < cpb; ++c) {
    if (c + 1 < cpb) {
      stageF(ib, cb, (cbase + c + 1) * 32, fbuf[(c + 1) & 1], wave, lane);
      asm volatile("s_waitcnt vmcnt(4)" ::: "memory");
    } else {
      asm volatile("s_waitcnt vmcnt(0)" ::: "memory");
    }
    __builtin_amdgcn_sched_barrier(0);
    __builtin_amdgcn_s_barrier();
    // ---- pack fp32 -> bf16 bbuf (1536 units of 16B, 2 per thread) ----
    {
      const char* fb = fbuf[c & 1];
#pragma unroll
      for (int u0 = 0; u0 < 2; ++u0) {
        const int u = tid + u0 * 768;
        const int zr = u >> 2, sub = u & 3;
        const char* src = fb + zr * 128 + sub * 32;
        f32x4 x = *(const f32x4*)src;
        f32x4 y = *(const f32x4*)(src + 16);
        S8U pk;
        pk.u[0] = pack_rne(x[0], x[1]);
        pk.u[1] = pack_rne(x[2], x[3]);
        pk.u[2] = pack_rne(y[0], y[1]);
        pk.u[3] = pack_rne(y[2], y[3]);
        *(short8*)(bbuf + zr * BROW + sub * 16) = pk.s;
      }
    }
    asm volatile("s_waitcnt lgkmcnt(0)" ::: "memory");
    __builtin_amdgcn_sched_barrier(0);
    __builtin_amdgcn_s_barrier();
    pair_dispatch(wave, bbuf, acc, l15, lg);
  }

  // -------- blocked flush: one contiguous 1KB record per 16x16 tile --------
  float* pbase = part + (size_t)(b * npart + strip) * NTILE * 256;
#pragma unroll
  for (int s = 0; s < 25; ++s)
    *(f32x4*)(pbase + ((size_t)(wave * 25 + s) * 64 + lane) * 4) = acc[s];
}

// ---------------- reduce blocked partials -> G (both triangles) -------------
// grid (75, NB), 256 threads: 4 records per block, NP fully unrolled.
template <int NP>
__global__ __launch_bounds__(256) void reduce_k(const float* __restrict__ part,
                                                float* __restrict__ G) {
  const int b = blockIdx.y;
  const int T = blockIdx.x * 4 + (threadIdx.x >> 6);
  const int lane = threadIdx.x & 63;
  const float* p = part + ((size_t)b * NP * NTILE + T) * 256 + lane * 4;
  f32x4 v[NP];
#pragma unroll
  for (int s = 0; s < NP; ++s) v[s] = *(const f32x4*)(p + (size_t)s * NTILE * 256);
  f32x4 sum = v[0];
#pragma unroll
  for (int s = 1; s < NP; ++s) {
    sum[0] += v[s][0]; sum[1] += v[s][1]; sum[2] += v[s][2]; sum[3] += v[s][3];
  }
  // decode record T -> Z-tile (rt, ct) with rt <= ct
  const int w = T / 25, s = T % 25;
  int rt, ct;
  if (s <= 23 - w) { rt = w; ct = w + s; }
  else { rt = 23 - w; ct = s - 1; }
  // map Z-tile to G type: rows 0..11 = I, 12..23 = C
  int type, gm, gn;
  if (ct < 12) { type = 2; gm = rt; gn = ct; }            // I*I^T
  else if (rt < 12) { type = 0; gm = rt; gn = ct - 12; }  // I*C^T (full)
  else { type = 1; gm = rt - 12; gn = ct - 12; }          // C*C^T
  float* Gm = G + ((size_t)type * NB + b) * GSZ;
  const int l15 = lane & 15, lg = lane >> 4;
  const int row0 = gm * 16 + lg * 4, col = gn * 16 + l15;
#pragma unroll
  for (int r = 0; r < 4; ++r) Gm[(size_t)(row0 + r) * CDIM + col] = sum[r];
  if (type != 0 && rt != ct) {
#pragma unroll
    for (int r = 0; r < 4; ++r) Gm[(size_t)col * CDIM + (row0 + r)] = sum[r];
  }
}

// ---------------- Kernel 2a: A_pre (type0), nq (type1), nk (type2) ----------
__global__ __launch_bounds__(256) void k2a(const float* __restrict__ G,
                                           const float* __restrict__ Wq,
                                           const float* __restrict__ Wk,
                                           float* __restrict__ A_pre,
                                           float* __restrict__ nqk) {
  const int b = blockIdx.x, type = blockIdx.y;
  __shared__ __align__(16) unsigned short Hs[192][200];
  const int tid = threadIdx.x, wave = tid >> 6, lane = tid & 63;
  const int l15 = lane & 15, lg = lane >> 4, row0 = wave * 48;
  const float* W1 = (type == 2) ? Wk : Wq;
  const float* Gm = G + ((size_t)type * NB + b) * GSZ;

  f32x4 acc[3][12];
#pragma unroll
  for (int t = 0; t < 3; t++)
#pragma unroll
    for (int j = 0; j < 12; j++) acc[t][j] = (f32x4){0.f, 0.f, 0.f, 0.f};

  for (int ks = 0; ks < 192; ks += 32) {
    short8 afr[3];
#pragma unroll
    for (int t = 0; t < 3; t++)
      afr[t] = load_cvt8(W1 + (size_t)(row0 + t * 16 + l15) * CDIM + ks + lg * 8);
#pragma unroll
    for (int tj = 0; tj < 12; tj++) {
      short8 bfr = load_cvt8(Gm + (size_t)(tj * 16 + l15) * CDIM + ks + lg * 8);
#pragma unroll
      for (int t = 0; t < 3; t++) acc[t][tj] = MFMA16(afr[t], bfr, acc[t][tj]);
    }
  }
#pragma unroll
  for (int t = 0; t < 3; t++)
#pragma unroll
    for (int tj = 0; tj < 12; tj++)
#pragma unroll
      for (int r = 0; r < 4; r++)
        Hs[row0 + t * 16 + lg * 4 + r][tj * 16 + l15] = bf16u_rne(acc[t][tj][r]);
  __syncthreads();

  if (type == 0) {
    f32x4 a2[3][12];
#pragma unroll
    for (int t = 0; t < 3; t++)
#pragma unroll
      for (int j = 0; j < 12; j++) a2[t][j] = (f32x4){0.f, 0.f, 0.f, 0.f};
    for (int ks = 0; ks < 192; ks += 32) {
      short8 afr[3];
#pragma unroll
      for (int t = 0; t < 3; t++)
        afr[t] = *(const short8*)&Hs[row0 + t * 16 + l15][ks + lg * 8];
#pragma unroll
      for (int tj = 0; tj < 12; tj++) {
        short8 bfr = load_cvt8(Wk + (size_t)(tj * 16 + l15) * CDIM + ks + lg * 8);
#pragma unroll
        for (int t = 0; t < 3; t++) a2[t][tj] = MFMA16(afr[t], bfr, a2[t][tj]);
      }
    }
    float* Ab = A_pre + (size_t)b * GSZ;
#pragma unroll
    for (int t = 0; t < 3; t++)
#pragma unroll
      for (int tj = 0; tj < 12; tj++)
#pragma unroll
        for (int r = 0; r < 4; r++)
          Ab[(size_t)(row0 + t * 16 + lg * 4 + r) * CDIM + tj * 16 + l15] = a2[t][tj][r];
  } else {
    f32x4 a2[3];
#pragma unroll
    for (int t = 0; t < 3; t++) a2[t] = (f32x4){0.f, 0.f, 0.f, 0.f};
    for (int ks = 0; ks < 192; ks += 32) {
#pragma unroll
      for (int t = 0; t < 3; t++) {
        short8 afr = *(const short8*)&Hs[row0 + t * 16 + l15][ks + lg * 8];
        short8 bfr = load_cvt8(W1 + (size_t)(row0 + t * 16 + l15) * CDIM + ks + lg * 8);
        a2[t] = MFMA16(afr, bfr, a2[t]);
      }
    }
    float* dst = nqk + ((size_t)(type - 1) * NB + b) * CDIM;
#pragma unroll
    for (int t = 0; t < 3; t++)
#pragma unroll
      for (int r = 0; r < 4; r++)
        if (lg * 4 + r == l15) dst[row0 + t * 16 + l15] = a2[t][r];
  }
}

// ---------------- Kernel 2b: per-head softmax ----------------
__global__ void k2b(const float* __restrict__ A_pre, const float* __restrict__ nqk,
                    float* __restrict__ attnw) {
  const int b = blockIdx.x, tid = threadIdx.x;
  const int h = tid >> 5, r = tid & 31;
  if (r >= 24) return;
  const float* Ab = A_pre + (size_t)b * GSZ;
  const float* nq = nqk + (size_t)b * CDIM;
  const float* nk = nqk + (size_t)(NB + b) * CDIM;
  const int c = h * 24 + r;
  const float qn = rsqrtf(fmaxf(nq[c], 1e-24f));
  float e[24];
  float mx = -1e30f;
#pragma unroll
  for (int d = 0; d < 24; d++) {
    float kn = rsqrtf(fmaxf(nk[h * 24 + d], 1e-24f));
    float l = Ab[(size_t)c * CDIM + h * 24 + d] * qn * kn;
    e[d] = l;
    mx = fmaxf(mx, l);
  }
  float s = 0.f;
#pragma unroll
  for (int d = 0; d < 24; d++) {
    float x = __expf(e[d] - mx);
    e[d] = x;
    s += x;
  }
  const float inv = 1.0f / s;
  float* dst = attnw + (((size_t)b * NB + h) * 24 + r) * 24;
#pragma unroll
  for (int d = 0; d < 24; d++) dst[d] = e[d] * inv;
}

// ---------------- Kernel 3: P = Wo * blockdiag(attn) * Wv  (bf16 out) -------
__global__ __launch_bounds__(256) void k3(const float* __restrict__ attnw,
                                          const float* __restrict__ Wo,
                                          const unsigned short* __restrict__ WvT,
                                          unsigned short* __restrict__ Pbf) {
  const int b = blockIdx.x;
  __shared__ __align__(16) unsigned short AT[192][200];
  __shared__ __align__(16) unsigned short Ms[192][200];
  const int tid = threadIdx.x, wave = tid >> 6, lane = tid & 63;
  const int l15 = lane & 15, lg = lane >> 4, row0 = wave * 48;

  unsigned int* ATu = (unsigned int*)&AT[0][0];
  for (int i = tid; i < 192 * 100; i += 256) ATu[i] = 0u;
  __syncthreads();
  const float* at = attnw + (size_t)b * NB * 24 * 24;
  for (int i = tid; i < 4608; i += 256) {
    int h = i / 576, rem = i % 576, c = rem / 24, d = rem % 24;
    AT[h * 24 + d][h * 24 + c] = bf16u_rne(at[(h * 24 + c) * 24 + d]);
  }
  __syncthreads();

  f32x4 acc[3][12];
#pragma unroll
  for (int t = 0; t < 3; t++)
#pragma unroll
    for (int j = 0; j < 12; j++) acc[t][j] = (f32x4){0.f, 0.f, 0.f, 0.f};
  for (int ks = 0; ks < 192; ks += 32) {
    short8 afr[3];
#pragma unroll
    for (int t = 0; t < 3; t++)
      afr[t] = load_cvt8(Wo + (size_t)(row0 + t * 16 + l15) * CDIM + ks + lg * 8);
#pragma unroll
    for (int tj = 0; tj < 12; tj++) {
      short8 bfr = *(const short8*)&AT[tj * 16 + l15][ks + lg * 8];
#pragma unroll
      for (int t = 0; t < 3; t++) acc[t][tj] = MFMA16(afr[t], bfr, acc[t][tj]);
    }
  }
#pragma unroll
  for (int t = 0; t < 3; t++)
#pragma unroll
    for (int tj = 0; tj < 12; tj++)
#pragma unroll
      for (int r = 0; r < 4; r++)
        Ms[row0 + t * 16 + lg * 4 + r][tj * 16 + l15] = bf16u_rne(acc[t][tj][r]);
  __syncthreads();

  f32x4 a2[3][12];
#pragma unroll
  for (int t = 0; t < 3; t++)
#pragma unroll
    for (int j = 0; j < 12; j++) a2[t][j] = (f32x4){0.f, 0.f, 0.f, 0.f};
  for (int ks = 0; ks < 192; ks += 32) {
    short8 afr[3];
#pragma unroll
    for (int t = 0; t < 3; t++)
      afr[t] = *(const short8*)&Ms[row0 + t * 16 + l15][ks + lg * 8];
#pragma unroll
    for (int tj = 0; tj < 12; tj++) {
      short8 bfr = *(const short8*)(WvT + (size_t)(tj * 16 + l15) * CDIM + ks + lg * 8);
#pragma unroll
      for (int t = 0; t < 3; t++) a2[t][tj] = MFMA16(afr[t], bfr, a2[t][tj]);
    }
  }
  unsigned short* Pb = Pbf + (size_t)b * GSZ;
#pragma unroll
  for (int t = 0; t < 3; t++)
#pragma unroll
    for (int tj = 0; tj < 12; tj++)
#pragma unroll
      for (int r = 0; r < 4; r++)
        Pb[(size_t)(row0 + t * 16 + lg * 4 + r) * CDIM + tj * 16 + l15] = bf16u_rne(a2[t][tj][r]);
}

// ---------------- Kernel D: out = P @ input  ----------------
__global__ __launch_bounds__(256) void kD(const unsigned short* __restrict__ Pbf,
                                          const float* __restrict__ input,
                                          float* __restrict__ out) {
  const int nchunk = blockIdx.x, b = blockIdx.y;
  const int n0 = nchunk * 128;
  __shared__ __align__(16) char BsT[128 * 384];
  const int tid = threadIdx.x, wave = tid >> 6, lane = tid & 63;
  const int l15 = lane & 15, lg = lane >> 4, row0 = wave * 48;

  {
    const int n4 = (tid & 31) * 4;
    const int kb0 = (tid >> 5) * 4;
    const float* src = input + (size_t)b * CDIM * HW + n0 + n4;
    f32x4 w[24];
#pragma unroll
    for (int rnd = 0; rnd < 6; ++rnd)
#pragma unroll
      for (int j = 0; j < 4; ++j)
        w[rnd * 4 + j] = *(const f32x4*)(src + (size_t)(kb0 + rnd * 32 + j) * HW);
    __builtin_amdgcn_sched_barrier(0);
    char* bsb = BsT;
#pragma unroll
    for (int rnd = 0; rnd < 6; ++rnd) {
      const int kb = kb0 + rnd * 32;
#pragma unroll
      for (int i = 0; i < 4; ++i) {
        const int n = n4 + i;
        unsigned long long pk =
            (unsigned long long)pack_rne(w[rnd * 4 + 0][i], w[rnd * 4 + 1][i]) |
            ((unsigned long long)pack_rne(w[rnd * 4 + 2][i], w[rnd * 4 + 3][i]) << 32);
        *(unsigned long long*)(bsb + n * 384 + ((kb * 2) ^ ((n & 7) << 4))) = pk;
      }
    }
  }
  __syncthreads();

  f32x4 acc[3][8];
#pragma unroll
  for (int t = 0; t < 3; t++)
#pragma unroll
    for (int j = 0; j < 8; j++) acc[t][j] = (f32x4){0.f, 0.f, 0.f, 0.f};

  const unsigned short* Pb = Pbf + (size_t)b * GSZ;
#pragma unroll 2
  for (int ks = 0; ks < 6; ks++) {
    short8 afr[3];
#pragma unroll
    for (int t = 0; t < 3; t++)
      afr[t] = *(const short8*)(Pb + (size_t)(row0 + t * 16 + l15) * CDIM + ks * 32 + lg * 8);
#pragma unroll
    for (int tn = 0; tn < 8; tn++) {
      const int n = tn * 16 + l15;
      short8 bfr = *(const short8*)(BsT + n * 384 + ((ks * 64 + lg * 16) ^ ((n & 7) << 4)));
#pragma unroll
      for (int t = 0; t < 3; t++) acc[t][tn] = MFMA16(afr[t], bfr, acc[t][tn]);
    }
  }
  float* ob = out + (size_t)b * CDIM * HW + n0;
#pragma unroll
  for (int t = 0; t < 3; t++)
#pragma unroll
    for (int tn = 0; tn < 8; tn++)
#pragma unroll
      for (int r = 0; r < 4; r++) {
        const int m = row0 + t * 16 + lg * 4 + r;
        ob[(size_t)m * HW + tn * 16 + l15] = acc[t][tn][r];
      }
}

// ---------------- launch ----------------
extern "C" void kernel_launch(void* const* d_in, const int* in_sizes, int n_in,
                              void* d_out, int out_size, void* d_ws, size_t ws_size,
                              hipStream_t stream) {
  const float* input = (const float*)d_in[0];
  const float* color = (const float*)d_in[1];
  const float* Wq = (const float*)d_in[2];
  const float* Wk = (const float*)d_in[3];
  const float* Wv = (const float*)d_in[4];
  const float* Wo = (const float*)d_in[5];
  float* out = (float*)d_out;
  char* ws = (char*)d_ws;

  const size_t OFF_G = 0;                        // 3*8*192*192*4 = 3538944
  const size_t OFF_APRE = 3538944;               // 8*192*192*4  = 1179648
  const size_t OFF_NQK = OFF_APRE + 1179648;     // 2*8*192*4    = 12288
  const size_t OFF_ATT = OFF_NQK + 12288;        // 8*8*24*24*4  = 147456
  const size_t OFF_WVT = OFF_ATT + 147456;       // 192*192*2    = 73728
  const size_t OFF_PBF = OFF_WVT + 73728;        // 8*192*192*2  = 589824
  const size_t OFF_PART = OFF_PBF + 589824;      // npart*8*300*1024

  float* G = (float*)(ws + OFF_G);
  float* A_pre = (float*)(ws + OFF_APRE);
  float* nqk = (float*)(ws + OFF_NQK);
  float* attnw = (float*)(ws + OFF_ATT);
  unsigned short* WvT = (unsigned short*)(ws + OFF_WVT);
  unsigned short* Pbf = (unsigned short*)(ws + OFF_PBF);
  float* part = (float*)(ws + OFF_PART);

  // choose partial count from available workspace (deterministic per run)
  int npart = 32;
  while (npart > 2 && OFF_PART + (size_t)npart * NB * NTILE * 1024 > ws_size) npart >>= 1;
  const int cpb = 512 / npart;  // 32-col chunks per block

  k0_wvt<<<dim3(144), dim3(256), 0, stream>>>(Wv, WvT);
  gram2_k<<<dim3(npart, NB), dim3(768), 0, stream>>>(input, color, part, npart, cpb);
  switch (npart) {
    case 32: reduce_k<32><<<dim3(75, NB), dim3(256), 0, stream>>>(part, G); break;
    case 16: reduce_k<16><<<dim3(75, NB), dim3(256), 0, stream>>>(part, G); break;
    case 8:  reduce_k<8><<<dim3(75, NB), dim3(256), 0, stream>>>(part, G); break;
    case 4:  reduce_k<4><<<dim3(75, NB), dim3(256), 0, stream>>>(part, G); break;
    default: reduce_k<2><<<dim3(75, NB), dim3(256), 0, stream>>>(part, G); break;
  }
  k2a<<<dim3(NB, 3), dim3(256), 0, stream>>>(G, Wq, Wk, A_pre, nqk);
  k2b<<<dim3(NB), dim3(256), 0, stream>>>(A_pre, nqk, attnw);
  k3<<<dim3(NB), dim3(256), 0, stream>>>(attnw, Wo, WvT, Pbf);
  kD<<<dim3(HW / 128, NB), dim3(256), 0, stream>>>(Pbf, input, out);
}

// Round 12
// 198.732 us; speedup vs baseline: 4.3385x; 1.0241x over previous
//
#include <hip/hip_runtime.h>
#include <hip/hip_bf16.h>

// Color_Attention: transposed (channel) attention.
//   gram2_k (fused): stages fp32 [I;C] 384x16-col chunks direct to LDS via
//   global_load_lds (4-slot ring, 2 chunk-pairs in flight), packs pairs to
//   bf16 (80B-stride rows), MFMA Z*Z^T upper triangle -> blocked partials.
//   reduce_k sums partials -> G {G_ic, G_cc, G_ii} (writes both triangles)
//   A_pre = Wq*G_ci*Wk^T ; nq = diag(Wq*G_cc*Wq^T); nk = diag(Wk*G_ii*Wk^T)
//   attn = softmax over head-diagonal 24x24 blocks of A_pre/(nq*nk)
//   P = Wo * blockdiag(attn) * Wv ; out = P @ input

typedef __attribute__((ext_vector_type(4))) float f32x4;
typedef __attribute__((ext_vector_type(8))) short short8;

#define MFMA16(a, b, c) __builtin_amdgcn_mfma_f32_16x16x32_bf16((a), (b), (c), 0, 0, 0)

__device__ __forceinline__ unsigned int pack_rne(float a, float b) {
  unsigned int ua = __float_as_uint(a), ub = __float_as_uint(b);
  ua += 0x7fffu + ((ua >> 16) & 1u);
  ub += 0x7fffu + ((ub >> 16) & 1u);
  return (ua >> 16) | (ub & 0xffff0000u);
}
__device__ __forceinline__ unsigned short bf16u_rne(float x) {
  unsigned int u = __float_as_uint(x);
  u += 0x7fffu + ((u >> 16) & 1u);
  return (unsigned short)(u >> 16);
}
union S8U { short8 s; unsigned int u[4]; };
__device__ __forceinline__ short8 load_cvt8(const float* p) {
  f32x4 x = *(const f32x4*)p;
  f32x4 y = *(const f32x4*)(p + 4);
  S8U r;
  r.u[0] = pack_rne(x[0], x[1]);
  r.u[1] = pack_rne(x[2], x[3]);
  r.u[2] = pack_rne(y[0], y[1]);
  r.u[3] = pack_rne(y[2], y[3]);
  return r.s;
}

#define HW 16384
#define CDIM 192
#define NB 8
#define GSZ (CDIM * CDIM)
#define NTILE 300     // blocked partial records per (b,strip): 12 waves * 25 tiles
#define FSLOT 24576   // fp32 slot: 384 rows x 16 cols x 4B (64B/row)
#define BROW 80       // bf16 buffer row stride (reads 2-way/free)

// ---------------- Kernel 0: transpose Wv -> bf16 WvT ----------------
__global__ void k0_wvt(const float* __restrict__ Wv, unsigned short* __restrict__ WvT) {
  int idx = blockIdx.x * 256 + threadIdx.x;
  if (idx < CDIM * CDIM) {
    int j = idx / CDIM, cp = idx % CDIM;
    WvT[idx] = bf16u_rne(Wv[(size_t)cp * CDIM + j]);
  }
}

// ---------------- Kernel B (fused): gram Z*Z^T, fp32 direct staging ----------
__device__ __forceinline__ short8 bfrag(const char* buf, int row, int lg) {
  return *(const short8*)(buf + row * BROW + lg * 16);
}

// stage one 384x16-col fp32 chunk: 24 x 1KB gload_lds (2 per wave).
// instr g covers 16 rows (4 lanes/row, 16B each); g<12 -> input, else color.
// LDS dst offset g*1024 + lane*16 == (tensor*192 + (g%12)*16 + lane>>2)*64 + (lane&3)*16.
__device__ __forceinline__ void stageC(const float* __restrict__ ib,
                                       const float* __restrict__ cb, int col0,
                                       char* fdst, int wave, int lane) {
#pragma unroll
  for (int i = 0; i < 2; ++i) {
    const int g = wave * 2 + i;  // 0..23
    const int tensor = g >= 12;
    const int row = (g - (tensor ? 12 : 0)) * 16 + (lane >> 2);
    const float* T = tensor ? cb : ib;
    const float* gp = T + (size_t)row * HW + col0 + (lane & 3) * 4;
    __builtin_amdgcn_global_load_lds(
        (const __attribute__((address_space(1))) void*)gp,
        (__attribute__((address_space(3))) void*)(fdst + g * 1024), 16, 0, 0);
  }
}

// wave W owns Z-tile rows {W, 23-W}: 25 upper-triangle tiles, static indexing.
// slots: row W, col ct -> ct-W (ct=W..23); row 23-W, col ct -> ct+1 (ct>=23-W)
template <int W>
__device__ __forceinline__ void pair_step(const char* bb, f32x4 (&acc)[25],
                                          int l15, int lg) {
  const short8 aT = bfrag(bb, W * 16 + l15, lg);
  const short8 aB = bfrag(bb, (23 - W) * 16 + l15, lg);
#pragma unroll
  for (int ct = W; ct < 24; ++ct) {
    const short8 b = bfrag(bb, ct * 16 + l15, lg);
    acc[ct - W] = MFMA16(aT, b, acc[ct - W]);
    if (ct >= 23 - W) acc[ct + 1] = MFMA16(aB, b, acc[ct + 1]);
  }
}

__device__ __forceinline__ void pair_dispatch(int wave, const char* bb,
                                              f32x4 (&acc)[25], int l15, int lg) {
  switch (wave) {
    case 0: pair_step<0>(bb, acc, l15, lg); break;
    case 1: pair_step<1>(bb, acc, l15, lg); break;
    case 2: pair_step<2>(bb, acc, l15, lg); break;
    case 3: pair_step<3>(bb, acc, l15, lg); break;
    case 4: pair_step<4>(bb, acc, l15, lg); break;
    case 5: pair_step<5>(bb, acc, l15, lg); break;
    case 6: pair_step<6>(bb, acc, l15, lg); break;
    case 7: pair_step<7>(bb, acc, l15, lg); break;
    case 8: pair_step<8>(bb, acc, l15, lg); break;
    case 9: pair_step<9>(bb, acc, l15, lg); break;
    case 10: pair_step<10>(bb, acc, l15, lg); break;
    default: pair_step<11>(bb, acc, l15, lg); break;
  }
}

// grid (NPART, 8), 768 threads (12 waves).
// LDS: fbuf 4x24KB slot ring + bbuf 30KB bf16 = 126KB (1 block/CU).
// Schedule per pair cp: wait vmcnt(4) [pair cp landed, cp+1 in flight] ->
// barrier -> pack(cp) -> lgkm+barrier -> issue pair cp+2 (slots safe) -> MFMA.
__global__ __launch_bounds__(768) void gram2_k(const float* __restrict__ input,
                                               const float* __restrict__ color,
                                               float* __restrict__ part,
                                               int npart, int ncp) {
  __shared__ __align__(16) char fbuf[4][FSLOT];
  __shared__ __align__(16) char bbuf[384 * BROW];
  const int tid = threadIdx.x, wave = tid >> 6, lane = tid & 63;
  const int l15 = lane & 15, lg = (lane >> 4) & 3;
  const int strip = blockIdx.x, b = blockIdx.y;
  const float* ib = input + (size_t)b * CDIM * HW;
  const float* cb = color + (size_t)b * CDIM * HW;
  const int ch0 = strip * ncp * 2;  // base chunk (16-col units)

  f32x4 acc[25];
#pragma unroll
  for (int i = 0; i < 25; ++i) acc[i] = (f32x4){0.f, 0.f, 0.f, 0.f};

  stageC(ib, cb, (ch0 + 0) * 16, fbuf[0], wave, lane);
  stageC(ib, cb, (ch0 + 1) * 16, fbuf[1], wave, lane);
  stageC(ib, cb, (ch0 + 2) * 16, fbuf[2], wave, lane);
  stageC(ib, cb, (ch0 + 3) * 16, fbuf[3], wave, lane);

#pragma unroll 1
  for (int cp = 0; cp < ncp; ++cp) {
    if (cp + 1 < ncp) {
      asm volatile("s_waitcnt vmcnt(4)" ::: "memory");
    } else {
      asm volatile("s_waitcnt vmcnt(0)" ::: "memory");
    }
    __builtin_amdgcn_sched_barrier(0);
    __builtin_amdgcn_s_barrier();
    // ---- pack pair cp: 1536 units (32B fp32 -> 16B bf16), 2 per thread ----
    {
      const char* sA = fbuf[(2 * cp) & 3];
      const char* sB = fbuf[(2 * cp + 1) & 3];
#pragma unroll
      for (int u0 = 0; u0 < 2; ++u0) {
        const int u = tid + u0 * 768;
        const int zr = u >> 2, sub = u & 3;
        const char* src = (sub < 2 ? sA : sB) + zr * 64 + (sub & 1) * 32;
        f32x4 x = *(const f32x4*)src;
        f32x4 y = *(const f32x4*)(src + 16);
        S8U pk;
        pk.u[0] = pack_rne(x[0], x[1]);
        pk.u[1] = pack_rne(x[2], x[3]);
        pk.u[2] = pack_rne(y[0], y[1]);
        pk.u[3] = pack_rne(y[2], y[3]);
        *(short8*)(bbuf + zr * BROW + sub * 16) = pk.s;
      }
    }
    asm volatile("s_waitcnt lgkmcnt(0)" ::: "memory");
    __builtin_amdgcn_sched_barrier(0);
    __builtin_amdgcn_s_barrier();
    if (cp + 2 < ncp) {
      stageC(ib, cb, (ch0 + 2 * cp + 4) * 16, fbuf[(2 * cp + 4) & 3], wave, lane);
      stageC(ib, cb, (ch0 + 2 * cp + 5) * 16, fbuf[(2 * cp + 5) & 3], wave, lane);
    }
    pair_dispatch(wave, bbuf, acc, l15, lg);
  }

  // -------- blocked flush: one contiguous 1KB record per 16x16 tile --------
  float* pbase = part + (size_t)(b * npart + strip) * NTILE * 256;
#pragma unroll
  for (int s = 0; s < 25; ++s)
    *(f32x4*)(pbase + ((size_t)(wave * 25 + s) * 64 + lane) * 4) = acc[s];
}

// ---------------- reduce blocked partials -> G (both triangles) -------------
// grid (75, NB), 256 threads: 4 records per block, NP fully unrolled.
template <int NP>
__global__ __launch_bounds__(256) void reduce_k(const float* __restrict__ part,
                                                float* __restrict__ G) {
  const int b = blockIdx.y;
  const int T = blockIdx.x * 4 + (threadIdx.x >> 6);
  const int lane = threadIdx.x & 63;
  const float* p = part + ((size_t)b * NP * NTILE + T) * 256 + lane * 4;
  f32x4 v[NP];
#pragma unroll
  for (int s = 0; s < NP; ++s) v[s] = *(const f32x4*)(p + (size_t)s * NTILE * 256);
  f32x4 sum = v[0];
#pragma unroll
  for (int s = 1; s < NP; ++s) {
    sum[0] += v[s][0]; sum[1] += v[s][1]; sum[2] += v[s][2]; sum[3] += v[s][3];
  }
  // decode record T -> Z-tile (rt, ct) with rt <= ct
  const int w = T / 25, s = T % 25;
  int rt, ct;
  if (s <= 23 - w) { rt = w; ct = w + s; }
  else { rt = 23 - w; ct = s - 1; }
  // map Z-tile to G type: rows 0..11 = I, 12..23 = C
  int type, gm, gn;
  if (ct < 12) { type = 2; gm = rt; gn = ct; }            // I*I^T
  else if (rt < 12) { type = 0; gm = rt; gn = ct - 12; }  // I*C^T (full)
  else { type = 1; gm = rt - 12; gn = ct - 12; }          // C*C^T
  float* Gm = G + ((size_t)type * NB + b) * GSZ;
  const int l15 = lane & 15, lg = lane >> 4;
  const int row0 = gm * 16 + lg * 4, col = gn * 16 + l15;
#pragma unroll
  for (int r = 0; r < 4; ++r) Gm[(size_t)(row0 + r) * CDIM + col] = sum[r];
  if (type != 0 && rt != ct) {
#pragma unroll
    for (int r = 0; r < 4; ++r) Gm[(size_t)col * CDIM + (row0 + r)] = sum[r];
  }
}

// ---------------- Kernel 2a: A_pre (type0), nq (type1), nk (type2) ----------
__global__ __launch_bounds__(256) void k2a(const float* __restrict__ G,
                                           const float* __restrict__ Wq,
                                           const float* __restrict__ Wk,
                                           float* __restrict__ A_pre,
                                           float* __restrict__ nqk) {
  const int b = blockIdx.x, type = blockIdx.y;
  __shared__ __align__(16) unsigned short Hs[192][200];
  const int tid = threadIdx.x, wave = tid >> 6, lane = tid & 63;
  const int l15 = lane & 15, lg = lane >> 4, row0 = wave * 48;
  const float* W1 = (type == 2) ? Wk : Wq;
  const float* Gm = G + ((size_t)type * NB + b) * GSZ;

  f32x4 acc[3][12];
#pragma unroll
  for (int t = 0; t < 3; t++)
#pragma unroll
    for (int j = 0; j < 12; j++) acc[t][j] = (f32x4){0.f, 0.f, 0.f, 0.f};

  for (int ks = 0; ks < 192; ks += 32) {
    short8 afr[3];
#pragma unroll
    for (int t = 0; t < 3; t++)
      afr[t] = load_cvt8(W1 + (size_t)(row0 + t * 16 + l15) * CDIM + ks + lg * 8);
#pragma unroll
    for (int tj = 0; tj < 12; tj++) {
      short8 bfr = load_cvt8(Gm + (size_t)(tj * 16 + l15) * CDIM + ks + lg * 8);
#pragma unroll
      for (int t = 0; t < 3; t++) acc[t][tj] = MFMA16(afr[t], bfr, acc[t][tj]);
    }
  }
#pragma unroll
  for (int t = 0; t < 3; t++)
#pragma unroll
    for (int tj = 0; tj < 12; tj++)
#pragma unroll
      for (int r = 0; r < 4; r++)
        Hs[row0 + t * 16 + lg * 4 + r][tj * 16 + l15] = bf16u_rne(acc[t][tj][r]);
  __syncthreads();

  if (type == 0) {
    f32x4 a2[3][12];
#pragma unroll
    for (int t = 0; t < 3; t++)
#pragma unroll
      for (int j = 0; j < 12; j++) a2[t][j] = (f32x4){0.f, 0.f, 0.f, 0.f};
    for (int ks = 0; ks < 192; ks += 32) {
      short8 afr[3];
#pragma unroll
      for (int t = 0; t < 3; t++)
        afr[t] = *(const short8*)&Hs[row0 + t * 16 + l15][ks + lg * 8];
#pragma unroll
      for (int tj = 0; tj < 12; tj++) {
        short8 bfr = load_cvt8(Wk + (size_t)(tj * 16 + l15) * CDIM + ks + lg * 8);
#pragma unroll
        for (int t = 0; t < 3; t++) a2[t][tj] = MFMA16(afr[t], bfr, a2[t][tj]);
      }
    }
    float* Ab = A_pre + (size_t)b * GSZ;
#pragma unroll
    for (int t = 0; t < 3; t++)
#pragma unroll
      for (int tj = 0; tj < 12; tj++)
#pragma unroll
        for (int r = 0; r < 4; r++)
          Ab[(size_t)(row0 + t * 16 + lg * 4 + r) * CDIM + tj * 16 + l15] = a2[t][tj][r];
  } else {
    f32x4 a2[3];
#pragma unroll
    for (int t = 0; t < 3; t++) a2[t] = (f32x4){0.f, 0.f, 0.f, 0.f};
    for (int ks = 0; ks < 192; ks += 32) {
#pragma unroll
      for (int t = 0; t < 3; t++) {
        short8 afr = *(const short8*)&Hs[row0 + t * 16 + l15][ks + lg * 8];
        short8 bfr = load_cvt8(W1 + (size_t)(row0 + t * 16 + l15) * CDIM + ks + lg * 8);
        a2[t] = MFMA16(afr, bfr, a2[t]);
      }
    }
    float* dst = nqk + ((size_t)(type - 1) * NB + b) * CDIM;
#pragma unroll
    for (int t = 0; t < 3; t++)
#pragma unroll
      for (int r = 0; r < 4; r++)
        if (lg * 4 + r == l15) dst[row0 + t * 16 + l15] = a2[t][r];
  }
}

// ---------------- Kernel 2b: per-head softmax ----------------
__global__ void k2b(const float* __restrict__ A_pre, const float* __restrict__ nqk,
                    float* __restrict__ attnw) {
  const int b = blockIdx.x, tid = threadIdx.x;
  const int h = tid >> 5, r = tid & 31;
  if (r >= 24) return;
  const float* Ab = A_pre + (size_t)b * GSZ;
  const float* nq = nqk + (size_t)b * CDIM;
  const float* nk = nqk + (size_t)(NB + b) * CDIM;
  const int c = h * 24 + r;
  const float qn = rsqrtf(fmaxf(nq[c], 1e-24f));
  float e[24];
  float mx = -1e30f;
#pragma unroll
  for (int d = 0; d < 24; d++) {
    float kn = rsqrtf(fmaxf(nk[h * 24 + d], 1e-24f));
    float l = Ab[(size_t)c * CDIM + h * 24 + d] * qn * kn;
    e[d] = l;
    mx = fmaxf(mx, l);
  }
  float s = 0.f;
#pragma unroll
  for (int d = 0; d < 24; d++) {
    float x = __expf(e[d] - mx);
    e[d] = x;
    s += x;
  }
  const float inv = 1.0f / s;
  float* dst = attnw + (((size_t)b * NB + h) * 24 + r) * 24;
#pragma unroll
  for (int d = 0; d < 24; d++) dst[d] = e[d] * inv;
}

// ---------------- Kernel 3: P = Wo * blockdiag(attn) * Wv  (bf16 out) -------
__global__ __launch_bounds__(256) void k3(const float* __restrict__ attnw,
                                          const float* __restrict__ Wo,
                                          const unsigned short* __restrict__ WvT,
                                          unsigned short* __restrict__ Pbf) {
  const int b = blockIdx.x;
  __shared__ __align__(16) unsigned short AT[192][200];
  __shared__ __align__(16) unsigned short Ms[192][200];
  const int tid = threadIdx.x, wave = tid >> 6, lane = tid & 63;
  const int l15 = lane & 15, lg = lane >> 4, row0 = wave * 48;

  unsigned int* ATu = (unsigned int*)&AT[0][0];
  for (int i = tid; i < 192 * 100; i += 256) ATu[i] = 0u;
  __syncthreads();
  const float* at = attnw + (size_t)b * NB * 24 * 24;
  for (int i = tid; i < 4608; i += 256) {
    int h = i / 576, rem = i % 576, c = rem / 24, d = rem % 24;
    AT[h * 24 + d][h * 24 + c] = bf16u_rne(at[(h * 24 + c) * 24 + d]);
  }
  __syncthreads();

  f32x4 acc[3][12];
#pragma unroll
  for (int t = 0; t < 3; t++)
#pragma unroll
    for (int j = 0; j < 12; j++) acc[t][j] = (f32x4){0.f, 0.f, 0.f, 0.f};
  for (int ks = 0; ks < 192; ks += 32) {
    short8 afr[3];
#pragma unroll
    for (int t = 0; t < 3; t++)
      afr[t] = load_cvt8(Wo + (size_t)(row0 + t * 16 + l15) * CDIM + ks + lg * 8);
#pragma unroll
    for (int tj = 0; tj < 12; tj++) {
      short8 bfr = *(const short8*)&AT[tj * 16 + l15][ks + lg * 8];
#pragma unroll
      for (int t = 0; t < 3; t++) acc[t][tj] = MFMA16(afr[t], bfr, acc[t][tj]);
    }
  }
#pragma unroll
  for (int t = 0; t < 3; t++)
#pragma unroll
    for (int tj = 0; tj < 12; tj++)
#pragma unroll
      for (int r = 0; r < 4; r++)
        Ms[row0 + t * 16 + lg * 4 + r][tj * 16 + l15] = bf16u_rne(acc[t][tj][r]);
  __syncthreads();

  f32x4 a2[3][12];
#pragma unroll
  for (int t = 0; t < 3; t++)
#pragma unroll
    for (int j = 0; j < 12; j++) a2[t][j] = (f32x4){0.f, 0.f, 0.f, 0.f};
  for (int ks = 0; ks < 192; ks += 32) {
    short8 afr[3];
#pragma unroll
    for (int t = 0; t < 3; t++)
      afr[t] = *(const short8*)&Ms[row0 + t * 16 + l15][ks + lg * 8];
#pragma unroll
    for (int tj = 0; tj < 12; tj++) {
      short8 bfr = *(const short8*)(WvT + (size_t)(tj * 16 + l15) * CDIM + ks + lg * 8);
#pragma unroll
      for (int t = 0; t < 3; t++) a2[t][tj] = MFMA16(afr[t], bfr, a2[t][tj]);
    }
  }
  unsigned short* Pb = Pbf + (size_t)b * GSZ;
#pragma unroll
  for (int t = 0; t < 3; t++)
#pragma unroll
    for (int tj = 0; tj < 12; tj++)
#pragma unroll
      for (int r = 0; r < 4; r++)
        Pb[(size_t)(row0 + t * 16 + lg * 4 + r) * CDIM + tj * 16 + l15] = bf16u_rne(a2[t][tj][r]);
}

// ---------------- Kernel D: out = P @ input  ----------------
__global__ __launch_bounds__(256) void kD(const unsigned short* __restrict__ Pbf,
                                          const float* __restrict__ input,
                                          float* __restrict__ out) {
  const int nchunk = blockIdx.x, b = blockIdx.y;
  const int n0 = nchunk * 128;
  __shared__ __align__(16) char BsT[128 * 384];
  const int tid = threadIdx.x, wave = tid >> 6, lane = tid & 63;
  const int l15 = lane & 15, lg = lane >> 4, row0 = wave * 48;

  {
    const int n4 = (tid & 31) * 4;
    const int kb0 = (tid >> 5) * 4;
    const float* src = input + (size_t)b * CDIM * HW + n0 + n4;
    f32x4 w[24];
#pragma unroll
    for (int rnd = 0; rnd < 6; ++rnd)
#pragma unroll
      for (int j = 0; j < 4; ++j)
        w[rnd * 4 + j] = *(const f32x4*)(src + (size_t)(kb0 + rnd * 32 + j) * HW);
    __builtin_amdgcn_sched_barrier(0);
    char* bsb = BsT;
#pragma unroll
    for (int rnd = 0; rnd < 6; ++rnd) {
      const int kb = kb0 + rnd * 32;
#pragma unroll
      for (int i = 0; i < 4; ++i) {
        const int n = n4 + i;
        unsigned long long pk =
            (unsigned long long)pack_rne(w[rnd * 4 + 0][i], w[rnd * 4 + 1][i]) |
            ((unsigned long long)pack_rne(w[rnd * 4 + 2][i], w[rnd * 4 + 3][i]) << 32);
        *(unsigned long long*)(bsb + n * 384 + ((kb * 2) ^ ((n & 7) << 4))) = pk;
      }
    }
  }
  __syncthreads();

  f32x4 acc[3][8];
#pragma unroll
  for (int t = 0; t < 3; t++)
#pragma unroll
    for (int j = 0; j < 8; j++) acc[t][j] = (f32x4){0.f, 0.f, 0.f, 0.f};

  const unsigned short* Pb = Pbf + (size_t)b * GSZ;
#pragma unroll 2
  for (int ks = 0; ks < 6; ks++) {
    short8 afr[3];
#pragma unroll
    for (int t = 0; t < 3; t++)
      afr[t] = *(const short8*)(Pb + (size_t)(row0 + t * 16 + l15) * CDIM + ks * 32 + lg * 8);
#pragma unroll
    for (int tn = 0; tn < 8; tn++) {
      const int n = tn * 16 + l15;
      short8 bfr = *(const short8*)(BsT + n * 384 + ((ks * 64 + lg * 16) ^ ((n & 7) << 4)));
#pragma unroll
      for (int t = 0; t < 3; t++) acc[t][tn] = MFMA16(afr[t], bfr, acc[t][tn]);
    }
  }
  float* ob = out + (size_t)b * CDIM * HW + n0;
#pragma unroll
  for (int t = 0; t < 3; t++)
#pragma unroll
    for (int tn = 0; tn < 8; tn++)
#pragma unroll
      for (int r = 0; r < 4; r++) {
        const int m = row0 + t * 16 + lg * 4 + r;
        ob[(size_t)m * HW + tn * 16 + l15] = acc[t][tn][r];
      }
}

// ---------------- launch ----------------
extern "C" void kernel_launch(void* const* d_in, const int* in_sizes, int n_in,
                              void* d_out, int out_size, void* d_ws, size_t ws_size,
                              hipStream_t stream) {
  const float* input = (const float*)d_in[0];
  const float* color = (const float*)d_in[1];
  const float* Wq = (const float*)d_in[2];
  const float* Wk = (const float*)d_in[3];
  const float* Wv = (const float*)d_in[4];
  const float* Wo = (const float*)d_in[5];
  float* out = (float*)d_out;
  char* ws = (char*)d_ws;

  const size_t OFF_G = 0;                        // 3*8*192*192*4 = 3538944
  const size_t OFF_APRE = 3538944;               // 8*192*192*4  = 1179648
  const size_t OFF_NQK = OFF_APRE + 1179648;     // 2*8*192*4    = 12288
  const size_t OFF_ATT = OFF_NQK + 12288;        // 8*8*24*24*4  = 147456
  const size_t OFF_WVT = OFF_ATT + 147456;       // 192*192*2    = 73728
  const size_t OFF_PBF = OFF_WVT + 73728;        // 8*192*192*2  = 589824
  const size_t OFF_PART = OFF_PBF + 589824;      // npart*8*300*1024

  float* G = (float*)(ws + OFF_G);
  float* A_pre = (float*)(ws + OFF_APRE);
  float* nqk = (float*)(ws + OFF_NQK);
  float* attnw = (float*)(ws + OFF_ATT);
  unsigned short* WvT = (unsigned short*)(ws + OFF_WVT);
  unsigned short* Pbf = (unsigned short*)(ws + OFF_PBF);
  float* part = (float*)(ws + OFF_PART);

  // choose partial count from available workspace (deterministic per run)
  int npart = 32;
  while (npart > 2 && OFF_PART + (size_t)npart * NB * NTILE * 1024 > ws_size) npart >>= 1;
  const int ncp = 512 / npart;  // chunk-pairs (32 cols each) per block

  k0_wvt<<<dim3(144), dim3(256), 0, stream>>>(Wv, WvT);
  gram2_k<<<dim3(npart, NB), dim3(768), 0, stream>>>(input, color, part, npart, ncp);
  switch (npart) {
    case 32: reduce_k<32><<<dim3(75, NB), dim3(256), 0, stream>>>(part, G); break;
    case 16: reduce_k<16><<<dim3(75, NB), dim3(256), 0, stream>>>(part, G); break;
    case 8:  reduce_k<8><<<dim3(75, NB), dim3(256), 0, stream>>>(part, G); break;
    case 4:  reduce_k<4><<<dim3(75, NB), dim3(256), 0, stream>>>(part, G); break;
    default: reduce_k<2><<<dim3(75, NB), dim3(256), 0, stream>>>(part, G); break;
  }
  k2a<<<dim3(NB, 3), dim3(256), 0, stream>>>(G, Wq, Wk, A_pre, nqk);
  k2b<<<dim3(NB), dim3(256), 0, stream>>>(A_pre, nqk, attnw);
  k3<<<dim3(NB), dim3(256), 0, stream>>>(attnw, Wo, WvT, Pbf);
  kD<<<dim3(HW / 128, NB), dim3(256), 0, stream>>>(Pbf, input, out);
}